// Round 1
// baseline (5306.602 us; speedup 1.0000x reference)
//
#include <hip/hip_runtime.h>
#include <math.h>

#define SEQ 2049
#define EMB 768
#define NHEADS 12
#define QKVW 2304
#define MROWS 4098
#define MPAD 4224
#define NEGV -1000000000.0f

typedef short bs8 __attribute__((ext_vector_type(8)));
typedef float f4 __attribute__((ext_vector_type(4)));

__device__ __forceinline__ unsigned short f2bf(float f){
  union { float f; unsigned u; } x; x.f = f;
  unsigned r = x.u + 0x7fffu + ((x.u >> 16) & 1u);
  return (unsigned short)(r >> 16);
}

__device__ __forceinline__ void gl_lds16(const void* g, void* l){
  __builtin_amdgcn_global_load_lds((const __attribute__((address_space(1))) void*)g,
                                   (__attribute__((address_space(3))) void*)l, 16, 0, 0);
}

// ---------------- weight transpose fp32 (L,K,N) -> bf16 dst[(l*LD+NOFF+n)*K+k]
__global__ void wtr_k(const float* __restrict__ src, unsigned short* __restrict__ dst,
                      int K, int N, int LD, int NOFF)
{
  __shared__ float tile[32][33];
  int k0 = blockIdx.x*32, n0 = blockIdx.y*32, z = blockIdx.z;
  int tx = threadIdx.x, ty = threadIdx.y;
  const float* s = src + (size_t)z*K*N;
#pragma unroll
  for (int i=0;i<4;++i)
    tile[ty*4+i][tx] = s[(size_t)(k0+ty*4+i)*N + n0+tx];
  __syncthreads();
  unsigned short* dz = dst + ((size_t)z*LD + NOFF)*K;
#pragma unroll
  for (int i=0;i<4;++i)
    dz[(size_t)(n0+ty*4+i)*K + k0+tx] = f2bf(tile[tx][ty*4+i]);
}

__global__ void castconv_k(const float* __restrict__ src, unsigned short* __restrict__ dst){
  size_t i = ((size_t)blockIdx.x*256 + threadIdx.x)*4;
  float4 f = *(const float4*)(src+i);
  dst[i+0]=f2bf(f.x); dst[i+1]=f2bf(f.y); dst[i+2]=f2bf(f.z); dst[i+3]=f2bf(f.w);
}

__global__ void biascat_k(const float* __restrict__ bq, const float* __restrict__ bk,
                          const float* __restrict__ bv, float* __restrict__ dst){
  int i = blockIdx.x*256+threadIdx.x;
  int l = i/QKVW, c = i%QKVW;
  float v = (c<768) ? bq[l*768+c] : (c<1536 ? bk[l*768+c-768] : bv[l*768+c-1536]);
  dst[i] = v;
}

// ---------------- patch extraction: x (2,1,128,256,256) f32 -> Xp (4096,4096) bf16
__global__ void patchify_k(const float* __restrict__ x, unsigned short* __restrict__ Xp)
{
  size_t gid = (size_t)blockIdx.x*256 + threadIdx.x;
  size_t oi = gid*4;
  int row = (int)(oi >> 12);
  int c = (int)(oi & 4095);
  int b = row >> 11; int p = row & 2047;
  int pd = p >> 8, ph = (p>>4)&15, pw = p&15;
  int pz = c >> 8, py = (c>>4)&15, px = c&15;
  size_t src = (((size_t)(b*128 + pd*16+pz)*256) + (size_t)(ph*16+py))*256 + (size_t)(pw*16+px);
  float4 f = *(const float4*)(x+src);
  Xp[oi+0]=f2bf(f.x); Xp[oi+1]=f2bf(f.y); Xp[oi+2]=f2bf(f.z); Xp[oi+3]=f2bf(f.w);
}

// ---------------- assemble h = [cls; patches] + pos, zero pads
__global__ void assemble_k(const float* __restrict__ tmp, const float* __restrict__ cls,
                           const float* __restrict__ pos_e, float* __restrict__ H)
{
  int row = blockIdx.x; int t = threadIdx.x;
  float* hr = H + (size_t)row*EMB;
  if (row >= MROWS) { hr[t]=0.f; hr[t+256]=0.f; hr[t+512]=0.f; return; }
  int b = row / SEQ; int pos = row - b*SEQ;
#pragma unroll
  for (int c0=0;c0<3;++c0) {
    int c = t + c0*256;
    float v = (pos==0) ? cls[c] : tmp[((size_t)(b*2048 + pos-1))*EMB + c];
    hr[c] = v + pos_e[(size_t)pos*EMB + c];
  }
}

// ---------------- layernorm row -> bf16
__global__ __launch_bounds__(256) void ln_k(const float* __restrict__ H,
    const float* __restrict__ gam, const float* __restrict__ bet,
    unsigned short* __restrict__ Y)
{
  int row = blockIdx.x, t = threadIdx.x;
  const float* hr = H + (size_t)row*EMB;
  float v0 = hr[t], v1 = hr[t+256], v2 = hr[t+512];
  float s = v0+v1+v2;
#pragma unroll
  for (int off=32; off>=1; off>>=1) s += __shfl_down(s, off);
  __shared__ float r1[4], r2[4];
  if ((t&63)==0) r1[t>>6] = s;
  __syncthreads();
  float mean = (r1[0]+r1[1]+r1[2]+r1[3]) * (1.f/768.f);
  float d0=v0-mean, d1=v1-mean, d2=v2-mean;
  float q = d0*d0+d1*d1+d2*d2;
#pragma unroll
  for (int off=32; off>=1; off>>=1) q += __shfl_down(q, off);
  if ((t&63)==0) r2[t>>6] = q;
  __syncthreads();
  float rstd = rsqrtf((r2[0]+r2[1]+r2[2]+r2[3])*(1.f/768.f) + 1e-5f);
  unsigned short* yr = Y + (size_t)row*EMB;
  yr[t]     = f2bf(d0*rstd*gam[t]     + bet[t]);
  yr[t+256] = f2bf(d1*rstd*gam[t+256] + bet[t+256]);
  yr[t+512] = f2bf(d2*rstd*gam[t+512] + bet[t+512]);
}

// ---------------- final layernorm on cls rows -> fp32 out
__global__ __launch_bounds__(256) void final_ln_k(const float* __restrict__ H,
   const float* __restrict__ gam, const float* __restrict__ bet, float* __restrict__ out)
{
  int b = blockIdx.x, t = threadIdx.x;
  const float* hr = H + (size_t)(b*SEQ)*EMB;
  float v0 = hr[t], v1 = hr[t+256], v2 = hr[t+512];
  float s = v0+v1+v2;
#pragma unroll
  for (int off=32; off>=1; off>>=1) s += __shfl_down(s, off);
  __shared__ float r1[4], r2[4];
  if ((t&63)==0) r1[t>>6] = s;
  __syncthreads();
  float mean = (r1[0]+r1[1]+r1[2]+r1[3]) * (1.f/768.f);
  float d0=v0-mean, d1=v1-mean, d2=v2-mean;
  float q = d0*d0+d1*d1+d2*d2;
#pragma unroll
  for (int off=32; off>=1; off>>=1) q += __shfl_down(q, off);
  if ((t&63)==0) r2[t>>6] = q;
  __syncthreads();
  float rstd = rsqrtf((r2[0]+r2[1]+r2[2]+r2[3])*(1.f/768.f) + 1e-5f);
  out[b*EMB + t]     = d0*rstd*gam[t]     + bet[t];
  out[b*EMB + t+256] = d1*rstd*gam[t+256] + bet[t+256];
  out[b*EMB + t+512] = d2*rstd*gam[t+512] + bet[t+512];
}

// ---------------- GEMM: A(Mx K) bf16 row-major, Bt(N x K) bf16, 128x128 tile
// MODE 0: bf16 out +bias; 1: bf16 out +bias+gelu; 2: f32 C += val+bias; 3: f32 out
template<int MODE>
__global__ __launch_bounds__(256) void gemm_k(
    const unsigned short* __restrict__ A,
    const unsigned short* __restrict__ Bt,
    const float* __restrict__ bias,
    unsigned short* __restrict__ Cb,
    float* __restrict__ Cf,
    int K, int ldc)
{
  __shared__ __attribute__((aligned(16))) unsigned short lA[128*32];
  __shared__ __attribute__((aligned(16))) unsigned short lB[128*32];
  const int tid = threadIdx.x;
  const int w = tid>>6, lane = tid&63, g = lane>>4, l16 = lane&15;
  const int lr = lane>>2, lc = (lane&3)*8;
  const int tm = blockIdx.y, tn = blockIdx.x;
  const unsigned short* Ab = A + (size_t)tm*128*K;
  const unsigned short* Bb = Bt + (size_t)tn*128*K;
  const int wm = (w>>1)*64, wn = (w&1)*64;
  f4 acc[4][4] = {};
  const int nkt = K>>5;
  for (int kt=0; kt<nkt; ++kt) {
    __syncthreads();
    const size_t ko = (size_t)(kt*32 + lc);
    gl_lds16(Ab + (size_t)(w*16 + lr)*K + ko,     ((char*)lA) + w*1024);
    gl_lds16(Ab + (size_t)((w+4)*16 + lr)*K + ko, ((char*)lA) + (w+4)*1024);
    gl_lds16(Bb + (size_t)(w*16 + lr)*K + ko,     ((char*)lB) + w*1024);
    gl_lds16(Bb + (size_t)((w+4)*16 + lr)*K + ko, ((char*)lB) + (w+4)*1024);
    __syncthreads();
    bs8 af[4], bf[4];
#pragma unroll
    for (int mi=0;mi<4;++mi) af[mi] = *(const bs8*)(lA + (wm+mi*16+l16)*32 + g*8);
#pragma unroll
    for (int ni=0;ni<4;++ni) bf[ni] = *(const bs8*)(lB + (wn+ni*16+l16)*32 + g*8);
#pragma unroll
    for (int mi=0;mi<4;++mi)
#pragma unroll
      for (int ni=0;ni<4;++ni)
        acc[mi][ni] = __builtin_amdgcn_mfma_f32_16x16x32_bf16(af[mi], bf[ni], acc[mi][ni], 0,0,0);
  }
#pragma unroll
  for (int mi=0;mi<4;++mi)
#pragma unroll
    for (int ni=0;ni<4;++ni) {
      int col = tn*128 + wn + ni*16 + l16;
      float bv = bias[col];
#pragma unroll
      for (int r=0;r<4;++r) {
        int row = tm*128 + wm + mi*16 + g*4 + r;
        float val = acc[mi][ni][r] + bv;
        if (MODE==1) val = 0.5f*val*(1.f+erff(val*0.70710678f));
        if (MODE<=1) Cb[(size_t)row*ldc + col] = f2bf(val);
        else if (MODE==2) Cf[(size_t)row*ldc + col] += val;
        else Cf[(size_t)row*ldc + col] = val;
      }
    }
}

// ---------------- dilated attention branch: one block = (qtile, seg, b*head)
// qkv: (MPAD, 2304) bf16; obuf (B,NSEG,12,512,64) f32; lse (B,NSEG,12,512)
__global__ __launch_bounds__(256) void attn_branch_k(
    const unsigned short* __restrict__ qkv,
    float* __restrict__ obuf, float* __restrict__ lsebuf,
    int R, int WSZ, int NSEG)
{
  __shared__ __attribute__((aligned(16))) unsigned short Pl[4][16][136];
  __shared__ __attribute__((aligned(16))) unsigned short Vt[64][136];
  const int tid = threadIdx.x;
  const int w = tid>>6, lane = tid&63, g = lane>>4, l16 = lane&15;
  const int b = blockIdx.z / NHEADS, hd = blockIdx.z % NHEADS;
  const int seg = blockIdx.y, qt = blockIdx.x;
  const int hr = hd % R;
  const int j0 = qt*64 + w*16;
  const int kbase = seg*WSZ + hr;

  bs8 z = {0,0,0,0,0,0,0,0};
  bs8 qf0 = z, qf1 = z;
  {
    int jq = j0 + l16;
    int qpos = kbase + jq*R;
    if (qpos < SEQ) {
      const unsigned short* qrow = qkv + ((size_t)(b*SEQ + qpos))*QKVW + hd*64 + g*8;
      qf0 = *(const bs8*)(qrow);
      qf1 = *(const bs8*)(qrow + 32);
    }
  }
  f4 sc[32];
#pragma unroll
  for (int kt=0; kt<32; ++kt) {
    int key = kt*16 + l16;
    int kpos = kbase + key*R;
    bool kvld = (kpos < SEQ);
    bs8 kf0 = z, kf1 = z;
    if (kvld) {
      const unsigned short* krow = qkv + ((size_t)(b*SEQ + kpos))*QKVW + EMB + hd*64 + g*8;
      kf0 = *(const bs8*)(krow);
      kf1 = *(const bs8*)(krow + 32);
    }
    f4 acc = {0.f,0.f,0.f,0.f};
    acc = __builtin_amdgcn_mfma_f32_16x16x32_bf16(qf0, kf0, acc, 0,0,0);
    acc = __builtin_amdgcn_mfma_f32_16x16x32_bf16(qf1, kf1, acc, 0,0,0);
#pragma unroll
    for (int r=0;r<4;++r) acc[r] = kvld ? acc[r]*0.125f : NEGV;
    sc[kt] = acc;
  }
  float srow[4], lse[4];
#pragma unroll
  for (int r=0;r<4;++r) {
    float m = NEGV;
#pragma unroll
    for (int kt=0;kt<32;++kt) m = fmaxf(m, sc[kt][r]);
    m = fmaxf(m, __shfl_xor(m, 1));
    m = fmaxf(m, __shfl_xor(m, 2));
    m = fmaxf(m, __shfl_xor(m, 4));
    m = fmaxf(m, __shfl_xor(m, 8));
    float s = 0.f;
#pragma unroll
    for (int kt=0;kt<32;++kt) { float p = __expf(sc[kt][r]-m); sc[kt][r] = p; s += p; }
    s += __shfl_xor(s, 1); s += __shfl_xor(s, 2);
    s += __shfl_xor(s, 4); s += __shfl_xor(s, 8);
    srow[r] = s; lse[r] = m + __logf(s);
  }
  f4 oacc[4] = {};
#pragma unroll
  for (int ck=0; ck<4; ++ck) {
    __syncthreads();
#pragma unroll
    for (int k2=0;k2<8;++k2) {
#pragma unroll
      for (int r=0;r<4;++r)
        Pl[w][g*4+r][k2*16+l16] = f2bf(sc[ck*8+k2][r]);
    }
#pragma unroll
    for (int it=0; it<4; ++it) {
      int idx = tid + it*256;
      int kk = idx & 127;
      int dblk = idx >> 7;
      int kpos = kbase + (ck*128 + kk)*R;
      unsigned short tv[8] = {0,0,0,0,0,0,0,0};
      if (kpos < SEQ) {
        const unsigned short* vrow = qkv + ((size_t)(b*SEQ + kpos))*QKVW + 1536 + hd*64 + dblk*8;
        *(bs8*)tv = *(const bs8*)vrow;
      }
#pragma unroll
      for (int ii=0; ii<8; ++ii) Vt[dblk*8+ii][kk] = tv[ii];
    }
    __syncthreads();
#pragma unroll
    for (int ks=0; ks<4; ++ks) {
      bs8 pa = *(const bs8*)(&Pl[w][l16][ks*32 + g*8]);
#pragma unroll
      for (int dt=0; dt<4; ++dt) {
        bs8 vb = *(const bs8*)(&Vt[dt*16+l16][ks*32 + g*8]);
        oacc[dt] = __builtin_amdgcn_mfma_f32_16x16x32_bf16(pa, vb, oacc[dt], 0,0,0);
      }
    }
  }
  size_t obase = ((size_t)(b*NSEG + seg)*NHEADS + hd)*512;
#pragma unroll
  for (int dt=0; dt<4; ++dt)
#pragma unroll
    for (int r=0;r<4;++r) {
      int j = j0 + g*4 + r;
      obuf[(obase + j)*64 + dt*16 + l16] = oacc[dt][r] / srow[r];
    }
  if (l16 == 0) {
#pragma unroll
    for (int r=0;r<4;++r) lsebuf[obase + j0 + g*4 + r] = lse[r];
  }
}

// ---------------- combine 3 branches via lse softmax -> attn bf16 (MPAD,768)
__global__ __launch_bounds__(256) void attn_combine_k(
   const float* __restrict__ o1, const float* __restrict__ l1,
   const float* __restrict__ o2, const float* __restrict__ l2,
   const float* __restrict__ o3, const float* __restrict__ l3,
   unsigned short* __restrict__ attn)
{
  int row = blockIdx.x; int t = threadIdx.x;
  unsigned short* arow = attn + (size_t)row*EMB;
  if (row >= MROWS) { arow[t]=0; arow[t+256]=0; arow[t+512]=0; return; }
  int b = row / SEQ, pos = row - (row/SEQ)*SEQ;
#pragma unroll
  for (int c0=0; c0<3; ++c0) {
    int cc = t + c0*256;
    int hd = cc >> 6, d = cc & 63;
    float L0,L1v,L2v,O0,O1v,O2v;
    {
      int seg = pos >> 9; int j = pos & 511;
      size_t base = ((size_t)(b*5 + seg)*NHEADS + hd)*512 + j;
      L0 = l1[base]; O0 = o1[base*64 + d];
    }
    if ((pos & 1) == (hd & 1)) {
      int seg = pos >> 10; int j = ((pos & 1023) - (hd&1)) >> 1;
      size_t base = ((size_t)(b*3 + seg)*NHEADS + hd)*512 + j;
      L1v = l2[base]; O1v = o2[base*64 + d];
    } else { L1v = NEGV; O1v = 0.f; }
    if ((pos & 3) == (hd & 3)) {
      int seg = pos >> 11; int j = ((pos & 2047) - (hd&3)) >> 2;
      size_t base = ((size_t)(b*2 + seg)*NHEADS + hd)*512 + j;
      L2v = l3[base]; O2v = o3[base*64 + d];
    } else { L2v = NEGV; O2v = 0.f; }
    float m = fmaxf(L0, fmaxf(L1v, L2v));
    float e0 = __expf(L0-m), e1 = __expf(L1v-m), e2 = __expf(L2v-m);
    float inv = 1.f/(e0+e1+e2);
    arow[cc] = f2bf((e0*O0+e1*O1v+e2*O2v)*inv);
  }
}

extern "C" void kernel_launch(void* const* d_in, const int* in_sizes, int n_in,
                              void* d_out, int out_size, void* d_ws, size_t ws_size,
                              hipStream_t stream) {
  const float* x       = (const float*)d_in[0];
  const float* conv_w  = (const float*)d_in[1];
  const float* conv_b  = (const float*)d_in[2];
  const float* cls     = (const float*)d_in[3];
  const float* pos_e   = (const float*)d_in[4];
  const float* ln1_g   = (const float*)d_in[5];
  const float* ln1_b   = (const float*)d_in[6];
  const float* wq      = (const float*)d_in[7];
  const float* bq      = (const float*)d_in[8];
  const float* wk      = (const float*)d_in[9];
  const float* bk      = (const float*)d_in[10];
  const float* wv      = (const float*)d_in[11];
  const float* bv      = (const float*)d_in[12];
  const float* wo      = (const float*)d_in[13];
  const float* bo      = (const float*)d_in[14];
  const float* ln2_g   = (const float*)d_in[15];
  const float* ln2_b   = (const float*)d_in[16];
  const float* w1      = (const float*)d_in[17];
  const float* b1      = (const float*)d_in[18];
  const float* w2      = (const float*)d_in[19];
  const float* b2      = (const float*)d_in[20];
  const float* nf_g    = (const float*)d_in[21];
  const float* nf_b    = (const float*)d_in[22];

  char* ws = (char*)d_ws;
  size_t off = 0;
  auto alloc = [&](size_t bytes)->char* {
    char* p = ws + off; off += (bytes + 255) & ~(size_t)255; return p;
  };
  unsigned short* wqkv_t = (unsigned short*)alloc((size_t)12*2304*768*2);
  unsigned short* wo_t   = (unsigned short*)alloc((size_t)12*768*768*2);
  unsigned short* w1_t   = (unsigned short*)alloc((size_t)12*3072*768*2);
  unsigned short* w2_t   = (unsigned short*)alloc((size_t)12*768*3072*2);
  unsigned short* cw_b   = (unsigned short*)alloc((size_t)768*4096*2);
  float* bqkv            = (float*)alloc((size_t)12*2304*4);
  unsigned short* Xp     = (unsigned short*)alloc((size_t)4096*4096*2);
  float* tmp             = (float*)alloc((size_t)4096*768*4);
  float* H               = (float*)alloc((size_t)MPAD*768*4);
  unsigned short* Y      = (unsigned short*)alloc((size_t)MPAD*768*2);
  unsigned short* QKV    = (unsigned short*)alloc((size_t)MPAD*2304*2);
  unsigned short* ATT    = (unsigned short*)alloc((size_t)MPAD*768*2);
  unsigned short* Y2     = (unsigned short*)alloc((size_t)MPAD*3072*2);
  float* O1 = (float*)alloc((size_t)2*5*12*512*64*4);
  float* O2 = (float*)alloc((size_t)2*3*12*512*64*4);
  float* O3 = (float*)alloc((size_t)2*2*12*512*64*4);
  float* L1 = (float*)alloc((size_t)2*5*12*512*4);
  float* L2 = (float*)alloc((size_t)2*3*12*512*4);
  float* L3 = (float*)alloc((size_t)2*2*12*512*4);

  dim3 tb(32,8);
  wtr_k<<<dim3(24,24,12), tb, 0, stream>>>(wq, wqkv_t, 768, 768, 2304, 0);
  wtr_k<<<dim3(24,24,12), tb, 0, stream>>>(wk, wqkv_t, 768, 768, 2304, 768);
  wtr_k<<<dim3(24,24,12), tb, 0, stream>>>(wv, wqkv_t, 768, 768, 2304, 1536);
  wtr_k<<<dim3(24,24,12), tb, 0, stream>>>(wo, wo_t, 768, 768, 768, 0);
  wtr_k<<<dim3(24,96,12), tb, 0, stream>>>(w1, w1_t, 768, 3072, 3072, 0);
  wtr_k<<<dim3(96,24,12), tb, 0, stream>>>(w2, w2_t, 3072, 768, 768, 0);
  castconv_k<<<3072,256,0,stream>>>(conv_w, cw_b);
  biascat_k<<<108,256,0,stream>>>(bq,bk,bv,bqkv);
  patchify_k<<<16384,256,0,stream>>>(x, Xp);
  gemm_k<3><<<dim3(6,32),256,0,stream>>>(Xp, cw_b, conv_b, nullptr, tmp, 4096, 768);
  assemble_k<<<MPAD,256,0,stream>>>(tmp, cls, pos_e, H);

  for (int l=0;l<12;++l) {
    ln_k<<<MPAD,256,0,stream>>>(H, ln1_g + l*768, ln1_b + l*768, Y);
    gemm_k<0><<<dim3(18,33),256,0,stream>>>(Y, wqkv_t + (size_t)l*2304*768, bqkv + l*2304, QKV, nullptr, 768, 2304);
    attn_branch_k<<<dim3(8,5,24),256,0,stream>>>(QKV, O1, L1, 1, 512, 5);
    attn_branch_k<<<dim3(8,3,24),256,0,stream>>>(QKV, O2, L2, 2, 1024, 3);
    attn_branch_k<<<dim3(8,2,24),256,0,stream>>>(QKV, O3, L3, 4, 2048, 2);
    attn_combine_k<<<MPAD,256,0,stream>>>(O1,L1,O2,L2,O3,L3, ATT);
    gemm_k<2><<<dim3(6,33),256,0,stream>>>(ATT, wo_t + (size_t)l*768*768, bo + l*768, nullptr, H, 768, 768);
    ln_k<<<MPAD,256,0,stream>>>(H, ln2_g + l*768, ln2_b + l*768, Y);
    gemm_k<1><<<dim3(24,33),256,0,stream>>>(Y, w1_t + (size_t)l*3072*768, b1 + l*3072, Y2, nullptr, 768, 3072);
    gemm_k<2><<<dim3(6,33),256,0,stream>>>(Y2, w2_t + (size_t)l*768*3072, b2 + l*768, nullptr, H, 3072, 768);
  }
  final_ln_k<<<2,256,0,stream>>>(H, nf_g, nf_b, (float*)d_out);
}

// Round 2
// 3893.540 us; speedup vs baseline: 1.3629x; 1.3629x over previous
//
#include <hip/hip_runtime.h>
#include <math.h>

#define SEQ 2049
#define EMB 768
#define NHEADS 12
#define QKVW 2304
#define MROWS 4098
#define MPAD 4224
#define NEGV -1000000000.0f

typedef short bs8 __attribute__((ext_vector_type(8)));
typedef float f4 __attribute__((ext_vector_type(4)));

__device__ __forceinline__ unsigned short f2bf(float f){
  union { float f; unsigned u; } x; x.f = f;
  unsigned r = x.u + 0x7fffu + ((x.u >> 16) & 1u);
  return (unsigned short)(r >> 16);
}
__device__ __forceinline__ float bf2f(unsigned short u){
  union { unsigned u; float f; } x; x.u = ((unsigned)u) << 16; return x.f;
}

__device__ __forceinline__ void gl_lds16(const void* g, void* l){
  __builtin_amdgcn_global_load_lds((const __attribute__((address_space(1))) void*)g,
                                   (__attribute__((address_space(3))) void*)l, 16, 0, 0);
}

// ---------------- weight transpose fp32 (L,K,N) -> bf16 dst[(l*LD+NOFF+n)*K+k]
__global__ void wtr_k(const float* __restrict__ src, unsigned short* __restrict__ dst,
                      int K, int N, int LD, int NOFF)
{
  __shared__ float tile[32][33];
  int k0 = blockIdx.x*32, n0 = blockIdx.y*32, z = blockIdx.z;
  int tx = threadIdx.x, ty = threadIdx.y;
  const float* s = src + (size_t)z*K*N;
#pragma unroll
  for (int i=0;i<4;++i)
    tile[ty*4+i][tx] = s[(size_t)(k0+ty*4+i)*N + n0+tx];
  __syncthreads();
  unsigned short* dz = dst + ((size_t)z*LD + NOFF)*K;
#pragma unroll
  for (int i=0;i<4;++i)
    dz[(size_t)(n0+ty*4+i)*K + k0+tx] = f2bf(tile[tx][ty*4+i]);
}

__global__ void castconv_k(const float* __restrict__ src, unsigned short* __restrict__ dst){
  size_t i = ((size_t)blockIdx.x*256 + threadIdx.x)*4;
  float4 f = *(const float4*)(src+i);
  dst[i+0]=f2bf(f.x); dst[i+1]=f2bf(f.y); dst[i+2]=f2bf(f.z); dst[i+3]=f2bf(f.w);
}

__global__ void biascat_k(const float* __restrict__ bq, const float* __restrict__ bk,
                          const float* __restrict__ bv, float* __restrict__ dst){
  int i = blockIdx.x*256+threadIdx.x;
  int l = i/QKVW, c = i%QKVW;
  float v = (c<768) ? bq[l*768+c] : (c<1536 ? bk[l*768+c-768] : bv[l*768+c-1536]);
  dst[i] = v;
}

// ---------------- patch extraction: x (2,1,128,256,256) f32 -> Xp (4096,4096) bf16
__global__ void patchify_k(const float* __restrict__ x, unsigned short* __restrict__ Xp)
{
  size_t gid = (size_t)blockIdx.x*256 + threadIdx.x;
  size_t oi = gid*4;
  int row = (int)(oi >> 12);
  int c = (int)(oi & 4095);
  int b = row >> 11; int p = row & 2047;
  int pd = p >> 8, ph = (p>>4)&15, pw = p&15;
  int pz = c >> 8, py = (c>>4)&15, px = c&15;
  size_t src = (((size_t)(b*128 + pd*16+pz)*256) + (size_t)(ph*16+py))*256 + (size_t)(pw*16+px);
  float4 f = *(const float4*)(x+src);
  Xp[oi+0]=f2bf(f.x); Xp[oi+1]=f2bf(f.y); Xp[oi+2]=f2bf(f.z); Xp[oi+3]=f2bf(f.w);
}

// ---------------- assemble h = [cls; patches] + pos, zero pads
__global__ void assemble_k(const float* __restrict__ tmp, const float* __restrict__ cls,
                           const float* __restrict__ pos_e, float* __restrict__ H)
{
  int row = blockIdx.x; int t = threadIdx.x;
  float* hr = H + (size_t)row*EMB;
  if (row >= MROWS) { hr[t]=0.f; hr[t+256]=0.f; hr[t+512]=0.f; return; }
  int b = row / SEQ; int pos = row - b*SEQ;
#pragma unroll
  for (int c0=0;c0<3;++c0) {
    int c = t + c0*256;
    float v = (pos==0) ? cls[c] : tmp[((size_t)(b*2048 + pos-1))*EMB + c];
    hr[c] = v + pos_e[(size_t)pos*EMB + c];
  }
}

// ---------------- layernorm row -> bf16
__global__ __launch_bounds__(256) void ln_k(const float* __restrict__ H,
    const float* __restrict__ gam, const float* __restrict__ bet,
    unsigned short* __restrict__ Y)
{
  int row = blockIdx.x, t = threadIdx.x;
  const float* hr = H + (size_t)row*EMB;
  float v0 = hr[t], v1 = hr[t+256], v2 = hr[t+512];
  float s = v0+v1+v2;
#pragma unroll
  for (int off=32; off>=1; off>>=1) s += __shfl_down(s, off);
  __shared__ float r1[4], r2[4];
  if ((t&63)==0) r1[t>>6] = s;
  __syncthreads();
  float mean = (r1[0]+r1[1]+r1[2]+r1[3]) * (1.f/768.f);
  float d0=v0-mean, d1=v1-mean, d2=v2-mean;
  float q = d0*d0+d1*d1+d2*d2;
#pragma unroll
  for (int off=32; off>=1; off>>=1) q += __shfl_down(q, off);
  if ((t&63)==0) r2[t>>6] = q;
  __syncthreads();
  float rstd = rsqrtf((r2[0]+r2[1]+r2[2]+r2[3])*(1.f/768.f) + 1e-5f);
  unsigned short* yr = Y + (size_t)row*EMB;
  yr[t]     = f2bf(d0*rstd*gam[t]     + bet[t]);
  yr[t+256] = f2bf(d1*rstd*gam[t+256] + bet[t+256]);
  yr[t+512] = f2bf(d2*rstd*gam[t+512] + bet[t+512]);
}

// ---------------- final layernorm on cls rows -> fp32 out
__global__ __launch_bounds__(256) void final_ln_k(const float* __restrict__ H,
   const float* __restrict__ gam, const float* __restrict__ bet, float* __restrict__ out)
{
  int b = blockIdx.x, t = threadIdx.x;
  const float* hr = H + (size_t)(b*SEQ)*EMB;
  float v0 = hr[t], v1 = hr[t+256], v2 = hr[t+512];
  float s = v0+v1+v2;
#pragma unroll
  for (int off=32; off>=1; off>>=1) s += __shfl_down(s, off);
  __shared__ float r1[4], r2[4];
  if ((t&63)==0) r1[t>>6] = s;
  __syncthreads();
  float mean = (r1[0]+r1[1]+r1[2]+r1[3]) * (1.f/768.f);
  float d0=v0-mean, d1=v1-mean, d2=v2-mean;
  float q = d0*d0+d1*d1+d2*d2;
#pragma unroll
  for (int off=32; off>=1; off>>=1) q += __shfl_down(q, off);
  if ((t&63)==0) r2[t>>6] = q;
  __syncthreads();
  float rstd = rsqrtf((r2[0]+r2[1]+r2[2]+r2[3])*(1.f/768.f) + 1e-5f);
  out[b*EMB + t]     = d0*rstd*gam[t]     + bet[t];
  out[b*EMB + t+256] = d1*rstd*gam[t+256] + bet[t+256];
  out[b*EMB + t+512] = d2*rstd*gam[t+512] + bet[t+512];
}

// ---------------- GEMM: A(MxK) bf16 row-major, Bt(NxK) bf16, 128x128 tile
// MODE 0: bf16 out +bias; 1: bf16 out +bias+gelu; 2: f32 C += val+bias; 3: f32 out
template<int MODE>
__global__ __launch_bounds__(256) void gemm_k(
    const unsigned short* __restrict__ A,
    const unsigned short* __restrict__ Bt,
    const float* __restrict__ bias,
    unsigned short* __restrict__ Cb,
    float* __restrict__ Cf,
    int K, int ldc)
{
  __shared__ __attribute__((aligned(16))) unsigned short lA[128*32];
  __shared__ __attribute__((aligned(16))) unsigned short lB[128*32];
  const int tid = threadIdx.x;
  const int w = tid>>6, lane = tid&63, g = lane>>4, l16 = lane&15;
  const int lr = lane>>2, lc = (lane&3)*8;
  const int tm = blockIdx.y, tn = blockIdx.x;
  const unsigned short* Ab = A + (size_t)tm*128*K;
  const unsigned short* Bb = Bt + (size_t)tn*128*K;
  const int wm = (w>>1)*64, wn = (w&1)*64;
  f4 acc[4][4] = {};
  const int nkt = K>>5;
  for (int kt=0; kt<nkt; ++kt) {
    __syncthreads();
    const size_t ko = (size_t)(kt*32 + lc);
    gl_lds16(Ab + (size_t)(w*16 + lr)*K + ko,     ((char*)lA) + w*1024);
    gl_lds16(Ab + (size_t)((w+4)*16 + lr)*K + ko, ((char*)lA) + (w+4)*1024);
    gl_lds16(Bb + (size_t)(w*16 + lr)*K + ko,     ((char*)lB) + w*1024);
    gl_lds16(Bb + (size_t)((w+4)*16 + lr)*K + ko, ((char*)lB) + (w+4)*1024);
    __syncthreads();
    bs8 af[4], bf[4];
#pragma unroll
    for (int mi=0;mi<4;++mi) af[mi] = *(const bs8*)(lA + (wm+mi*16+l16)*32 + g*8);
#pragma unroll
    for (int ni=0;ni<4;++ni) bf[ni] = *(const bs8*)(lB + (wn+ni*16+l16)*32 + g*8);
#pragma unroll
    for (int mi=0;mi<4;++mi)
#pragma unroll
      for (int ni=0;ni<4;++ni)
        acc[mi][ni] = __builtin_amdgcn_mfma_f32_16x16x32_bf16(af[mi], bf[ni], acc[mi][ni], 0,0,0);
  }
#pragma unroll
  for (int mi=0;mi<4;++mi)
#pragma unroll
    for (int ni=0;ni<4;++ni) {
      int col = tn*128 + wn + ni*16 + l16;
      float bv = bias[col];
#pragma unroll
      for (int r=0;r<4;++r) {
        int row = tm*128 + wm + mi*16 + g*4 + r;
        float val = acc[mi][ni][r] + bv;
        if (MODE==1) val = 0.5f*val*(1.f+erff(val*0.70710678f));
        if (MODE<=1) Cb[(size_t)row*ldc + col] = f2bf(val);
        else if (MODE==2) Cf[(size_t)row*ldc + col] += val;
        else Cf[(size_t)row*ldc + col] = val;
      }
    }
}

// ---------------- fused dilated attention, all 3 branches, online-flash
// block = 256 thr (4 waves); each block: 64 q rows x 512 keys of one (branch,seg,b,head)
__global__ __launch_bounds__(256) void attn_all_k(
    const unsigned short* __restrict__ qkv,
    unsigned short* __restrict__ O1, float* __restrict__ L1,
    unsigned short* __restrict__ O2, float* __restrict__ L2,
    unsigned short* __restrict__ O3, float* __restrict__ L3)
{
  __shared__ __attribute__((aligned(16))) unsigned short lK[128*72];    // [key][72]
  __shared__ __attribute__((aligned(16))) unsigned short lVt[64*136];   // [d][136]
  __shared__ __attribute__((aligned(16))) unsigned short Pl[4][16][136];
  const int tid = threadIdx.x;
  const int w = tid>>6, lane = tid&63, g = lane>>4, l16 = lane&15;

  int id = blockIdx.x;
  int R, WSZ, NSEG; unsigned short* OB; float* LB;
  if (id < 960)       { R=1; WSZ=512;  NSEG=5; OB=O1; LB=L1; }
  else if (id < 1536) { id -= 960;  R=2; WSZ=1024; NSEG=3; OB=O2; LB=L2; }
  else                { id -= 1536; R=4; WSZ=2048; NSEG=2; OB=O3; LB=L3; }
  const int qt = id & 7; int rest = id >> 3;
  const int seg = rest % NSEG; const int bh = rest / NSEG;
  const int b = bh / NHEADS, hd = bh % NHEADS;
  const int hr = hd % R;
  const int j0 = qt*64 + w*16;
  const int kbase = seg*WSZ + hr;
  const unsigned short* qkvb = qkv + (size_t)b*SEQ*QKVW;

  bs8 z = {0,0,0,0,0,0,0,0};
  bs8 qf0 = z, qf1 = z;
  {
    int qpos = kbase + (j0 + l16)*R;
    if (qpos < SEQ) {
      const unsigned short* qrow = qkvb + (size_t)qpos*QKVW + hd*64 + g*8;
      qf0 = *(const bs8*)(qrow);
      qf1 = *(const bs8*)(qrow + 32);
    }
  }

  float rm[4], rs[4];
  f4 oacc[4] = {};
#pragma unroll
  for (int r=0;r<4;++r) { rm[r] = NEGV; rs[r] = 0.f; }

  for (int c=0; c<4; ++c) {
    __syncthreads();
    // ---- stage K chunk: rows = 8 per instr, coalesced 128B per row
#pragma unroll
    for (int it=0; it<4; ++it) {
      int idx = tid + it*256;
      int kk = idx >> 3, dblk = idx & 7;
      int kpos = kbase + (c*128 + kk)*R;
      bs8 kv = z;
      if (kpos < SEQ) kv = *(const bs8*)(qkvb + (size_t)kpos*QKVW + EMB + hd*64 + dblk*8);
      *(bs8*)(lK + kk*72 + dblk*8) = kv;
    }
    // ---- stage V chunk transposed
#pragma unroll
    for (int it=0; it<4; ++it) {
      int idx = tid + it*256;
      int kk = idx & 127, dblk = idx >> 7;
      int kpos = kbase + (c*128 + kk)*R;
      unsigned short tv[8] = {0,0,0,0,0,0,0,0};
      if (kpos < SEQ)
        *(bs8*)tv = *(const bs8*)(qkvb + (size_t)kpos*QKVW + 1536 + hd*64 + dblk*8);
#pragma unroll
      for (int ii=0; ii<8; ++ii) lVt[(dblk*8+ii)*136 + kk] = tv[ii];
    }
    __syncthreads();

    // ---- scores for this 128-key chunk
    f4 sc[8];
#pragma unroll
    for (int kt=0; kt<8; ++kt) {
      int key = kt*16 + l16;
      bs8 kf0 = *(const bs8*)(lK + key*72 + g*8);
      bs8 kf1 = *(const bs8*)(lK + key*72 + 32 + g*8);
      f4 acc = {0.f,0.f,0.f,0.f};
      acc = __builtin_amdgcn_mfma_f32_16x16x32_bf16(qf0, kf0, acc, 0,0,0);
      acc = __builtin_amdgcn_mfma_f32_16x16x32_bf16(qf1, kf1, acc, 0,0,0);
      int kpos = kbase + (c*128 + key)*R;
      bool kvld = (kpos < SEQ);
#pragma unroll
      for (int r=0;r<4;++r) sc[kt][r] = kvld ? acc[r]*0.125f : NEGV;
    }
    // ---- online softmax update
    float scl[4];
#pragma unroll
    for (int r=0;r<4;++r) {
      float mx = sc[0][r];
#pragma unroll
      for (int kt=1;kt<8;++kt) mx = fmaxf(mx, sc[kt][r]);
      mx = fmaxf(mx, __shfl_xor(mx, 1));
      mx = fmaxf(mx, __shfl_xor(mx, 2));
      mx = fmaxf(mx, __shfl_xor(mx, 4));
      mx = fmaxf(mx, __shfl_xor(mx, 8));
      float mn = fmaxf(rm[r], mx);
      scl[r] = __expf(rm[r] - mn);
      rm[r] = mn;
    }
#pragma unroll
    for (int r=0;r<4;++r) {
      float sm = 0.f;
#pragma unroll
      for (int kt=0;kt<8;++kt) { float p = __expf(sc[kt][r] - rm[r]); sc[kt][r] = p; sm += p; }
      sm += __shfl_xor(sm, 1); sm += __shfl_xor(sm, 2);
      sm += __shfl_xor(sm, 4); sm += __shfl_xor(sm, 8);
      rs[r] = rs[r]*scl[r] + sm;
    }
#pragma unroll
    for (int dt=0; dt<4; ++dt)
#pragma unroll
      for (int r=0;r<4;++r) oacc[dt][r] *= scl[r];
    // ---- P -> LDS (per-wave region, no barrier needed)
#pragma unroll
    for (int kt=0;kt<8;++kt)
#pragma unroll
      for (int r=0;r<4;++r)
        Pl[w][g*4+r][kt*16+l16] = f2bf(sc[kt][r]);
    // ---- PV accumulate
#pragma unroll
    for (int ks=0; ks<4; ++ks) {
      bs8 pa = *(const bs8*)(&Pl[w][l16][ks*32 + g*8]);
#pragma unroll
      for (int dt=0; dt<4; ++dt) {
        bs8 vb = *(const bs8*)(lVt + (dt*16+l16)*136 + ks*32 + g*8);
        oacc[dt] = __builtin_amdgcn_mfma_f32_16x16x32_bf16(pa, vb, oacc[dt], 0,0,0);
      }
    }
  }

  size_t obase = ((size_t)(b*NSEG + seg)*NHEADS + hd)*512;
#pragma unroll
  for (int dt=0; dt<4; ++dt)
#pragma unroll
    for (int r=0;r<4;++r) {
      int j = j0 + g*4 + r;
      OB[(obase + j)*64 + dt*16 + l16] = f2bf(oacc[dt][r] / rs[r]);
    }
  if (l16 == 0) {
#pragma unroll
    for (int r=0;r<4;++r) LB[obase + j0 + g*4 + r] = rm[r] + __logf(rs[r]);
  }
}

// ---------------- combine 3 branches via lse softmax -> attn bf16 (MPAD,768)
__global__ __launch_bounds__(256) void attn_combine_k(
   const unsigned short* __restrict__ o1, const float* __restrict__ l1,
   const unsigned short* __restrict__ o2, const float* __restrict__ l2,
   const unsigned short* __restrict__ o3, const float* __restrict__ l3,
   unsigned short* __restrict__ attn)
{
  int row = blockIdx.x; int t = threadIdx.x;
  unsigned short* arow = attn + (size_t)row*EMB;
  if (row >= MROWS) { arow[t]=0; arow[t+256]=0; arow[t+512]=0; return; }
  int b = row / SEQ, pos = row - (row/SEQ)*SEQ;
#pragma unroll
  for (int c0=0; c0<3; ++c0) {
    int cc = t + c0*256;
    int hd = cc >> 6, d = cc & 63;
    float L0,L1v,L2v,O0,O1v,O2v;
    {
      int seg = pos >> 9; int j = pos & 511;
      size_t base = ((size_t)(b*5 + seg)*NHEADS + hd)*512 + j;
      L0 = l1[base]; O0 = bf2f(o1[base*64 + d]);
    }
    if ((pos & 1) == (hd & 1)) {
      int seg = pos >> 10; int j = ((pos & 1023) - (hd&1)) >> 1;
      size_t base = ((size_t)(b*3 + seg)*NHEADS + hd)*512 + j;
      L1v = l2[base]; O1v = bf2f(o2[base*64 + d]);
    } else { L1v = NEGV; O1v = 0.f; }
    if ((pos & 3) == (hd & 3)) {
      int seg = pos >> 11; int j = ((pos & 2047) - (hd&3)) >> 2;
      size_t base = ((size_t)(b*2 + seg)*NHEADS + hd)*512 + j;
      L2v = l3[base]; O2v = bf2f(o3[base*64 + d]);
    } else { L2v = NEGV; O2v = 0.f; }
    float m = fmaxf(L0, fmaxf(L1v, L2v));
    float e0 = __expf(L0-m), e1 = __expf(L1v-m), e2 = __expf(L2v-m);
    float inv = 1.f/(e0+e1+e2);
    arow[cc] = f2bf((e0*O0+e1*O1v+e2*O2v)*inv);
  }
}

extern "C" void kernel_launch(void* const* d_in, const int* in_sizes, int n_in,
                              void* d_out, int out_size, void* d_ws, size_t ws_size,
                              hipStream_t stream) {
  const float* x       = (const float*)d_in[0];
  const float* conv_w  = (const float*)d_in[1];
  const float* conv_b  = (const float*)d_in[2];
  const float* cls     = (const float*)d_in[3];
  const float* pos_e   = (const float*)d_in[4];
  const float* ln1_g   = (const float*)d_in[5];
  const float* ln1_b   = (const float*)d_in[6];
  const float* wq      = (const float*)d_in[7];
  const float* bq      = (const float*)d_in[8];
  const float* wk      = (const float*)d_in[9];
  const float* bk      = (const float*)d_in[10];
  const float* wv      = (const float*)d_in[11];
  const float* bv      = (const float*)d_in[12];
  const float* wo      = (const float*)d_in[13];
  const float* bo      = (const float*)d_in[14];
  const float* ln2_g   = (const float*)d_in[15];
  const float* ln2_b   = (const float*)d_in[16];
  const float* w1      = (const float*)d_in[17];
  const float* b1      = (const float*)d_in[18];
  const float* w2      = (const float*)d_in[19];
  const float* b2      = (const float*)d_in[20];
  const float* nf_g    = (const float*)d_in[21];
  const float* nf_b    = (const float*)d_in[22];

  char* ws = (char*)d_ws;
  size_t off = 0;
  auto alloc = [&](size_t bytes)->char* {
    char* p = ws + off; off += (bytes + 255) & ~(size_t)255; return p;
  };
  unsigned short* wqkv_t = (unsigned short*)alloc((size_t)12*2304*768*2);
  unsigned short* wo_t   = (unsigned short*)alloc((size_t)12*768*768*2);
  unsigned short* w1_t   = (unsigned short*)alloc((size_t)12*3072*768*2);
  unsigned short* w2_t   = (unsigned short*)alloc((size_t)12*768*3072*2);
  unsigned short* cw_b   = (unsigned short*)alloc((size_t)768*4096*2);
  float* bqkv            = (float*)alloc((size_t)12*2304*4);
  unsigned short* Xp     = (unsigned short*)alloc((size_t)4096*4096*2);
  float* tmp             = (float*)alloc((size_t)4096*768*4);
  float* H               = (float*)alloc((size_t)MPAD*768*4);
  unsigned short* Y      = (unsigned short*)alloc((size_t)MPAD*768*2);
  unsigned short* QKV    = (unsigned short*)alloc((size_t)MPAD*2304*2);
  unsigned short* ATT    = (unsigned short*)alloc((size_t)MPAD*768*2);
  unsigned short* Y2     = (unsigned short*)alloc((size_t)MPAD*3072*2);
  unsigned short* O1 = (unsigned short*)alloc((size_t)2*5*12*512*64*2);
  unsigned short* O2 = (unsigned short*)alloc((size_t)2*3*12*512*64*2);
  unsigned short* O3 = (unsigned short*)alloc((size_t)2*2*12*512*64*2);
  float* L1 = (float*)alloc((size_t)2*5*12*512*4);
  float* L2 = (float*)alloc((size_t)2*3*12*512*4);
  float* L3 = (float*)alloc((size_t)2*2*12*512*4);

  dim3 tb(32,8);
  wtr_k<<<dim3(24,24,12), tb, 0, stream>>>(wq, wqkv_t, 768, 768, 2304, 0);
  wtr_k<<<dim3(24,24,12), tb, 0, stream>>>(wk, wqkv_t, 768, 768, 2304, 768);
  wtr_k<<<dim3(24,24,12), tb, 0, stream>>>(wv, wqkv_t, 768, 768, 2304, 1536);
  wtr_k<<<dim3(24,24,12), tb, 0, stream>>>(wo, wo_t, 768, 768, 768, 0);
  wtr_k<<<dim3(24,96,12), tb, 0, stream>>>(w1, w1_t, 768, 3072, 3072, 0);
  wtr_k<<<dim3(96,24,12), tb, 0, stream>>>(w2, w2_t, 3072, 768, 768, 0);
  castconv_k<<<3072,256,0,stream>>>(conv_w, cw_b);
  biascat_k<<<108,256,0,stream>>>(bq,bk,bv,bqkv);
  patchify_k<<<16384,256,0,stream>>>(x, Xp);
  gemm_k<3><<<dim3(6,32),256,0,stream>>>(Xp, cw_b, conv_b, nullptr, tmp, 4096, 768);
  assemble_k<<<MPAD,256,0,stream>>>(tmp, cls, pos_e, H);

  for (int l=0;l<12;++l) {
    ln_k<<<MPAD,256,0,stream>>>(H, ln1_g + l*768, ln1_b + l*768, Y);
    gemm_k<0><<<dim3(18,33),256,0,stream>>>(Y, wqkv_t + (size_t)l*2304*768, bqkv + l*2304, QKV, nullptr, 768, 2304);
    attn_all_k<<<1920,256,0,stream>>>(QKV, O1,L1,O2,L2,O3,L3);
    attn_combine_k<<<MPAD,256,0,stream>>>(O1,L1,O2,L2,O3,L3, ATT);
    gemm_k<2><<<dim3(6,33),256,0,stream>>>(ATT, wo_t + (size_t)l*768*768, bo + l*768, nullptr, H, 768, 768);
    ln_k<<<MPAD,256,0,stream>>>(H, ln2_g + l*768, ln2_b + l*768, Y);
    gemm_k<1><<<dim3(24,33),256,0,stream>>>(Y, w1_t + (size_t)l*3072*768, b1 + l*3072, Y2, nullptr, 768, 3072);
    gemm_k<2><<<dim3(6,33),256,0,stream>>>(Y2, w2_t + (size_t)l*768*3072, b2 + l*768, nullptr, H, 3072, 768);
  }
  final_ln_k<<<2,256,0,stream>>>(H, nf_g, nf_b, (float*)d_out);
}

// Round 3
// 3213.126 us; speedup vs baseline: 1.6515x; 1.2118x over previous
//
#include <hip/hip_runtime.h>
#include <math.h>

#define SEQ 2049
#define EMB 768
#define NHEADS 12
#define QKVW 2304
#define MROWS 4098
#define MPAD 4224
#define NEGV -1000000000.0f

typedef short bs8 __attribute__((ext_vector_type(8)));
typedef float f4 __attribute__((ext_vector_type(4)));

__device__ __forceinline__ unsigned short f2bf(float f){
  union { float f; unsigned u; } x; x.f = f;
  unsigned r = x.u + 0x7fffu + ((x.u >> 16) & 1u);
  return (unsigned short)(r >> 16);
}
__device__ __forceinline__ float bf2f(unsigned short u){
  union { unsigned u; float f; } x; x.u = ((unsigned)u) << 16; return x.f;
}

__device__ __forceinline__ void gl_lds16(const void* g, void* l){
  __builtin_amdgcn_global_load_lds((const __attribute__((address_space(1))) void*)g,
                                   (__attribute__((address_space(3))) void*)l, 16, 0, 0);
}

// ---------------- weight transpose fp32 (L,K,N) -> bf16 dst[(l*LD+NOFF+n)*K+k]
__global__ void wtr_k(const float* __restrict__ src, unsigned short* __restrict__ dst,
                      int K, int N, int LD, int NOFF)
{
  __shared__ float tile[32][33];
  int k0 = blockIdx.x*32, n0 = blockIdx.y*32, z = blockIdx.z;
  int tx = threadIdx.x, ty = threadIdx.y;
  const float* s = src + (size_t)z*K*N;
#pragma unroll
  for (int i=0;i<4;++i)
    tile[ty*4+i][tx] = s[(size_t)(k0+ty*4+i)*N + n0+tx];
  __syncthreads();
  unsigned short* dz = dst + ((size_t)z*LD + NOFF)*K;
#pragma unroll
  for (int i=0;i<4;++i)
    dz[(size_t)(n0+ty*4+i)*K + k0+tx] = f2bf(tile[tx][ty*4+i]);
}

__global__ void castconv_k(const float* __restrict__ src, unsigned short* __restrict__ dst){
  size_t i = ((size_t)blockIdx.x*256 + threadIdx.x)*4;
  float4 f = *(const float4*)(src+i);
  dst[i+0]=f2bf(f.x); dst[i+1]=f2bf(f.y); dst[i+2]=f2bf(f.z); dst[i+3]=f2bf(f.w);
}

__global__ void biascat_k(const float* __restrict__ bq, const float* __restrict__ bk,
                          const float* __restrict__ bv, float* __restrict__ dst){
  int i = blockIdx.x*256+threadIdx.x;
  int l = i/QKVW, c = i%QKVW;
  float v = (c<768) ? bq[l*768+c] : (c<1536 ? bk[l*768+c-768] : bv[l*768+c-1536]);
  dst[i] = v;
}

// ---------------- patch extraction: x (2,1,128,256,256) f32 -> Xp (4096,4096) bf16
__global__ void patchify_k(const float* __restrict__ x, unsigned short* __restrict__ Xp)
{
  size_t gid = (size_t)blockIdx.x*256 + threadIdx.x;
  size_t oi = gid*4;
  int row = (int)(oi >> 12);
  int c = (int)(oi & 4095);
  int b = row >> 11; int p = row & 2047;
  int pd = p >> 8, ph = (p>>4)&15, pw = p&15;
  int pz = c >> 8, py = (c>>4)&15, px = c&15;
  size_t src = (((size_t)(b*128 + pd*16+pz)*256) + (size_t)(ph*16+py))*256 + (size_t)(pw*16+px);
  float4 f = *(const float4*)(x+src);
  Xp[oi+0]=f2bf(f.x); Xp[oi+1]=f2bf(f.y); Xp[oi+2]=f2bf(f.z); Xp[oi+3]=f2bf(f.w);
}

// ---------------- assemble h = [cls; sum4(P)] + pos, zero pads
__global__ void assemble_k(const float* __restrict__ P, size_t pstride,
                           const float* __restrict__ cls,
                           const float* __restrict__ pos_e, float* __restrict__ H)
{
  int row = blockIdx.x; int t = threadIdx.x;
  float* hr = H + (size_t)row*EMB;
  if (row >= MROWS) { hr[t]=0.f; hr[t+256]=0.f; hr[t+512]=0.f; return; }
  int b = row / SEQ; int pos = row - b*SEQ;
#pragma unroll
  for (int c0=0;c0<3;++c0) {
    int c = t + c0*256;
    float v;
    if (pos==0) v = cls[c];
    else {
      size_t idx = ((size_t)(b*2048 + pos-1))*EMB + c;
      v = P[idx] + P[pstride+idx] + P[2*pstride+idx] + P[3*pstride+idx];
    }
    hr[c] = v + pos_e[(size_t)pos*EMB + c];
  }
}

// ---------------- layernorm row -> bf16 (no reduction input)
__global__ __launch_bounds__(256) void ln_k(const float* __restrict__ H,
    const float* __restrict__ gam, const float* __restrict__ bet,
    unsigned short* __restrict__ Y)
{
  int row = blockIdx.x, t = threadIdx.x;
  const float* hr = H + (size_t)row*EMB;
  float v0 = hr[t], v1 = hr[t+256], v2 = hr[t+512];
  float s = v0+v1+v2;
#pragma unroll
  for (int off=32; off>=1; off>>=1) s += __shfl_down(s, off);
  __shared__ float r1[4], r2[4];
  if ((t&63)==0) r1[t>>6] = s;
  __syncthreads();
  float mean = (r1[0]+r1[1]+r1[2]+r1[3]) * (1.f/768.f);
  float d0=v0-mean, d1=v1-mean, d2=v2-mean;
  float q = d0*d0+d1*d1+d2*d2;
#pragma unroll
  for (int off=32; off>=1; off>>=1) q += __shfl_down(q, off);
  if ((t&63)==0) r2[t>>6] = q;
  __syncthreads();
  float rstd = rsqrtf((r2[0]+r2[1]+r2[2]+r2[3])*(1.f/768.f) + 1e-5f);
  unsigned short* yr = Y + (size_t)row*EMB;
  yr[t]     = f2bf(d0*rstd*gam[t]     + bet[t]);
  yr[t+256] = f2bf(d1*rstd*gam[t+256] + bet[t+256]);
  yr[t+512] = f2bf(d2*rstd*gam[t+512] + bet[t+512]);
}

// ---------------- fused: H += sum_{s<S} P[s]; Y = LN(H)
template<int S>
__global__ __launch_bounds__(256) void ln_red_k(float* __restrict__ H,
    const float* __restrict__ P, size_t pstride,
    const float* __restrict__ gam, const float* __restrict__ bet,
    unsigned short* __restrict__ Y)
{
  int row = blockIdx.x, t = threadIdx.x;
  size_t base = (size_t)row*EMB;
  float v[3];
#pragma unroll
  for (int c0=0;c0<3;++c0) {
    size_t idx = base + t + c0*256;
    float h = H[idx];
#pragma unroll
    for (int s=0;s<S;++s) h += P[(size_t)s*pstride + idx];
    H[idx] = h; v[c0] = h;
  }
  float s = v[0]+v[1]+v[2];
#pragma unroll
  for (int off=32; off>=1; off>>=1) s += __shfl_down(s, off);
  __shared__ float r1[4], r2[4];
  if ((t&63)==0) r1[t>>6] = s;
  __syncthreads();
  float mean = (r1[0]+r1[1]+r1[2]+r1[3]) * (1.f/768.f);
  float d0=v[0]-mean, d1=v[1]-mean, d2=v[2]-mean;
  float q = d0*d0+d1*d1+d2*d2;
#pragma unroll
  for (int off=32; off>=1; off>>=1) q += __shfl_down(q, off);
  if ((t&63)==0) r2[t>>6] = q;
  __syncthreads();
  float rstd = rsqrtf((r2[0]+r2[1]+r2[2]+r2[3])*(1.f/768.f) + 1e-5f);
  unsigned short* yr = Y + base;
  yr[t]     = f2bf(d0*rstd*gam[t]     + bet[t]);
  yr[t+256] = f2bf(d1*rstd*gam[t+256] + bet[t+256]);
  yr[t+512] = f2bf(d2*rstd*gam[t+512] + bet[t+512]);
}

// ---------------- final layernorm on cls rows (with 4-way partial reduce) -> fp32 out
__global__ __launch_bounds__(256) void final_ln_red_k(const float* __restrict__ H,
   const float* __restrict__ P, size_t pstride,
   const float* __restrict__ gam, const float* __restrict__ bet, float* __restrict__ out)
{
  int b = blockIdx.x, t = threadIdx.x;
  size_t base = (size_t)(b*SEQ)*EMB;
  float v[3];
#pragma unroll
  for (int c0=0;c0<3;++c0) {
    size_t idx = base + t + c0*256;
    float h = H[idx];
#pragma unroll
    for (int s=0;s<4;++s) h += P[(size_t)s*pstride + idx];
    v[c0] = h;
  }
  float s = v[0]+v[1]+v[2];
#pragma unroll
  for (int off=32; off>=1; off>>=1) s += __shfl_down(s, off);
  __shared__ float r1[4], r2[4];
  if ((t&63)==0) r1[t>>6] = s;
  __syncthreads();
  float mean = (r1[0]+r1[1]+r1[2]+r1[3]) * (1.f/768.f);
  float d0=v[0]-mean, d1=v[1]-mean, d2=v[2]-mean;
  float q = d0*d0+d1*d1+d2*d2;
#pragma unroll
  for (int off=32; off>=1; off>>=1) q += __shfl_down(q, off);
  if ((t&63)==0) r2[t>>6] = q;
  __syncthreads();
  float rstd = rsqrtf((r2[0]+r2[1]+r2[2]+r2[3])*(1.f/768.f) + 1e-5f);
  out[b*EMB + t]     = d0*rstd*gam[t]     + bet[t];
  out[b*EMB + t+256] = d1*rstd*gam[t+256] + bet[t+256];
  out[b*EMB + t+512] = d2*rstd*gam[t+512] + bet[t+512];
}

// ---------------- GEMM: A(MxK) bf16 row-major, Bt(NxK) bf16, 128x128 tile
// MODE 0: bf16 out +bias; 1: bf16 out +bias+gelu; 3: f32 split-partial write
template<int MODE, int NSPLIT>
__global__ __launch_bounds__(256) void gemm_k(
    const unsigned short* __restrict__ A,
    const unsigned short* __restrict__ Bt,
    const float* __restrict__ bias,
    unsigned short* __restrict__ Cb,
    float* __restrict__ Cf,
    int K, int ldc, size_t splitStride)
{
  __shared__ __attribute__((aligned(16))) unsigned short lA[128*32];
  __shared__ __attribute__((aligned(16))) unsigned short lB[128*32];
  const int tid = threadIdx.x;
  const int w = tid>>6, lane = tid&63, g = lane>>4, l16 = lane&15;
  const int lr = lane>>2, lc = (lane&3)*8;
  // bijective XCD-chunked swizzle (m204): consecutive new-ids on one XCD
  const int nwg = gridDim.x*gridDim.y;
  const int id = blockIdx.y*gridDim.x + blockIdx.x;
  const int q = nwg>>3, r = nwg&7, xc = id&7, si = id>>3;
  const int nid = (xc<r ? xc*(q+1) : r*(q+1)+(xc-r)*q) + si;
  const int tm = nid / gridDim.x;
  const int tn = nid - tm*gridDim.x;
  const int kchunk = K / NSPLIT;
  const int kofs = (NSPLIT>1) ? blockIdx.z * kchunk : 0;
  const unsigned short* Ab = A + (size_t)tm*128*K + kofs;
  const unsigned short* Bb = Bt + (size_t)tn*128*K + kofs;
  const int wm = (w>>1)*64, wn = (w&1)*64;
  f4 acc[4][4] = {};
  const int nkt = kchunk>>5;
  for (int kt=0; kt<nkt; ++kt) {
    __syncthreads();
    const size_t ko = (size_t)(kt*32 + lc);
    gl_lds16(Ab + (size_t)(w*16 + lr)*K + ko,     ((char*)lA) + w*1024);
    gl_lds16(Ab + (size_t)((w+4)*16 + lr)*K + ko, ((char*)lA) + (w+4)*1024);
    gl_lds16(Bb + (size_t)(w*16 + lr)*K + ko,     ((char*)lB) + w*1024);
    gl_lds16(Bb + (size_t)((w+4)*16 + lr)*K + ko, ((char*)lB) + (w+4)*1024);
    __syncthreads();
    bs8 af[4], bf[4];
#pragma unroll
    for (int mi=0;mi<4;++mi) af[mi] = *(const bs8*)(lA + (wm+mi*16+l16)*32 + g*8);
#pragma unroll
    for (int ni=0;ni<4;++ni) bf[ni] = *(const bs8*)(lB + (wn+ni*16+l16)*32 + g*8);
#pragma unroll
    for (int mi=0;mi<4;++mi)
#pragma unroll
      for (int ni=0;ni<4;++ni)
        acc[mi][ni] = __builtin_amdgcn_mfma_f32_16x16x32_bf16(af[mi], bf[ni], acc[mi][ni], 0,0,0);
  }
  const float bscale = (NSPLIT==1 || blockIdx.z==0) ? 1.f : 0.f;
#pragma unroll
  for (int mi=0;mi<4;++mi)
#pragma unroll
    for (int ni=0;ni<4;++ni) {
      int col = tn*128 + wn + ni*16 + l16;
      float bv = bias[col]*bscale;
#pragma unroll
      for (int r0=0;r0<4;++r0) {
        int row = tm*128 + wm + mi*16 + g*4 + r0;
        float val = acc[mi][ni][r0] + bv;
        if (MODE==1) val = 0.5f*val*(1.f+erff(val*0.70710678f));
        if (MODE<=1) Cb[(size_t)row*ldc + col] = f2bf(val);
        else Cf[(size_t)blockIdx.z*splitStride + (size_t)row*ldc + col] = val;
      }
    }
}

// ---------------- fused dilated attention, all 3 branches, online-flash
__global__ __launch_bounds__(256) void attn_all_k(
    const unsigned short* __restrict__ qkv,
    unsigned short* __restrict__ O1, float* __restrict__ L1,
    unsigned short* __restrict__ O2, float* __restrict__ L2,
    unsigned short* __restrict__ O3, float* __restrict__ L3)
{
  __shared__ __attribute__((aligned(16))) unsigned short lK[128*72];    // [key][72]
  __shared__ __attribute__((aligned(16))) unsigned short lVt[64*136];   // [d][136]
  __shared__ __attribute__((aligned(16))) unsigned short Pl[4][16][136];
  const int tid = threadIdx.x;
  const int w = tid>>6, lane = tid&63, g = lane>>4, l16 = lane&15;

  int id = blockIdx.x;
  int R, WSZ, NSEG; unsigned short* OB; float* LB;
  if (id < 960)       { R=1; WSZ=512;  NSEG=5; OB=O1; LB=L1; }
  else if (id < 1536) { id -= 960;  R=2; WSZ=1024; NSEG=3; OB=O2; LB=L2; }
  else                { id -= 1536; R=4; WSZ=2048; NSEG=2; OB=O3; LB=L3; }
  const int qt = id & 7; int rest = id >> 3;
  const int seg = rest % NSEG; const int bh = rest / NSEG;
  const int b = bh / NHEADS, hd = bh % NHEADS;
  const int hr = hd % R;
  const int j0 = qt*64 + w*16;
  const int kbase = seg*WSZ + hr;
  const unsigned short* qkvb = qkv + (size_t)b*SEQ*QKVW;

  bs8 z = {0,0,0,0,0,0,0,0};
  bs8 qf0 = z, qf1 = z;
  {
    int qpos = kbase + (j0 + l16)*R;
    if (qpos < SEQ) {
      const unsigned short* qrow = qkvb + (size_t)qpos*QKVW + hd*64 + g*8;
      qf0 = *(const bs8*)(qrow);
      qf1 = *(const bs8*)(qrow + 32);
    }
  }

  float rm[4], rs[4];
  f4 oacc[4] = {};
#pragma unroll
  for (int r=0;r<4;++r) { rm[r] = NEGV; rs[r] = 0.f; }

  for (int c=0; c<4; ++c) {
    __syncthreads();
#pragma unroll
    for (int it=0; it<4; ++it) {
      int idx = tid + it*256;
      int kk = idx >> 3, dblk = idx & 7;
      int kpos = kbase + (c*128 + kk)*R;
      bs8 kv = z;
      if (kpos < SEQ) kv = *(const bs8*)(qkvb + (size_t)kpos*QKVW + EMB + hd*64 + dblk*8);
      *(bs8*)(lK + kk*72 + dblk*8) = kv;
    }
#pragma unroll
    for (int it=0; it<4; ++it) {
      int idx = tid + it*256;
      int kk = idx & 127, dblk = idx >> 7;
      int kpos = kbase + (c*128 + kk)*R;
      unsigned short tv[8] = {0,0,0,0,0,0,0,0};
      if (kpos < SEQ)
        *(bs8*)tv = *(const bs8*)(qkvb + (size_t)kpos*QKVW + 1536 + hd*64 + dblk*8);
#pragma unroll
      for (int ii=0; ii<8; ++ii) lVt[(dblk*8+ii)*136 + kk] = tv[ii];
    }
    __syncthreads();

    f4 sc[8];
#pragma unroll
    for (int kt=0; kt<8; ++kt) {
      int key = kt*16 + l16;
      bs8 kf0 = *(const bs8*)(lK + key*72 + g*8);
      bs8 kf1 = *(const bs8*)(lK + key*72 + 32 + g*8);
      f4 acc = {0.f,0.f,0.f,0.f};
      acc = __builtin_amdgcn_mfma_f32_16x16x32_bf16(qf0, kf0, acc, 0,0,0);
      acc = __builtin_amdgcn_mfma_f32_16x16x32_bf16(qf1, kf1, acc, 0,0,0);
      int kpos = kbase + (c*128 + key)*R;
      bool kvld = (kpos < SEQ);
#pragma unroll
      for (int r=0;r<4;++r) sc[kt][r] = kvld ? acc[r]*0.125f : NEGV;
    }
    float scl[4];
#pragma unroll
    for (int r=0;r<4;++r) {
      float mx = sc[0][r];
#pragma unroll
      for (int kt=1;kt<8;++kt) mx = fmaxf(mx, sc[kt][r]);
      mx = fmaxf(mx, __shfl_xor(mx, 1));
      mx = fmaxf(mx, __shfl_xor(mx, 2));
      mx = fmaxf(mx, __shfl_xor(mx, 4));
      mx = fmaxf(mx, __shfl_xor(mx, 8));
      float mn = fmaxf(rm[r], mx);
      scl[r] = __expf(rm[r] - mn);
      rm[r] = mn;
    }
#pragma unroll
    for (int r=0;r<4;++r) {
      float sm = 0.f;
#pragma unroll
      for (int kt=0;kt<8;++kt) { float p = __expf(sc[kt][r] - rm[r]); sc[kt][r] = p; sm += p; }
      sm += __shfl_xor(sm, 1); sm += __shfl_xor(sm, 2);
      sm += __shfl_xor(sm, 4); sm += __shfl_xor(sm, 8);
      rs[r] = rs[r]*scl[r] + sm;
    }
#pragma unroll
    for (int dt=0; dt<4; ++dt)
#pragma unroll
      for (int r=0;r<4;++r) oacc[dt][r] *= scl[r];
#pragma unroll
    for (int kt=0;kt<8;++kt)
#pragma unroll
      for (int r=0;r<4;++r)
        Pl[w][g*4+r][kt*16+l16] = f2bf(sc[kt][r]);
#pragma unroll
    for (int ks=0; ks<4; ++ks) {
      bs8 pa = *(const bs8*)(&Pl[w][l16][ks*32 + g*8]);
#pragma unroll
      for (int dt=0; dt<4; ++dt) {
        bs8 vb = *(const bs8*)(lVt + (dt*16+l16)*136 + ks*32 + g*8);
        oacc[dt] = __builtin_amdgcn_mfma_f32_16x16x32_bf16(pa, vb, oacc[dt], 0,0,0);
      }
    }
  }

  size_t obase = ((size_t)(b*NSEG + seg)*NHEADS + hd)*512;
#pragma unroll
  for (int dt=0; dt<4; ++dt)
#pragma unroll
    for (int r=0;r<4;++r) {
      int j = j0 + g*4 + r;
      OB[(obase + j)*64 + dt*16 + l16] = f2bf(oacc[dt][r] / rs[r]);
    }
  if (l16 == 0) {
#pragma unroll
    for (int r=0;r<4;++r) LB[obase + j0 + g*4 + r] = rm[r] + __logf(rs[r]);
  }
}

// ---------------- combine 3 branches via lse softmax -> attn bf16 (MPAD,768)
__global__ __launch_bounds__(256) void attn_combine_k(
   const unsigned short* __restrict__ o1, const float* __restrict__ l1,
   const unsigned short* __restrict__ o2, const float* __restrict__ l2,
   const unsigned short* __restrict__ o3, const float* __restrict__ l3,
   unsigned short* __restrict__ attn)
{
  int row = blockIdx.x; int t = threadIdx.x;
  unsigned short* arow = attn + (size_t)row*EMB;
  if (row >= MROWS) { arow[t]=0; arow[t+256]=0; arow[t+512]=0; return; }
  int b = row / SEQ, pos = row - (row/SEQ)*SEQ;
#pragma unroll
  for (int c0=0; c0<3; ++c0) {
    int cc = t + c0*256;
    int hd = cc >> 6, d = cc & 63;
    float L0,L1v,L2v,O0,O1v,O2v;
    {
      int seg = pos >> 9; int j = pos & 511;
      size_t base = ((size_t)(b*5 + seg)*NHEADS + hd)*512 + j;
      L0 = l1[base]; O0 = bf2f(o1[base*64 + d]);
    }
    if ((pos & 1) == (hd & 1)) {
      int seg = pos >> 10; int j = ((pos & 1023) - (hd&1)) >> 1;
      size_t base = ((size_t)(b*3 + seg)*NHEADS + hd)*512 + j;
      L1v = l2[base]; O1v = bf2f(o2[base*64 + d]);
    } else { L1v = NEGV; O1v = 0.f; }
    if ((pos & 3) == (hd & 3)) {
      int seg = pos >> 11; int j = ((pos & 2047) - (hd&3)) >> 2;
      size_t base = ((size_t)(b*2 + seg)*NHEADS + hd)*512 + j;
      L2v = l3[base]; O2v = bf2f(o3[base*64 + d]);
    } else { L2v = NEGV; O2v = 0.f; }
    float m = fmaxf(L0, fmaxf(L1v, L2v));
    float e0 = __expf(L0-m), e1 = __expf(L1v-m), e2 = __expf(L2v-m);
    float inv = 1.f/(e0+e1+e2);
    arow[cc] = f2bf((e0*O0+e1*O1v+e2*O2v)*inv);
  }
}

extern "C" void kernel_launch(void* const* d_in, const int* in_sizes, int n_in,
                              void* d_out, int out_size, void* d_ws, size_t ws_size,
                              hipStream_t stream) {
  const float* x       = (const float*)d_in[0];
  const float* conv_w  = (const float*)d_in[1];
  const float* conv_b  = (const float*)d_in[2];
  const float* cls     = (const float*)d_in[3];
  const float* pos_e   = (const float*)d_in[4];
  const float* ln1_g   = (const float*)d_in[5];
  const float* ln1_b   = (const float*)d_in[6];
  const float* wq      = (const float*)d_in[7];
  const float* bq      = (const float*)d_in[8];
  const float* wk      = (const float*)d_in[9];
  const float* bk      = (const float*)d_in[10];
  const float* wv      = (const float*)d_in[11];
  const float* bv      = (const float*)d_in[12];
  const float* wo      = (const float*)d_in[13];
  const float* bo      = (const float*)d_in[14];
  const float* ln2_g   = (const float*)d_in[15];
  const float* ln2_b   = (const float*)d_in[16];
  const float* w1      = (const float*)d_in[17];
  const float* b1      = (const float*)d_in[18];
  const float* w2      = (const float*)d_in[19];
  const float* b2      = (const float*)d_in[20];
  const float* nf_g    = (const float*)d_in[21];
  const float* nf_b    = (const float*)d_in[22];

  char* ws = (char*)d_ws;
  size_t off = 0;
  auto alloc = [&](size_t bytes)->char* {
    char* p = ws + off; off += (bytes + 255) & ~(size_t)255; return p;
  };
  unsigned short* wqkv_t = (unsigned short*)alloc((size_t)12*2304*768*2);
  unsigned short* wo_t   = (unsigned short*)alloc((size_t)12*768*768*2);
  unsigned short* w1_t   = (unsigned short*)alloc((size_t)12*3072*768*2);
  unsigned short* w2_t   = (unsigned short*)alloc((size_t)12*768*3072*2);
  unsigned short* cw_b   = (unsigned short*)alloc((size_t)768*4096*2);
  float* bqkv            = (float*)alloc((size_t)12*2304*4);
  unsigned short* Xp     = (unsigned short*)alloc((size_t)4096*4096*2);
  float* H               = (float*)alloc((size_t)MPAD*768*4);
  float* P               = (float*)alloc((size_t)4*MPAD*768*4);
  unsigned short* Y      = (unsigned short*)alloc((size_t)MPAD*768*2);
  unsigned short* QKV    = (unsigned short*)alloc((size_t)MPAD*2304*2);
  unsigned short* ATT    = (unsigned short*)alloc((size_t)MPAD*768*2);
  unsigned short* Y2     = (unsigned short*)alloc((size_t)MPAD*3072*2);
  unsigned short* O1 = (unsigned short*)alloc((size_t)2*5*12*512*64*2);
  unsigned short* O2 = (unsigned short*)alloc((size_t)2*3*12*512*64*2);
  unsigned short* O3 = (unsigned short*)alloc((size_t)2*2*12*512*64*2);
  float* L1 = (float*)alloc((size_t)2*5*12*512*4);
  float* L2 = (float*)alloc((size_t)2*3*12*512*4);
  float* L3 = (float*)alloc((size_t)2*2*12*512*4);
  const size_t PSTR = (size_t)MPAD*768;

  dim3 tb(32,8);
  wtr_k<<<dim3(24,24,12), tb, 0, stream>>>(wq, wqkv_t, 768, 768, 2304, 0);
  wtr_k<<<dim3(24,24,12), tb, 0, stream>>>(wk, wqkv_t, 768, 768, 2304, 768);
  wtr_k<<<dim3(24,24,12), tb, 0, stream>>>(wv, wqkv_t, 768, 768, 2304, 1536);
  wtr_k<<<dim3(24,24,12), tb, 0, stream>>>(wo, wo_t, 768, 768, 768, 0);
  wtr_k<<<dim3(24,96,12), tb, 0, stream>>>(w1, w1_t, 768, 3072, 3072, 0);
  wtr_k<<<dim3(96,24,12), tb, 0, stream>>>(w2, w2_t, 3072, 768, 768, 0);
  castconv_k<<<3072,256,0,stream>>>(conv_w, cw_b);
  biascat_k<<<108,256,0,stream>>>(bq,bk,bv,bqkv);
  patchify_k<<<16384,256,0,stream>>>(x, Xp);
  gemm_k<3,4><<<dim3(6,32,4),256,0,stream>>>(Xp, cw_b, conv_b, nullptr, P, 4096, 768, PSTR);
  assemble_k<<<MPAD,256,0,stream>>>(P, PSTR, cls, pos_e, H);

  for (int l=0;l<12;++l) {
    if (l==0) ln_k<<<MPAD,256,0,stream>>>(H, ln1_g, ln1_b, Y);
    else ln_red_k<4><<<MPAD,256,0,stream>>>(H, P, PSTR, ln1_g + l*768, ln1_b + l*768, Y);
    gemm_k<0,1><<<dim3(18,33),256,0,stream>>>(Y, wqkv_t + (size_t)l*2304*768, bqkv + l*2304, QKV, nullptr, 768, 2304, 0);
    attn_all_k<<<1920,256,0,stream>>>(QKV, O1,L1,O2,L2,O3,L3);
    attn_combine_k<<<MPAD,256,0,stream>>>(O1,L1,O2,L2,O3,L3, ATT);
    gemm_k<3,2><<<dim3(6,33,2),256,0,stream>>>(ATT, wo_t + (size_t)l*768*768, bo + l*768, nullptr, P, 768, 768, PSTR);
    ln_red_k<2><<<MPAD,256,0,stream>>>(H, P, PSTR, ln2_g + l*768, ln2_b + l*768, Y);
    gemm_k<1,1><<<dim3(24,33),256,0,stream>>>(Y, w1_t + (size_t)l*3072*768, b1 + l*3072, Y2, nullptr, 768, 3072, 0);
    gemm_k<3,4><<<dim3(6,33,4),256,0,stream>>>(Y2, w2_t + (size_t)l*768*3072, b2 + l*768, nullptr, P, 3072, 768, PSTR);
  }
  final_ln_red_k<<<2,256,0,stream>>>(H, P, PSTR, nf_g, nf_b, (float*)d_out);
}

// Round 4
// 3062.920 us; speedup vs baseline: 1.7325x; 1.0490x over previous
//
#include <hip/hip_runtime.h>
#include <math.h>

#define SEQ 2049
#define EMB 768
#define NHEADS 12
#define QKVW 2304
#define MROWS 4098
#define MPAD 4224
#define NEGV -1000000000.0f

typedef short bs8 __attribute__((ext_vector_type(8)));
typedef float f4 __attribute__((ext_vector_type(4)));

__device__ __forceinline__ unsigned short f2bf(float f){
  union { float f; unsigned u; } x; x.f = f;
  unsigned r = x.u + 0x7fffu + ((x.u >> 16) & 1u);
  return (unsigned short)(r >> 16);
}
__device__ __forceinline__ float bf2f(unsigned short u){
  union { unsigned u; float f; } x; x.u = ((unsigned)u) << 16; return x.f;
}

__device__ __forceinline__ void gl_lds16(const void* g, void* l){
  __builtin_amdgcn_global_load_lds((const __attribute__((address_space(1))) void*)g,
                                   (__attribute__((address_space(3))) void*)l, 16, 0, 0);
}

// ---------------- weight transpose fp32 (L,K,N) -> bf16 dst[(l*LD+NOFF+n)*K+k]
__global__ void wtr_k(const float* __restrict__ src, unsigned short* __restrict__ dst,
                      int K, int N, int LD, int NOFF)
{
  __shared__ float tile[32][33];
  int k0 = blockIdx.x*32, n0 = blockIdx.y*32, z = blockIdx.z;
  int tx = threadIdx.x, ty = threadIdx.y;
  const float* s = src + (size_t)z*K*N;
#pragma unroll
  for (int i=0;i<4;++i)
    tile[ty*4+i][tx] = s[(size_t)(k0+ty*4+i)*N + n0+tx];
  __syncthreads();
  unsigned short* dz = dst + ((size_t)z*LD + NOFF)*K;
#pragma unroll
  for (int i=0;i<4;++i)
    dz[(size_t)(n0+ty*4+i)*K + k0+tx] = f2bf(tile[tx][ty*4+i]);
}

__global__ void castconv_k(const float* __restrict__ src, unsigned short* __restrict__ dst){
  size_t i = ((size_t)blockIdx.x*256 + threadIdx.x)*4;
  float4 f = *(const float4*)(src+i);
  dst[i+0]=f2bf(f.x); dst[i+1]=f2bf(f.y); dst[i+2]=f2bf(f.z); dst[i+3]=f2bf(f.w);
}

__global__ void biascat_k(const float* __restrict__ bq, const float* __restrict__ bk,
                          const float* __restrict__ bv, float* __restrict__ dst){
  int i = blockIdx.x*256+threadIdx.x;
  int l = i/QKVW, c = i%QKVW;
  float v = (c<768) ? bq[l*768+c] : (c<1536 ? bk[l*768+c-768] : bv[l*768+c-1536]);
  dst[i] = v;
}

// ---------------- patch extraction: x (2,1,128,256,256) f32 -> Xp (4096,4096) bf16
__global__ void patchify_k(const float* __restrict__ x, unsigned short* __restrict__ Xp)
{
  size_t gid = (size_t)blockIdx.x*256 + threadIdx.x;
  size_t oi = gid*4;
  int row = (int)(oi >> 12);
  int c = (int)(oi & 4095);
  int b = row >> 11; int p = row & 2047;
  int pd = p >> 8, ph = (p>>4)&15, pw = p&15;
  int pz = c >> 8, py = (c>>4)&15, px = c&15;
  size_t src = (((size_t)(b*128 + pd*16+pz)*256) + (size_t)(ph*16+py))*256 + (size_t)(pw*16+px);
  float4 f = *(const float4*)(x+src);
  Xp[oi+0]=f2bf(f.x); Xp[oi+1]=f2bf(f.y); Xp[oi+2]=f2bf(f.z); Xp[oi+3]=f2bf(f.w);
}

// ---------------- assemble h = [cls; sum4(P)] + pos, zero pads
__global__ void assemble_k(const float* __restrict__ P, size_t pstride,
                           const float* __restrict__ cls,
                           const float* __restrict__ pos_e, float* __restrict__ H)
{
  int row = blockIdx.x; int t = threadIdx.x;
  float* hr = H + (size_t)row*EMB;
  if (row >= MROWS) { hr[t]=0.f; hr[t+256]=0.f; hr[t+512]=0.f; return; }
  int b = row / SEQ; int pos = row - b*SEQ;
#pragma unroll
  for (int c0=0;c0<3;++c0) {
    int c = t + c0*256;
    float v;
    if (pos==0) v = cls[c];
    else {
      size_t idx = ((size_t)(b*2048 + pos-1))*EMB + c;
      v = P[idx] + P[pstride+idx] + P[2*pstride+idx] + P[3*pstride+idx];
    }
    hr[c] = v + pos_e[(size_t)pos*EMB + c];
  }
}

// ---------------- layernorm row -> bf16 (no reduction input)
__global__ __launch_bounds__(256) void ln_k(const float* __restrict__ H,
    const float* __restrict__ gam, const float* __restrict__ bet,
    unsigned short* __restrict__ Y)
{
  int row = blockIdx.x, t = threadIdx.x;
  const float* hr = H + (size_t)row*EMB;
  float v0 = hr[t], v1 = hr[t+256], v2 = hr[t+512];
  float s = v0+v1+v2;
#pragma unroll
  for (int off=32; off>=1; off>>=1) s += __shfl_down(s, off);
  __shared__ float r1[4], r2[4];
  if ((t&63)==0) r1[t>>6] = s;
  __syncthreads();
  float mean = (r1[0]+r1[1]+r1[2]+r1[3]) * (1.f/768.f);
  float d0=v0-mean, d1=v1-mean, d2=v2-mean;
  float q = d0*d0+d1*d1+d2*d2;
#pragma unroll
  for (int off=32; off>=1; off>>=1) q += __shfl_down(q, off);
  if ((t&63)==0) r2[t>>6] = q;
  __syncthreads();
  float rstd = rsqrtf((r2[0]+r2[1]+r2[2]+r2[3])*(1.f/768.f) + 1e-5f);
  unsigned short* yr = Y + (size_t)row*EMB;
  yr[t]     = f2bf(d0*rstd*gam[t]     + bet[t]);
  yr[t+256] = f2bf(d1*rstd*gam[t+256] + bet[t+256]);
  yr[t+512] = f2bf(d2*rstd*gam[t+512] + bet[t+512]);
}

// ---------------- fused: H += sum_{s<S} P[s]; Y = LN(H)
template<int S>
__global__ __launch_bounds__(256) void ln_red_k(float* __restrict__ H,
    const float* __restrict__ P, size_t pstride,
    const float* __restrict__ gam, const float* __restrict__ bet,
    unsigned short* __restrict__ Y)
{
  int row = blockIdx.x, t = threadIdx.x;
  size_t base = (size_t)row*EMB;
  float v[3];
#pragma unroll
  for (int c0=0;c0<3;++c0) {
    size_t idx = base + t + c0*256;
    float h = H[idx];
#pragma unroll
    for (int s=0;s<S;++s) h += P[(size_t)s*pstride + idx];
    H[idx] = h; v[c0] = h;
  }
  float s = v[0]+v[1]+v[2];
#pragma unroll
  for (int off=32; off>=1; off>>=1) s += __shfl_down(s, off);
  __shared__ float r1[4], r2[4];
  if ((t&63)==0) r1[t>>6] = s;
  __syncthreads();
  float mean = (r1[0]+r1[1]+r1[2]+r1[3]) * (1.f/768.f);
  float d0=v[0]-mean, d1=v[1]-mean, d2=v[2]-mean;
  float q = d0*d0+d1*d1+d2*d2;
#pragma unroll
  for (int off=32; off>=1; off>>=1) q += __shfl_down(q, off);
  if ((t&63)==0) r2[t>>6] = q;
  __syncthreads();
  float rstd = rsqrtf((r2[0]+r2[1]+r2[2]+r2[3])*(1.f/768.f) + 1e-5f);
  unsigned short* yr = Y + base;
  yr[t]     = f2bf(d0*rstd*gam[t]     + bet[t]);
  yr[t+256] = f2bf(d1*rstd*gam[t+256] + bet[t+256]);
  yr[t+512] = f2bf(d2*rstd*gam[t+512] + bet[t+512]);
}

// ---------------- final layernorm on cls rows (with 4-way partial reduce) -> fp32 out
__global__ __launch_bounds__(256) void final_ln_red_k(const float* __restrict__ H,
   const float* __restrict__ P, size_t pstride,
   const float* __restrict__ gam, const float* __restrict__ bet, float* __restrict__ out)
{
  int b = blockIdx.x, t = threadIdx.x;
  size_t base = (size_t)(b*SEQ)*EMB;
  float v[3];
#pragma unroll
  for (int c0=0;c0<3;++c0) {
    size_t idx = base + t + c0*256;
    float h = H[idx];
#pragma unroll
    for (int s=0;s<4;++s) h += P[(size_t)s*pstride + idx];
    v[c0] = h;
  }
  float s = v[0]+v[1]+v[2];
#pragma unroll
  for (int off=32; off>=1; off>>=1) s += __shfl_down(s, off);
  __shared__ float r1[4], r2[4];
  if ((t&63)==0) r1[t>>6] = s;
  __syncthreads();
  float mean = (r1[0]+r1[1]+r1[2]+r1[3]) * (1.f/768.f);
  float d0=v[0]-mean, d1=v[1]-mean, d2=v[2]-mean;
  float q = d0*d0+d1*d1+d2*d2;
#pragma unroll
  for (int off=32; off>=1; off>>=1) q += __shfl_down(q, off);
  if ((t&63)==0) r2[t>>6] = q;
  __syncthreads();
  float rstd = rsqrtf((r2[0]+r2[1]+r2[2]+r2[3])*(1.f/768.f) + 1e-5f);
  out[b*EMB + t]     = d0*rstd*gam[t]     + bet[t];
  out[b*EMB + t+256] = d1*rstd*gam[t+256] + bet[t+256];
  out[b*EMB + t+512] = d2*rstd*gam[t+512] + bet[t+512];
}

// ---------------- GEMM: A(MxK) bf16 row-major, Bt(NxK) bf16, 128x128 tile
// 2-phase double-buffered K-loop, counted vmcnt, raw barriers, XOR-swizzled LDS.
// MODE 0: bf16 out +bias; 1: bf16 out +bias+gelu; 3: f32 split-partial write
template<int MODE, int NSPLIT>
__global__ __launch_bounds__(256) void gemm_k(
    const unsigned short* __restrict__ A,
    const unsigned short* __restrict__ Bt,
    const float* __restrict__ bias,
    unsigned short* __restrict__ Cb,
    float* __restrict__ Cf,
    int K, int ldc, size_t splitStride)
{
  __shared__ __attribute__((aligned(16))) unsigned short lA[2][128*32];
  __shared__ __attribute__((aligned(16))) unsigned short lB[2][128*32];
  const int tid = threadIdx.x;
  const int w = tid>>6, lane = tid&63, g = lane>>4, l16 = lane&15;
  const int lr = lane>>2;
  // swizzled source column-group: cg_phys holds global cg ^ ((row>>1)&3)
  const int lcs = (((lane&3) ^ ((lane>>3)&3)))*8;
  // swizzled read offset (constant per lane)
  const int swz = ((g ^ ((l16>>1)&3)))*8;
  // bijective XCD-chunked swizzle (m204)
  const int nwg = gridDim.x*gridDim.y;
  const int id = blockIdx.y*gridDim.x + blockIdx.x;
  const int q = nwg>>3, r = nwg&7, xc = id&7, si = id>>3;
  const int nid = (xc<r ? xc*(q+1) : r*(q+1)+(xc-r)*q) + si;
  const int tm = nid / gridDim.x;
  const int tn = nid - tm*gridDim.x;
  const int kchunk = K / NSPLIT;
  const int kofs = (NSPLIT>1) ? blockIdx.z * kchunk : 0;
  const unsigned short* Ab = A + (size_t)tm*128*K + kofs;
  const unsigned short* Bb = Bt + (size_t)tn*128*K + kofs;
  const int wm = (w>>1)*64, wn = (w&1)*64;
  f4 acc[4][4] = {};
  const int nkt = kchunk>>5;

  auto STAGE = [&](int buf, int kt){
    const size_t ko = (size_t)(kt*32 + lcs);
    gl_lds16(Ab + (size_t)(w*16 + lr)*K + ko,     ((char*)lA[buf]) + w*1024);
    gl_lds16(Ab + (size_t)((w+4)*16 + lr)*K + ko, ((char*)lA[buf]) + (w+4)*1024);
    gl_lds16(Bb + (size_t)(w*16 + lr)*K + ko,     ((char*)lB[buf]) + w*1024);
    gl_lds16(Bb + (size_t)((w+4)*16 + lr)*K + ko, ((char*)lB[buf]) + (w+4)*1024);
  };

  STAGE(0, 0);
  int cur = 0;
  for (int kt=0; kt<nkt; ++kt) {
    if (kt+1 < nkt) {
      STAGE(cur^1, kt+1);
      asm volatile("s_waitcnt vmcnt(4)" ::: "memory");
    } else {
      asm volatile("s_waitcnt vmcnt(0)" ::: "memory");
    }
    __builtin_amdgcn_sched_barrier(0);
    __builtin_amdgcn_s_barrier();          // buf[cur] ready for all waves
    bs8 af[4], bf[4];
#pragma unroll
    for (int mi=0;mi<4;++mi) af[mi] = *(const bs8*)(lA[cur] + (wm+mi*16+l16)*32 + swz);
#pragma unroll
    for (int ni=0;ni<4;++ni) bf[ni] = *(const bs8*)(lB[cur] + (wn+ni*16+l16)*32 + swz);
    asm volatile("s_waitcnt lgkmcnt(0)" ::: "memory");
    __builtin_amdgcn_sched_barrier(0);
    __builtin_amdgcn_s_barrier();          // all reads of buf[cur] done -> free
#pragma unroll
    for (int mi=0;mi<4;++mi)
#pragma unroll
      for (int ni=0;ni<4;++ni)
        acc[mi][ni] = __builtin_amdgcn_mfma_f32_16x16x32_bf16(af[mi], bf[ni], acc[mi][ni], 0,0,0);
    cur ^= 1;
  }
  const float bscale = (NSPLIT==1 || blockIdx.z==0) ? 1.f : 0.f;
#pragma unroll
  for (int mi=0;mi<4;++mi)
#pragma unroll
    for (int ni=0;ni<4;++ni) {
      int col = tn*128 + wn + ni*16 + l16;
      float bv = bias[col]*bscale;
#pragma unroll
      for (int r0=0;r0<4;++r0) {
        int row = tm*128 + wm + mi*16 + g*4 + r0;
        float val = acc[mi][ni][r0] + bv;
        if (MODE==1) val = 0.5f*val*(1.f+erff(val*0.70710678f));
        if (MODE<=1) Cb[(size_t)row*ldc + col] = f2bf(val);
        else Cf[(size_t)blockIdx.z*splitStride + (size_t)row*ldc + col] = val;
      }
    }
}

// ---------------- fused dilated attention, all 3 branches, online-flash
__global__ __launch_bounds__(256) void attn_all_k(
    const unsigned short* __restrict__ qkv,
    unsigned short* __restrict__ O1, float* __restrict__ L1,
    unsigned short* __restrict__ O2, float* __restrict__ L2,
    unsigned short* __restrict__ O3, float* __restrict__ L3)
{
  __shared__ __attribute__((aligned(16))) unsigned short lK[128*72];    // [key][72]
  __shared__ __attribute__((aligned(16))) unsigned short lVt[64*136];   // [d][136]
  __shared__ __attribute__((aligned(16))) unsigned short Pl[4][16][136];
  const int tid = threadIdx.x;
  const int w = tid>>6, lane = tid&63, g = lane>>4, l16 = lane&15;

  int id = blockIdx.x;
  int R, WSZ, NSEG; unsigned short* OB; float* LB;
  if (id < 960)       { R=1; WSZ=512;  NSEG=5; OB=O1; LB=L1; }
  else if (id < 1536) { id -= 960;  R=2; WSZ=1024; NSEG=3; OB=O2; LB=L2; }
  else                { id -= 1536; R=4; WSZ=2048; NSEG=2; OB=O3; LB=L3; }
  const int qt = id & 7; int rest = id >> 3;
  const int seg = rest % NSEG; const int bh = rest / NSEG;
  const int b = bh / NHEADS, hd = bh % NHEADS;
  const int hr = hd % R;
  const int j0 = qt*64 + w*16;
  const int kbase = seg*WSZ + hr;
  const unsigned short* qkvb = qkv + (size_t)b*SEQ*QKVW;

  bs8 z = {0,0,0,0,0,0,0,0};
  bs8 qf0 = z, qf1 = z;
  {
    int qpos = kbase + (j0 + l16)*R;
    if (qpos < SEQ) {
      const unsigned short* qrow = qkvb + (size_t)qpos*QKVW + hd*64 + g*8;
      qf0 = *(const bs8*)(qrow);
      qf1 = *(const bs8*)(qrow + 32);
    }
  }

  float rm[4], rs[4];
  f4 oacc[4] = {};
#pragma unroll
  for (int r=0;r<4;++r) { rm[r] = NEGV; rs[r] = 0.f; }

  for (int c=0; c<4; ++c) {
    __syncthreads();
#pragma unroll
    for (int it=0; it<4; ++it) {
      int idx = tid + it*256;
      int kk = idx >> 3, dblk = idx & 7;
      int kpos = kbase + (c*128 + kk)*R;
      bs8 kv = z;
      if (kpos < SEQ) kv = *(const bs8*)(qkvb + (size_t)kpos*QKVW + EMB + hd*64 + dblk*8);
      *(bs8*)(lK + kk*72 + dblk*8) = kv;
    }
#pragma unroll
    for (int it=0; it<4; ++it) {
      int idx = tid + it*256;
      int kk = idx & 127, dblk = idx >> 7;
      int kpos = kbase + (c*128 + kk)*R;
      unsigned short tv[8] = {0,0,0,0,0,0,0,0};
      if (kpos < SEQ)
        *(bs8*)tv = *(const bs8*)(qkvb + (size_t)kpos*QKVW + 1536 + hd*64 + dblk*8);
#pragma unroll
      for (int ii=0; ii<8; ++ii) lVt[(dblk*8+ii)*136 + kk] = tv[ii];
    }
    __syncthreads();

    f4 sc[8];
#pragma unroll
    for (int kt=0; kt<8; ++kt) {
      int key = kt*16 + l16;
      bs8 kf0 = *(const bs8*)(lK + key*72 + g*8);
      bs8 kf1 = *(const bs8*)(lK + key*72 + 32 + g*8);
      f4 acc = {0.f,0.f,0.f,0.f};
      acc = __builtin_amdgcn_mfma_f32_16x16x32_bf16(qf0, kf0, acc, 0,0,0);
      acc = __builtin_amdgcn_mfma_f32_16x16x32_bf16(qf1, kf1, acc, 0,0,0);
      int kpos = kbase + (c*128 + key)*R;
      bool kvld = (kpos < SEQ);
#pragma unroll
      for (int r=0;r<4;++r) sc[kt][r] = kvld ? acc[r]*0.125f : NEGV;
    }
    float scl[4];
#pragma unroll
    for (int r=0;r<4;++r) {
      float mx = sc[0][r];
#pragma unroll
      for (int kt=1;kt<8;++kt) mx = fmaxf(mx, sc[kt][r]);
      mx = fmaxf(mx, __shfl_xor(mx, 1));
      mx = fmaxf(mx, __shfl_xor(mx, 2));
      mx = fmaxf(mx, __shfl_xor(mx, 4));
      mx = fmaxf(mx, __shfl_xor(mx, 8));
      float mn = fmaxf(rm[r], mx);
      scl[r] = __expf(rm[r] - mn);
      rm[r] = mn;
    }
#pragma unroll
    for (int r=0;r<4;++r) {
      float sm = 0.f;
#pragma unroll
      for (int kt=0;kt<8;++kt) { float p = __expf(sc[kt][r] - rm[r]); sc[kt][r] = p; sm += p; }
      sm += __shfl_xor(sm, 1); sm += __shfl_xor(sm, 2);
      sm += __shfl_xor(sm, 4); sm += __shfl_xor(sm, 8);
      rs[r] = rs[r]*scl[r] + sm;
    }
#pragma unroll
    for (int dt=0; dt<4; ++dt)
#pragma unroll
      for (int r=0;r<4;++r) oacc[dt][r] *= scl[r];
#pragma unroll
    for (int kt=0;kt<8;++kt)
#pragma unroll
      for (int r=0;r<4;++r)
        Pl[w][g*4+r][kt*16+l16] = f2bf(sc[kt][r]);
#pragma unroll
    for (int ks=0; ks<4; ++ks) {
      bs8 pa = *(const bs8*)(&Pl[w][l16][ks*32 + g*8]);
#pragma unroll
      for (int dt=0; dt<4; ++dt) {
        bs8 vb = *(const bs8*)(lVt + (dt*16+l16)*136 + ks*32 + g*8);
        oacc[dt] = __builtin_amdgcn_mfma_f32_16x16x32_bf16(pa, vb, oacc[dt], 0,0,0);
      }
    }
  }

  size_t obase = ((size_t)(b*NSEG + seg)*NHEADS + hd)*512;
#pragma unroll
  for (int dt=0; dt<4; ++dt)
#pragma unroll
    for (int r=0;r<4;++r) {
      int j = j0 + g*4 + r;
      OB[(obase + j)*64 + dt*16 + l16] = f2bf(oacc[dt][r] / rs[r]);
    }
  if (l16 == 0) {
#pragma unroll
    for (int r=0;r<4;++r) LB[obase + j0 + g*4 + r] = rm[r] + __logf(rs[r]);
  }
}

// ---------------- combine 3 branches via lse softmax -> attn bf16 (MPAD,768)
__global__ __launch_bounds__(256) void attn_combine_k(
   const unsigned short* __restrict__ o1, const float* __restrict__ l1,
   const unsigned short* __restrict__ o2, const float* __restrict__ l2,
   const unsigned short* __restrict__ o3, const float* __restrict__ l3,
   unsigned short* __restrict__ attn)
{
  int row = blockIdx.x; int t = threadIdx.x;
  unsigned short* arow = attn + (size_t)row*EMB;
  if (row >= MROWS) { arow[t]=0; arow[t+256]=0; arow[t+512]=0; return; }
  int b = row / SEQ, pos = row - (row/SEQ)*SEQ;
#pragma unroll
  for (int c0=0; c0<3; ++c0) {
    int cc = t + c0*256;
    int hd = cc >> 6, d = cc & 63;
    float L0,L1v,L2v,O0,O1v,O2v;
    {
      int seg = pos >> 9; int j = pos & 511;
      size_t base = ((size_t)(b*5 + seg)*NHEADS + hd)*512 + j;
      L0 = l1[base]; O0 = bf2f(o1[base*64 + d]);
    }
    if ((pos & 1) == (hd & 1)) {
      int seg = pos >> 10; int j = ((pos & 1023) - (hd&1)) >> 1;
      size_t base = ((size_t)(b*3 + seg)*NHEADS + hd)*512 + j;
      L1v = l2[base]; O1v = bf2f(o2[base*64 + d]);
    } else { L1v = NEGV; O1v = 0.f; }
    if ((pos & 3) == (hd & 3)) {
      int seg = pos >> 11; int j = ((pos & 2047) - (hd&3)) >> 2;
      size_t base = ((size_t)(b*2 + seg)*NHEADS + hd)*512 + j;
      L2v = l3[base]; O2v = bf2f(o3[base*64 + d]);
    } else { L2v = NEGV; O2v = 0.f; }
    float m = fmaxf(L0, fmaxf(L1v, L2v));
    float e0 = __expf(L0-m), e1 = __expf(L1v-m), e2 = __expf(L2v-m);
    float inv = 1.f/(e0+e1+e2);
    arow[cc] = f2bf((e0*O0+e1*O1v+e2*O2v)*inv);
  }
}

extern "C" void kernel_launch(void* const* d_in, const int* in_sizes, int n_in,
                              void* d_out, int out_size, void* d_ws, size_t ws_size,
                              hipStream_t stream) {
  const float* x       = (const float*)d_in[0];
  const float* conv_w  = (const float*)d_in[1];
  const float* conv_b  = (const float*)d_in[2];
  const float* cls     = (const float*)d_in[3];
  const float* pos_e   = (const float*)d_in[4];
  const float* ln1_g   = (const float*)d_in[5];
  const float* ln1_b   = (const float*)d_in[6];
  const float* wq      = (const float*)d_in[7];
  const float* bq      = (const float*)d_in[8];
  const float* wk      = (const float*)d_in[9];
  const float* bk      = (const float*)d_in[10];
  const float* wv      = (const float*)d_in[11];
  const float* bv      = (const float*)d_in[12];
  const float* wo      = (const float*)d_in[13];
  const float* bo      = (const float*)d_in[14];
  const float* ln2_g   = (const float*)d_in[15];
  const float* ln2_b   = (const float*)d_in[16];
  const float* w1      = (const float*)d_in[17];
  const float* b1      = (const float*)d_in[18];
  const float* w2      = (const float*)d_in[19];
  const float* b2      = (const float*)d_in[20];
  const float* nf_g    = (const float*)d_in[21];
  const float* nf_b    = (const float*)d_in[22];

  char* ws = (char*)d_ws;
  size_t off = 0;
  auto alloc = [&](size_t bytes)->char* {
    char* p = ws + off; off += (bytes + 255) & ~(size_t)255; return p;
  };
  unsigned short* wqkv_t = (unsigned short*)alloc((size_t)12*2304*768*2);
  unsigned short* wo_t   = (unsigned short*)alloc((size_t)12*768*768*2);
  unsigned short* w1_t   = (unsigned short*)alloc((size_t)12*3072*768*2);
  unsigned short* w2_t   = (unsigned short*)alloc((size_t)12*768*3072*2);
  unsigned short* cw_b   = (unsigned short*)alloc((size_t)768*4096*2);
  float* bqkv            = (float*)alloc((size_t)12*2304*4);
  unsigned short* Xp     = (unsigned short*)alloc((size_t)4096*4096*2);
  float* H               = (float*)alloc((size_t)MPAD*768*4);
  float* P               = (float*)alloc((size_t)4*MPAD*768*4);
  unsigned short* Y      = (unsigned short*)alloc((size_t)MPAD*768*2);
  unsigned short* QKV    = (unsigned short*)alloc((size_t)MPAD*2304*2);
  unsigned short* ATT    = (unsigned short*)alloc((size_t)MPAD*768*2);
  unsigned short* Y2     = (unsigned short*)alloc((size_t)MPAD*3072*2);
  unsigned short* O1 = (unsigned short*)alloc((size_t)2*5*12*512*64*2);
  unsigned short* O2 = (unsigned short*)alloc((size_t)2*3*12*512*64*2);
  unsigned short* O3 = (unsigned short*)alloc((size_t)2*2*12*512*64*2);
  float* L1 = (float*)alloc((size_t)2*5*12*512*4);
  float* L2 = (float*)alloc((size_t)2*3*12*512*4);
  float* L3 = (float*)alloc((size_t)2*2*12*512*4);
  const size_t PSTR = (size_t)MPAD*768;

  dim3 tb(32,8);
  wtr_k<<<dim3(24,24,12), tb, 0, stream>>>(wq, wqkv_t, 768, 768, 2304, 0);
  wtr_k<<<dim3(24,24,12), tb, 0, stream>>>(wk, wqkv_t, 768, 768, 2304, 768);
  wtr_k<<<dim3(24,24,12), tb, 0, stream>>>(wv, wqkv_t, 768, 768, 2304, 1536);
  wtr_k<<<dim3(24,24,12), tb, 0, stream>>>(wo, wo_t, 768, 768, 768, 0);
  wtr_k<<<dim3(24,96,12), tb, 0, stream>>>(w1, w1_t, 768, 3072, 3072, 0);
  wtr_k<<<dim3(96,24,12), tb, 0, stream>>>(w2, w2_t, 3072, 768, 768, 0);
  castconv_k<<<3072,256,0,stream>>>(conv_w, cw_b);
  biascat_k<<<108,256,0,stream>>>(bq,bk,bv,bqkv);
  patchify_k<<<16384,256,0,stream>>>(x, Xp);
  gemm_k<3,4><<<dim3(6,32,4),256,0,stream>>>(Xp, cw_b, conv_b, nullptr, P, 4096, 768, PSTR);
  assemble_k<<<MPAD,256,0,stream>>>(P, PSTR, cls, pos_e, H);

  for (int l=0;l<12;++l) {
    if (l==0) ln_k<<<MPAD,256,0,stream>>>(H, ln1_g, ln1_b, Y);
    else ln_red_k<4><<<MPAD,256,0,stream>>>(H, P, PSTR, ln1_g + l*768, ln1_b + l*768, Y);
    gemm_k<0,1><<<dim3(18,33),256,0,stream>>>(Y, wqkv_t + (size_t)l*2304*768, bqkv + l*2304, QKV, nullptr, 768, 2304, 0);
    attn_all_k<<<1920,256,0,stream>>>(QKV, O1,L1,O2,L2,O3,L3);
    attn_combine_k<<<MPAD,256,0,stream>>>(O1,L1,O2,L2,O3,L3, ATT);
    gemm_k<3,2><<<dim3(6,33,2),256,0,stream>>>(ATT, wo_t + (size_t)l*768*768, bo + l*768, nullptr, P, 768, 768, PSTR);
    ln_red_k<2><<<MPAD,256,0,stream>>>(H, P, PSTR, ln2_g + l*768, ln2_b + l*768, Y);
    gemm_k<1,1><<<dim3(24,33),256,0,stream>>>(Y, w1_t + (size_t)l*3072*768, b1 + l*3072, Y2, nullptr, 768, 3072, 0);
    gemm_k<3,4><<<dim3(6,33,4),256,0,stream>>>(Y2, w2_t + (size_t)l*768*3072, b2 + l*768, nullptr, P, 3072, 768, PSTR);
  }
  final_ln_red_k<<<2,256,0,stream>>>(H, P, PSTR, nf_g, nf_b, (float*)d_out);
}

// Round 5
// 3020.443 us; speedup vs baseline: 1.7569x; 1.0141x over previous
//
#include <hip/hip_runtime.h>
#include <math.h>

#define SEQ 2049
#define EMB 768
#define NHEADS 12
#define QKVW 2304
#define MROWS 4098
#define MPAD 4224
#define NEGV -1000000000.0f

typedef short bs8 __attribute__((ext_vector_type(8)));
typedef float f4 __attribute__((ext_vector_type(4)));

__device__ __forceinline__ unsigned short f2bf(float f){
  union { float f; unsigned u; } x; x.f = f;
  unsigned r = x.u + 0x7fffu + ((x.u >> 16) & 1u);
  return (unsigned short)(r >> 16);
}
__device__ __forceinline__ float bf2f(unsigned short u){
  union { unsigned u; float f; } x; x.u = ((unsigned)u) << 16; return x.f;
}

// gelu(x) = 0.5 x (1 + erf(x/sqrt2)), erf via A&S 7.1.26 (|eps|<=1.5e-7)
__device__ __forceinline__ float gelu_f(float x){
  float ax = fabsf(x)*0.70710678f;
  float t = 1.f/(1.f + 0.3275911f*ax);
  float p = t*(0.254829592f + t*(-0.284496736f + t*(1.421413741f
            + t*(-1.453152027f + t*1.061405429f))));
  float erfv = 1.f - p*__expf(-ax*ax);
  float s = (x >= 0.f) ? erfv : -erfv;
  return 0.5f*x*(1.f + s);
}

__device__ __forceinline__ void gl_lds16(const void* g, void* l){
  __builtin_amdgcn_global_load_lds((const __attribute__((address_space(1))) void*)g,
                                   (__attribute__((address_space(3))) void*)l, 16, 0, 0);
}

// ---------------- weight transpose fp32 (L,K,N) -> bf16 dst[(l*LD+NOFF+n)*K+k]
__global__ void wtr_k(const float* __restrict__ src, unsigned short* __restrict__ dst,
                      int K, int N, int LD, int NOFF)
{
  __shared__ float tile[32][33];
  int k0 = blockIdx.x*32, n0 = blockIdx.y*32, z = blockIdx.z;
  int tx = threadIdx.x, ty = threadIdx.y;
  const float* s = src + (size_t)z*K*N;
#pragma unroll
  for (int i=0;i<4;++i)
    tile[ty*4+i][tx] = s[(size_t)(k0+ty*4+i)*N + n0+tx];
  __syncthreads();
  unsigned short* dz = dst + ((size_t)z*LD + NOFF)*K;
#pragma unroll
  for (int i=0;i<4;++i)
    dz[(size_t)(n0+ty*4+i)*K + k0+tx] = f2bf(tile[tx][ty*4+i]);
}

__global__ void castconv_k(const float* __restrict__ src, unsigned short* __restrict__ dst){
  size_t i = ((size_t)blockIdx.x*256 + threadIdx.x)*4;
  float4 f = *(const float4*)(src+i);
  dst[i+0]=f2bf(f.x); dst[i+1]=f2bf(f.y); dst[i+2]=f2bf(f.z); dst[i+3]=f2bf(f.w);
}

__global__ void biascat_k(const float* __restrict__ bq, const float* __restrict__ bk,
                          const float* __restrict__ bv, float* __restrict__ dst){
  int i = blockIdx.x*256+threadIdx.x;
  int l = i/QKVW, c = i%QKVW;
  float v = (c<768) ? bq[l*768+c] : (c<1536 ? bk[l*768+c-768] : bv[l*768+c-1536]);
  dst[i] = v;
}

// ---------------- patch extraction: x (2,1,128,256,256) f32 -> Xp (4096,4096) bf16
__global__ void patchify_k(const float* __restrict__ x, unsigned short* __restrict__ Xp)
{
  size_t gid = (size_t)blockIdx.x*256 + threadIdx.x;
  size_t oi = gid*4;
  int row = (int)(oi >> 12);
  int c = (int)(oi & 4095);
  int b = row >> 11; int p = row & 2047;
  int pd = p >> 8, ph = (p>>4)&15, pw = p&15;
  int pz = c >> 8, py = (c>>4)&15, px = c&15;
  size_t src = (((size_t)(b*128 + pd*16+pz)*256) + (size_t)(ph*16+py))*256 + (size_t)(pw*16+px);
  float4 f = *(const float4*)(x+src);
  Xp[oi+0]=f2bf(f.x); Xp[oi+1]=f2bf(f.y); Xp[oi+2]=f2bf(f.z); Xp[oi+3]=f2bf(f.w);
}

// ---------------- assemble h = [cls; sum4(P)] + pos, zero pads
__global__ void assemble_k(const float* __restrict__ P, size_t pstride,
                           const float* __restrict__ cls,
                           const float* __restrict__ pos_e, float* __restrict__ H)
{
  int row = blockIdx.x; int t = threadIdx.x;
  float* hr = H + (size_t)row*EMB;
  if (row >= MROWS) { hr[t]=0.f; hr[t+256]=0.f; hr[t+512]=0.f; return; }
  int b = row / SEQ; int pos = row - b*SEQ;
#pragma unroll
  for (int c0=0;c0<3;++c0) {
    int c = t + c0*256;
    float v;
    if (pos==0) v = cls[c];
    else {
      size_t idx = ((size_t)(b*2048 + pos-1))*EMB + c;
      v = P[idx] + P[pstride+idx] + P[2*pstride+idx] + P[3*pstride+idx];
    }
    hr[c] = v + pos_e[(size_t)pos*EMB + c];
  }
}

// ---------------- layernorm row -> bf16 (no reduction input)
__global__ __launch_bounds__(256) void ln_k(const float* __restrict__ H,
    const float* __restrict__ gam, const float* __restrict__ bet,
    unsigned short* __restrict__ Y)
{
  int row = blockIdx.x, t = threadIdx.x;
  const float* hr = H + (size_t)row*EMB;
  float v0 = hr[t], v1 = hr[t+256], v2 = hr[t+512];
  float s = v0+v1+v2;
#pragma unroll
  for (int off=32; off>=1; off>>=1) s += __shfl_down(s, off);
  __shared__ float r1[4], r2[4];
  if ((t&63)==0) r1[t>>6] = s;
  __syncthreads();
  float mean = (r1[0]+r1[1]+r1[2]+r1[3]) * (1.f/768.f);
  float d0=v0-mean, d1=v1-mean, d2=v2-mean;
  float q = d0*d0+d1*d1+d2*d2;
#pragma unroll
  for (int off=32; off>=1; off>>=1) q += __shfl_down(q, off);
  if ((t&63)==0) r2[t>>6] = q;
  __syncthreads();
  float rstd = rsqrtf((r2[0]+r2[1]+r2[2]+r2[3])*(1.f/768.f) + 1e-5f);
  unsigned short* yr = Y + (size_t)row*EMB;
  yr[t]     = f2bf(d0*rstd*gam[t]     + bet[t]);
  yr[t+256] = f2bf(d1*rstd*gam[t+256] + bet[t+256]);
  yr[t+512] = f2bf(d2*rstd*gam[t+512] + bet[t+512]);
}

// ---------------- fused: H += sum_{s<S} P[s]; Y = LN(H)
template<int S>
__global__ __launch_bounds__(256) void ln_red_k(float* __restrict__ H,
    const float* __restrict__ P, size_t pstride,
    const float* __restrict__ gam, const float* __restrict__ bet,
    unsigned short* __restrict__ Y)
{
  int row = blockIdx.x, t = threadIdx.x;
  size_t base = (size_t)row*EMB;
  float v[3];
#pragma unroll
  for (int c0=0;c0<3;++c0) {
    size_t idx = base + t + c0*256;
    float h = H[idx];
#pragma unroll
    for (int s=0;s<S;++s) h += P[(size_t)s*pstride + idx];
    H[idx] = h; v[c0] = h;
  }
  float s = v[0]+v[1]+v[2];
#pragma unroll
  for (int off=32; off>=1; off>>=1) s += __shfl_down(s, off);
  __shared__ float r1[4], r2[4];
  if ((t&63)==0) r1[t>>6] = s;
  __syncthreads();
  float mean = (r1[0]+r1[1]+r1[2]+r1[3]) * (1.f/768.f);
  float d0=v[0]-mean, d1=v[1]-mean, d2=v[2]-mean;
  float q = d0*d0+d1*d1+d2*d2;
#pragma unroll
  for (int off=32; off>=1; off>>=1) q += __shfl_down(q, off);
  if ((t&63)==0) r2[t>>6] = q;
  __syncthreads();
  float rstd = rsqrtf((r2[0]+r2[1]+r2[2]+r2[3])*(1.f/768.f) + 1e-5f);
  unsigned short* yr = Y + base;
  yr[t]     = f2bf(d0*rstd*gam[t]     + bet[t]);
  yr[t+256] = f2bf(d1*rstd*gam[t+256] + bet[t+256]);
  yr[t+512] = f2bf(d2*rstd*gam[t+512] + bet[t+512]);
}

// ---------------- final layernorm on cls rows (with 4-way partial reduce) -> fp32 out
__global__ __launch_bounds__(256) void final_ln_red_k(const float* __restrict__ H,
   const float* __restrict__ P, size_t pstride,
   const float* __restrict__ gam, const float* __restrict__ bet, float* __restrict__ out)
{
  int b = blockIdx.x, t = threadIdx.x;
  size_t base = (size_t)(b*SEQ)*EMB;
  float v[3];
#pragma unroll
  for (int c0=0;c0<3;++c0) {
    size_t idx = base + t + c0*256;
    float h = H[idx];
#pragma unroll
    for (int s=0;s<4;++s) h += P[(size_t)s*pstride + idx];
    v[c0] = h;
  }
  float s = v[0]+v[1]+v[2];
#pragma unroll
  for (int off=32; off>=1; off>>=1) s += __shfl_down(s, off);
  __shared__ float r1[4], r2[4];
  if ((t&63)==0) r1[t>>6] = s;
  __syncthreads();
  float mean = (r1[0]+r1[1]+r1[2]+r1[3]) * (1.f/768.f);
  float d0=v[0]-mean, d1=v[1]-mean, d2=v[2]-mean;
  float q = d0*d0+d1*d1+d2*d2;
#pragma unroll
  for (int off=32; off>=1; off>>=1) q += __shfl_down(q, off);
  if ((t&63)==0) r2[t>>6] = q;
  __syncthreads();
  float rstd = rsqrtf((r2[0]+r2[1]+r2[2]+r2[3])*(1.f/768.f) + 1e-5f);
  out[b*EMB + t]     = d0*rstd*gam[t]     + bet[t];
  out[b*EMB + t+256] = d1*rstd*gam[t+256] + bet[t+256];
  out[b*EMB + t+512] = d2*rstd*gam[t+512] + bet[t+512];
}

// ---------------- GEMM: A(MxK) bf16 row-major, Bt(NxK) bf16, 128x128 tile
// depth-2 prefetch pipeline: 3 LDS buffers, steady-state vmcnt(8); XOR-swizzled LDS.
// MODE 0: bf16 out +bias; 1: bf16 out +bias+gelu; 3: f32 split-partial write
template<int MODE, int NSPLIT>
__global__ __launch_bounds__(256) void gemm_k(
    const unsigned short* __restrict__ A,
    const unsigned short* __restrict__ Bt,
    const float* __restrict__ bias,
    unsigned short* __restrict__ Cb,
    float* __restrict__ Cf,
    int K, int ldc, size_t splitStride)
{
  __shared__ __attribute__((aligned(16))) unsigned short lA[3][128*32];
  __shared__ __attribute__((aligned(16))) unsigned short lB[3][128*32];
  const int tid = threadIdx.x;
  const int w = tid>>6, lane = tid&63, g = lane>>4, l16 = lane&15;
  const int lr = lane>>2;
  // swizzled source column-group: phys slot p holds logical cg p ^ ((row>>1)&3)
  const int lcs = (((lane&3) ^ ((lane>>3)&3)))*8;
  // swizzled read offset (constant per lane)
  const int swz = ((g ^ ((l16>>1)&3)))*8;
  // bijective XCD-chunked swizzle (m204)
  const int nwg = gridDim.x*gridDim.y;
  const int id = blockIdx.y*gridDim.x + blockIdx.x;
  const int q = nwg>>3, r = nwg&7, xc = id&7, si = id>>3;
  const int nid = (xc<r ? xc*(q+1) : r*(q+1)+(xc-r)*q) + si;
  const int tm = nid / gridDim.x;
  const int tn = nid - tm*gridDim.x;
  const int kchunk = K / NSPLIT;
  const int kofs = (NSPLIT>1) ? blockIdx.z * kchunk : 0;
  const unsigned short* Ab = A + (size_t)tm*128*K + kofs;
  const unsigned short* Bb = Bt + (size_t)tn*128*K + kofs;
  const int wm = (w>>1)*64, wn = (w&1)*64;
  f4 acc[4][4] = {};
  const int nkt = kchunk>>5;

  auto STAGE = [&](int buf, int kt){
    const size_t ko = (size_t)(kt*32 + lcs);
    gl_lds16(Ab + (size_t)(w*16 + lr)*K + ko,     ((char*)lA[buf]) + w*1024);
    gl_lds16(Ab + (size_t)((w+4)*16 + lr)*K + ko, ((char*)lA[buf]) + (w+4)*1024);
    gl_lds16(Bb + (size_t)(w*16 + lr)*K + ko,     ((char*)lB[buf]) + w*1024);
    gl_lds16(Bb + (size_t)((w+4)*16 + lr)*K + ko, ((char*)lB[buf]) + (w+4)*1024);
  };

  STAGE(0, 0);
  STAGE(1, 1);
  for (int kt=0; kt<nkt; ++kt) {
    const int cur = kt % 3;
    if (kt+2 < nkt) {
      STAGE((kt+2)%3, kt+2);
      asm volatile("s_waitcnt vmcnt(8)" ::: "memory");   // kt's 4 loads done
    } else if (kt+1 < nkt) {
      asm volatile("s_waitcnt vmcnt(4)" ::: "memory");
    } else {
      asm volatile("s_waitcnt vmcnt(0)" ::: "memory");
    }
    __builtin_amdgcn_sched_barrier(0);
    __builtin_amdgcn_s_barrier();          // buf[cur] ready for all waves
    bs8 af[4], bf[4];
#pragma unroll
    for (int mi=0;mi<4;++mi) af[mi] = *(const bs8*)(lA[cur] + (wm+mi*16+l16)*32 + swz);
#pragma unroll
    for (int ni=0;ni<4;++ni) bf[ni] = *(const bs8*)(lB[cur] + (wn+ni*16+l16)*32 + swz);
    asm volatile("s_waitcnt lgkmcnt(0)" ::: "memory");
    __builtin_amdgcn_sched_barrier(0);
    __builtin_amdgcn_s_barrier();          // all reads of buf[cur] done -> reusable
#pragma unroll
    for (int mi=0;mi<4;++mi)
#pragma unroll
      for (int ni=0;ni<4;++ni)
        acc[mi][ni] = __builtin_amdgcn_mfma_f32_16x16x32_bf16(af[mi], bf[ni], acc[mi][ni], 0,0,0);
  }
  const float bscale = (NSPLIT==1 || blockIdx.z==0) ? 1.f : 0.f;
#pragma unroll
  for (int mi=0;mi<4;++mi)
#pragma unroll
    for (int ni=0;ni<4;++ni) {
      int col = tn*128 + wn + ni*16 + l16;
      float bv = bias[col]*bscale;
#pragma unroll
      for (int r0=0;r0<4;++r0) {
        int row = tm*128 + wm + mi*16 + g*4 + r0;
        float val = acc[mi][ni][r0] + bv;
        if (MODE==1) val = gelu_f(val);
        if (MODE<=1) Cb[(size_t)row*ldc + col] = f2bf(val);
        else Cf[(size_t)blockIdx.z*splitStride + (size_t)row*ldc + col] = val;
      }
    }
}

// ---------------- fused dilated attention, all 3 branches, online-flash
__global__ __launch_bounds__(256) void attn_all_k(
    const unsigned short* __restrict__ qkv,
    unsigned short* __restrict__ O1, float* __restrict__ L1,
    unsigned short* __restrict__ O2, float* __restrict__ L2,
    unsigned short* __restrict__ O3, float* __restrict__ L3)
{
  __shared__ __attribute__((aligned(16))) unsigned short lK[128*72];    // [key][72]
  __shared__ __attribute__((aligned(16))) unsigned short lVt[64*136];   // [d][136]
  __shared__ __attribute__((aligned(16))) unsigned short Pl[4][16][136];
  const int tid = threadIdx.x;
  const int w = tid>>6, lane = tid&63, g = lane>>4, l16 = lane&15;

  int id = blockIdx.x;
  int R, WSZ, NSEG; unsigned short* OB; float* LB;
  if (id < 960)       { R=1; WSZ=512;  NSEG=5; OB=O1; LB=L1; }
  else if (id < 1536) { id -= 960;  R=2; WSZ=1024; NSEG=3; OB=O2; LB=L2; }
  else                { id -= 1536; R=4; WSZ=2048; NSEG=2; OB=O3; LB=L3; }
  const int qt = id & 7; int rest = id >> 3;
  const int seg = rest % NSEG; const int bh = rest / NSEG;
  const int b = bh / NHEADS, hd = bh % NHEADS;
  const int hr = hd % R;
  const int j0 = qt*64 + w*16;
  const int kbase = seg*WSZ + hr;
  const unsigned short* qkvb = qkv + (size_t)b*SEQ*QKVW;

  bs8 z = {0,0,0,0,0,0,0,0};
  bs8 qf0 = z, qf1 = z;
  {
    int qpos = kbase + (j0 + l16)*R;
    if (qpos < SEQ) {
      const unsigned short* qrow = qkvb + (size_t)qpos*QKVW + hd*64 + g*8;
      qf0 = *(const bs8*)(qrow);
      qf1 = *(const bs8*)(qrow + 32);
    }
  }

  float rm[4], rs[4];
  f4 oacc[4] = {};
#pragma unroll
  for (int r=0;r<4;++r) { rm[r] = NEGV; rs[r] = 0.f; }

  for (int c=0; c<4; ++c) {
    __syncthreads();
#pragma unroll
    for (int it=0; it<4; ++it) {
      int idx = tid + it*256;
      int kk = idx >> 3, dblk = idx & 7;
      int kpos = kbase + (c*128 + kk)*R;
      bs8 kv = z;
      if (kpos < SEQ) kv = *(const bs8*)(qkvb + (size_t)kpos*QKVW + EMB + hd*64 + dblk*8);
      *(bs8*)(lK + kk*72 + dblk*8) = kv;
    }
#pragma unroll
    for (int it=0; it<4; ++it) {
      int idx = tid + it*256;
      int kk = idx & 127, dblk = idx >> 7;
      int kpos = kbase + (c*128 + kk)*R;
      unsigned short tv[8] = {0,0,0,0,0,0,0,0};
      if (kpos < SEQ)
        *(bs8*)tv = *(const bs8*)(qkvb + (size_t)kpos*QKVW + 1536 + hd*64 + dblk*8);
#pragma unroll
      for (int ii=0; ii<8; ++ii) lVt[(dblk*8+ii)*136 + kk] = tv[ii];
    }
    __syncthreads();

    f4 sc[8];
#pragma unroll
    for (int kt=0; kt<8; ++kt) {
      int key = kt*16 + l16;
      bs8 kf0 = *(const bs8*)(lK + key*72 + g*8);
      bs8 kf1 = *(const bs8*)(lK + key*72 + 32 + g*8);
      f4 acc = {0.f,0.f,0.f,0.f};
      acc = __builtin_amdgcn_mfma_f32_16x16x32_bf16(qf0, kf0, acc, 0,0,0);
      acc = __builtin_amdgcn_mfma_f32_16x16x32_bf16(qf1, kf1, acc, 0,0,0);
      int kpos = kbase + (c*128 + key)*R;
      bool kvld = (kpos < SEQ);
#pragma unroll
      for (int r=0;r<4;++r) sc[kt][r] = kvld ? acc[r]*0.125f : NEGV;
    }
    float scl[4];
#pragma unroll
    for (int r=0;r<4;++r) {
      float mx = sc[0][r];
#pragma unroll
      for (int kt=1;kt<8;++kt) mx = fmaxf(mx, sc[kt][r]);
      mx = fmaxf(mx, __shfl_xor(mx, 1));
      mx = fmaxf(mx, __shfl_xor(mx, 2));
      mx = fmaxf(mx, __shfl_xor(mx, 4));
      mx = fmaxf(mx, __shfl_xor(mx, 8));
      float mn = fmaxf(rm[r], mx);
      scl[r] = __expf(rm[r] - mn);
      rm[r] = mn;
    }
#pragma unroll
    for (int r=0;r<4;++r) {
      float sm = 0.f;
#pragma unroll
      for (int kt=0;kt<8;++kt) { float p = __expf(sc[kt][r] - rm[r]); sc[kt][r] = p; sm += p; }
      sm += __shfl_xor(sm, 1); sm += __shfl_xor(sm, 2);
      sm += __shfl_xor(sm, 4); sm += __shfl_xor(sm, 8);
      rs[r] = rs[r]*scl[r] + sm;
    }
#pragma unroll
    for (int dt=0; dt<4; ++dt)
#pragma unroll
      for (int r=0;r<4;++r) oacc[dt][r] *= scl[r];
#pragma unroll
    for (int kt=0;kt<8;++kt)
#pragma unroll
      for (int r=0;r<4;++r)
        Pl[w][g*4+r][kt*16+l16] = f2bf(sc[kt][r]);
#pragma unroll
    for (int ks=0; ks<4; ++ks) {
      bs8 pa = *(const bs8*)(&Pl[w][l16][ks*32 + g*8]);
#pragma unroll
      for (int dt=0; dt<4; ++dt) {
        bs8 vb = *(const bs8*)(lVt + (dt*16+l16)*136 + ks*32 + g*8);
        oacc[dt] = __builtin_amdgcn_mfma_f32_16x16x32_bf16(pa, vb, oacc[dt], 0,0,0);
      }
    }
  }

  size_t obase = ((size_t)(b*NSEG + seg)*NHEADS + hd)*512;
#pragma unroll
  for (int dt=0; dt<4; ++dt)
#pragma unroll
    for (int r=0;r<4;++r) {
      int j = j0 + g*4 + r;
      OB[(obase + j)*64 + dt*16 + l16] = f2bf(oacc[dt][r] / rs[r]);
    }
  if (l16 == 0) {
#pragma unroll
    for (int r=0;r<4;++r) LB[obase + j0 + g*4 + r] = rm[r] + __logf(rs[r]);
  }
}

// ---------------- combine 3 branches via lse softmax -> attn bf16 (MPAD,768)
__global__ __launch_bounds__(256) void attn_combine_k(
   const unsigned short* __restrict__ o1, const float* __restrict__ l1,
   const unsigned short* __restrict__ o2, const float* __restrict__ l2,
   const unsigned short* __restrict__ o3, const float* __restrict__ l3,
   unsigned short* __restrict__ attn)
{
  int row = blockIdx.x; int t = threadIdx.x;
  unsigned short* arow = attn + (size_t)row*EMB;
  if (row >= MROWS) { arow[t]=0; arow[t+256]=0; arow[t+512]=0; return; }
  int b = row / SEQ, pos = row - (row/SEQ)*SEQ;
#pragma unroll
  for (int c0=0; c0<3; ++c0) {
    int cc = t + c0*256;
    int hd = cc >> 6, d = cc & 63;
    float L0,L1v,L2v,O0,O1v,O2v;
    {
      int seg = pos >> 9; int j = pos & 511;
      size_t base = ((size_t)(b*5 + seg)*NHEADS + hd)*512 + j;
      L0 = l1[base]; O0 = bf2f(o1[base*64 + d]);
    }
    if ((pos & 1) == (hd & 1)) {
      int seg = pos >> 10; int j = ((pos & 1023) - (hd&1)) >> 1;
      size_t base = ((size_t)(b*3 + seg)*NHEADS + hd)*512 + j;
      L1v = l2[base]; O1v = bf2f(o2[base*64 + d]);
    } else { L1v = NEGV; O1v = 0.f; }
    if ((pos & 3) == (hd & 3)) {
      int seg = pos >> 11; int j = ((pos & 2047) - (hd&3)) >> 2;
      size_t base = ((size_t)(b*2 + seg)*NHEADS + hd)*512 + j;
      L2v = l3[base]; O2v = bf2f(o3[base*64 + d]);
    } else { L2v = NEGV; O2v = 0.f; }
    float m = fmaxf(L0, fmaxf(L1v, L2v));
    float e0 = __expf(L0-m), e1 = __expf(L1v-m), e2 = __expf(L2v-m);
    float inv = 1.f/(e0+e1+e2);
    arow[cc] = f2bf((e0*O0+e1*O1v+e2*O2v)*inv);
  }
}

extern "C" void kernel_launch(void* const* d_in, const int* in_sizes, int n_in,
                              void* d_out, int out_size, void* d_ws, size_t ws_size,
                              hipStream_t stream) {
  const float* x       = (const float*)d_in[0];
  const float* conv_w  = (const float*)d_in[1];
  const float* conv_b  = (const float*)d_in[2];
  const float* cls     = (const float*)d_in[3];
  const float* pos_e   = (const float*)d_in[4];
  const float* ln1_g   = (const float*)d_in[5];
  const float* ln1_b   = (const float*)d_in[6];
  const float* wq      = (const float*)d_in[7];
  const float* bq      = (const float*)d_in[8];
  const float* wk      = (const float*)d_in[9];
  const float* bk      = (const float*)d_in[10];
  const float* wv      = (const float*)d_in[11];
  const float* bv      = (const float*)d_in[12];
  const float* wo      = (const float*)d_in[13];
  const float* bo      = (const float*)d_in[14];
  const float* ln2_g   = (const float*)d_in[15];
  const float* ln2_b   = (const float*)d_in[16];
  const float* w1      = (const float*)d_in[17];
  const float* b1      = (const float*)d_in[18];
  const float* w2      = (const float*)d_in[19];
  const float* b2      = (const float*)d_in[20];
  const float* nf_g    = (const float*)d_in[21];
  const float* nf_b    = (const float*)d_in[22];

  char* ws = (char*)d_ws;
  size_t off = 0;
  auto alloc = [&](size_t bytes)->char* {
    char* p = ws + off; off += (bytes + 255) & ~(size_t)255; return p;
  };
  unsigned short* wqkv_t = (unsigned short*)alloc((size_t)12*2304*768*2);
  unsigned short* wo_t   = (unsigned short*)alloc((size_t)12*768*768*2);
  unsigned short* w1_t   = (unsigned short*)alloc((size_t)12*3072*768*2);
  unsigned short* w2_t   = (unsigned short*)alloc((size_t)12*768*3072*2);
  unsigned short* cw_b   = (unsigned short*)alloc((size_t)768*4096*2);
  float* bqkv            = (float*)alloc((size_t)12*2304*4);
  unsigned short* Xp     = (unsigned short*)alloc((size_t)4096*4096*2);
  float* H               = (float*)alloc((size_t)MPAD*768*4);
  float* P               = (float*)alloc((size_t)4*MPAD*768*4);
  unsigned short* Y      = (unsigned short*)alloc((size_t)MPAD*768*2);
  unsigned short* QKV    = (unsigned short*)alloc((size_t)MPAD*2304*2);
  unsigned short* ATT    = (unsigned short*)alloc((size_t)MPAD*768*2);
  unsigned short* Y2     = (unsigned short*)alloc((size_t)MPAD*3072*2);
  unsigned short* O1 = (unsigned short*)alloc((size_t)2*5*12*512*64*2);
  unsigned short* O2 = (unsigned short*)alloc((size_t)2*3*12*512*64*2);
  unsigned short* O3 = (unsigned short*)alloc((size_t)2*2*12*512*64*2);
  float* L1 = (float*)alloc((size_t)2*5*12*512*4);
  float* L2 = (float*)alloc((size_t)2*3*12*512*4);
  float* L3 = (float*)alloc((size_t)2*2*12*512*4);
  const size_t PSTR = (size_t)MPAD*768;

  dim3 tb(32,8);
  wtr_k<<<dim3(24,24,12), tb, 0, stream>>>(wq, wqkv_t, 768, 768, 2304, 0);
  wtr_k<<<dim3(24,24,12), tb, 0, stream>>>(wk, wqkv_t, 768, 768, 2304, 768);
  wtr_k<<<dim3(24,24,12), tb, 0, stream>>>(wv, wqkv_t, 768, 768, 2304, 1536);
  wtr_k<<<dim3(24,24,12), tb, 0, stream>>>(wo, wo_t, 768, 768, 768, 0);
  wtr_k<<<dim3(24,96,12), tb, 0, stream>>>(w1, w1_t, 768, 3072, 3072, 0);
  wtr_k<<<dim3(96,24,12), tb, 0, stream>>>(w2, w2_t, 3072, 768, 768, 0);
  castconv_k<<<3072,256,0,stream>>>(conv_w, cw_b);
  biascat_k<<<108,256,0,stream>>>(bq,bk,bv,bqkv);
  patchify_k<<<16384,256,0,stream>>>(x, Xp);
  gemm_k<3,4><<<dim3(6,32,4),256,0,stream>>>(Xp, cw_b, conv_b, nullptr, P, 4096, 768, PSTR);
  assemble_k<<<MPAD,256,0,stream>>>(P, PSTR, cls, pos_e, H);

  for (int l=0;l<12;++l) {
    if (l==0) ln_k<<<MPAD,256,0,stream>>>(H, ln1_g, ln1_b, Y);
    else ln_red_k<4><<<MPAD,256,0,stream>>>(H, P, PSTR, ln1_g + l*768, ln1_b + l*768, Y);
    gemm_k<0,1><<<dim3(18,33),256,0,stream>>>(Y, wqkv_t + (size_t)l*2304*768, bqkv + l*2304, QKV, nullptr, 768, 2304, 0);
    attn_all_k<<<1920,256,0,stream>>>(QKV, O1,L1,O2,L2,O3,L3);
    attn_combine_k<<<MPAD,256,0,stream>>>(O1,L1,O2,L2,O3,L3, ATT);
    gemm_k<3,2><<<dim3(6,33,2),256,0,stream>>>(ATT, wo_t + (size_t)l*768*768, bo + l*768, nullptr, P, 768, 768, PSTR);
    ln_red_k<2><<<MPAD,256,0,stream>>>(H, P, PSTR, ln2_g + l*768, ln2_b + l*768, Y);
    gemm_k<1,1><<<dim3(24,33),256,0,stream>>>(Y, w1_t + (size_t)l*3072*768, b1 + l*3072, Y2, nullptr, 768, 3072, 0);
    gemm_k<3,4><<<dim3(6,33,4),256,0,stream>>>(Y2, w2_t + (size_t)l*768*3072, b2 + l*768, nullptr, P, 3072, 768, PSTR);
  }
  final_ln_red_k<<<2,256,0,stream>>>(H, P, PSTR, nf_g, nf_b, (float*)d_out);
}

// Round 6
// 2855.605 us; speedup vs baseline: 1.8583x; 1.0577x over previous
//
#include <hip/hip_runtime.h>
#include <math.h>

#define SEQ 2049
#define EMB 768
#define NHEADS 12
#define QKVW 2304
#define MROWS 4098
#define MPAD 4224
#define NEGV -1000000000.0f

typedef short bs8 __attribute__((ext_vector_type(8)));
typedef float f4 __attribute__((ext_vector_type(4)));

__device__ __forceinline__ unsigned short f2bf(float f){
  union { float f; unsigned u; } x; x.f = f;
  unsigned r = x.u + 0x7fffu + ((x.u >> 16) & 1u);
  return (unsigned short)(r >> 16);
}
// fast round (values known finite/positive-ish, 1ulp bias ok)
__device__ __forceinline__ unsigned short f2bf_fast(float f){
  union { float f; unsigned u; } x; x.f = f;
  return (unsigned short)((x.u + 0x8000u) >> 16);
}
__device__ __forceinline__ float bf2f(unsigned short u){
  union { unsigned u; float f; } x; x.u = ((unsigned)u) << 16; return x.f;
}

// gelu(x) = 0.5 x (1 + erf(x/sqrt2)), erf via A&S 7.1.26 (|eps|<=1.5e-7)
__device__ __forceinline__ float gelu_f(float x){
  float ax = fabsf(x)*0.70710678f;
  float t = 1.f/(1.f + 0.3275911f*ax);
  float p = t*(0.254829592f + t*(-0.284496736f + t*(1.421413741f
            + t*(-1.453152027f + t*1.061405429f))));
  float erfv = 1.f - p*__expf(-ax*ax);
  float s = (x >= 0.f) ? erfv : -erfv;
  return 0.5f*x*(1.f + s);
}

__device__ __forceinline__ void gl_lds16(const void* g, void* l){
  __builtin_amdgcn_global_load_lds((const __attribute__((address_space(1))) void*)g,
                                   (__attribute__((address_space(3))) void*)l, 16, 0, 0);
}

// ---------------- weight transpose fp32 (L,K,N) -> bf16 dst[(l*LD+NOFF+n)*K+k]
__global__ void wtr_k(const float* __restrict__ src, unsigned short* __restrict__ dst,
                      int K, int N, int LD, int NOFF)
{
  __shared__ float tile[32][33];
  int k0 = blockIdx.x*32, n0 = blockIdx.y*32, z = blockIdx.z;
  int tx = threadIdx.x, ty = threadIdx.y;
  const float* s = src + (size_t)z*K*N;
#pragma unroll
  for (int i=0;i<4;++i)
    tile[ty*4+i][tx] = s[(size_t)(k0+ty*4+i)*N + n0+tx];
  __syncthreads();
  unsigned short* dz = dst + ((size_t)z*LD + NOFF)*K;
#pragma unroll
  for (int i=0;i<4;++i)
    dz[(size_t)(n0+ty*4+i)*K + k0+tx] = f2bf(tile[tx][ty*4+i]);
}

__global__ void castconv_k(const float* __restrict__ src, unsigned short* __restrict__ dst){
  size_t i = ((size_t)blockIdx.x*256 + threadIdx.x)*4;
  float4 f = *(const float4*)(src+i);
  dst[i+0]=f2bf(f.x); dst[i+1]=f2bf(f.y); dst[i+2]=f2bf(f.z); dst[i+3]=f2bf(f.w);
}

__global__ void biascat_k(const float* __restrict__ bq, const float* __restrict__ bk,
                          const float* __restrict__ bv, float* __restrict__ dst){
  int i = blockIdx.x*256+threadIdx.x;
  int l = i/QKVW, c = i%QKVW;
  float v = (c<768) ? bq[l*768+c] : (c<1536 ? bk[l*768+c-768] : bv[l*768+c-1536]);
  dst[i] = v;
}

// ---------------- patch extraction: x (2,1,128,256,256) f32 -> Xp (4096,4096) bf16
__global__ void patchify_k(const float* __restrict__ x, unsigned short* __restrict__ Xp)
{
  size_t gid = (size_t)blockIdx.x*256 + threadIdx.x;
  size_t oi = gid*4;
  int row = (int)(oi >> 12);
  int c = (int)(oi & 4095);
  int b = row >> 11; int p = row & 2047;
  int pd = p >> 8, ph = (p>>4)&15, pw = p&15;
  int pz = c >> 8, py = (c>>4)&15, px = c&15;
  size_t src = (((size_t)(b*128 + pd*16+pz)*256) + (size_t)(ph*16+py))*256 + (size_t)(pw*16+px);
  float4 f = *(const float4*)(x+src);
  Xp[oi+0]=f2bf(f.x); Xp[oi+1]=f2bf(f.y); Xp[oi+2]=f2bf(f.z); Xp[oi+3]=f2bf(f.w);
}

// ---------------- assemble h = [cls; sum4(P)] + pos, zero pads
__global__ void assemble_k(const float* __restrict__ P, size_t pstride,
                           const float* __restrict__ cls,
                           const float* __restrict__ pos_e, float* __restrict__ H)
{
  int row = blockIdx.x; int t = threadIdx.x;
  float* hr = H + (size_t)row*EMB;
  if (row >= MROWS) { hr[t]=0.f; hr[t+256]=0.f; hr[t+512]=0.f; return; }
  int b = row / SEQ; int pos = row - b*SEQ;
#pragma unroll
  for (int c0=0;c0<3;++c0) {
    int c = t + c0*256;
    float v;
    if (pos==0) v = cls[c];
    else {
      size_t idx = ((size_t)(b*2048 + pos-1))*EMB + c;
      v = P[idx] + P[pstride+idx] + P[2*pstride+idx] + P[3*pstride+idx];
    }
    hr[c] = v + pos_e[(size_t)pos*EMB + c];
  }
}

// ---------------- layernorm row -> bf16 (no reduction input)
__global__ __launch_bounds__(256) void ln_k(const float* __restrict__ H,
    const float* __restrict__ gam, const float* __restrict__ bet,
    unsigned short* __restrict__ Y)
{
  int row = blockIdx.x, t = threadIdx.x;
  const float* hr = H + (size_t)row*EMB;
  float v0 = hr[t], v1 = hr[t+256], v2 = hr[t+512];
  float s = v0+v1+v2;
#pragma unroll
  for (int off=32; off>=1; off>>=1) s += __shfl_down(s, off);
  __shared__ float r1[4], r2[4];
  if ((t&63)==0) r1[t>>6] = s;
  __syncthreads();
  float mean = (r1[0]+r1[1]+r1[2]+r1[3]) * (1.f/768.f);
  float d0=v0-mean, d1=v1-mean, d2=v2-mean;
  float q = d0*d0+d1*d1+d2*d2;
#pragma unroll
  for (int off=32; off>=1; off>>=1) q += __shfl_down(q, off);
  if ((t&63)==0) r2[t>>6] = q;
  __syncthreads();
  float rstd = rsqrtf((r2[0]+r2[1]+r2[2]+r2[3])*(1.f/768.f) + 1e-5f);
  unsigned short* yr = Y + (size_t)row*EMB;
  yr[t]     = f2bf(d0*rstd*gam[t]     + bet[t]);
  yr[t+256] = f2bf(d1*rstd*gam[t+256] + bet[t+256]);
  yr[t+512] = f2bf(d2*rstd*gam[t+512] + bet[t+512]);
}

// ---------------- fused: H += sum_{s<S} P[s]; Y = LN(H)
template<int S>
__global__ __launch_bounds__(256) void ln_red_k(float* __restrict__ H,
    const float* __restrict__ P, size_t pstride,
    const float* __restrict__ gam, const float* __restrict__ bet,
    unsigned short* __restrict__ Y)
{
  int row = blockIdx.x, t = threadIdx.x;
  size_t base = (size_t)row*EMB;
  float v[3];
#pragma unroll
  for (int c0=0;c0<3;++c0) {
    size_t idx = base + t + c0*256;
    float h = H[idx];
#pragma unroll
    for (int s=0;s<S;++s) h += P[(size_t)s*pstride + idx];
    H[idx] = h; v[c0] = h;
  }
  float s = v[0]+v[1]+v[2];
#pragma unroll
  for (int off=32; off>=1; off>>=1) s += __shfl_down(s, off);
  __shared__ float r1[4], r2[4];
  if ((t&63)==0) r1[t>>6] = s;
  __syncthreads();
  float mean = (r1[0]+r1[1]+r1[2]+r1[3]) * (1.f/768.f);
  float d0=v[0]-mean, d1=v[1]-mean, d2=v[2]-mean;
  float q = d0*d0+d1*d1+d2*d2;
#pragma unroll
  for (int off=32; off>=1; off>>=1) q += __shfl_down(q, off);
  if ((t&63)==0) r2[t>>6] = q;
  __syncthreads();
  float rstd = rsqrtf((r2[0]+r2[1]+r2[2]+r2[3])*(1.f/768.f) + 1e-5f);
  unsigned short* yr = Y + base;
  yr[t]     = f2bf(d0*rstd*gam[t]     + bet[t]);
  yr[t+256] = f2bf(d1*rstd*gam[t+256] + bet[t+256]);
  yr[t+512] = f2bf(d2*rstd*gam[t+512] + bet[t+512]);
}

// ---------------- final layernorm on cls rows (with S-way partial reduce) -> fp32 out
template<int S>
__global__ __launch_bounds__(256) void final_ln_red_k(const float* __restrict__ H,
   const float* __restrict__ P, size_t pstride,
   const float* __restrict__ gam, const float* __restrict__ bet, float* __restrict__ out)
{
  int b = blockIdx.x, t = threadIdx.x;
  size_t base = (size_t)(b*SEQ)*EMB;
  float v[3];
#pragma unroll
  for (int c0=0;c0<3;++c0) {
    size_t idx = base + t + c0*256;
    float h = H[idx];
#pragma unroll
    for (int s=0;s<S;++s) h += P[(size_t)s*pstride + idx];
    v[c0] = h;
  }
  float s = v[0]+v[1]+v[2];
#pragma unroll
  for (int off=32; off>=1; off>>=1) s += __shfl_down(s, off);
  __shared__ float r1[4], r2[4];
  if ((t&63)==0) r1[t>>6] = s;
  __syncthreads();
  float mean = (r1[0]+r1[1]+r1[2]+r1[3]) * (1.f/768.f);
  float d0=v[0]-mean, d1=v[1]-mean, d2=v[2]-mean;
  float q = d0*d0+d1*d1+d2*d2;
#pragma unroll
  for (int off=32; off>=1; off>>=1) q += __shfl_down(q, off);
  if ((t&63)==0) r2[t>>6] = q;
  __syncthreads();
  float rstd = rsqrtf((r2[0]+r2[1]+r2[2]+r2[3])*(1.f/768.f) + 1e-5f);
  out[b*EMB + t]     = d0*rstd*gam[t]     + bet[t];
  out[b*EMB + t+256] = d1*rstd*gam[t+256] + bet[t+256];
  out[b*EMB + t+512] = d2*rstd*gam[t+512] + bet[t+512];
}

// ---------------- GEMM: A(MxK) bf16 row-major, Bt(NxK) bf16, 128x128 tile
// depth-2 prefetch pipeline: 3 LDS buffers, steady-state vmcnt(8); XOR-swizzled LDS.
// MODE 0: bf16 out +bias; 1: bf16 out +bias+gelu; 3: f32 split-partial write
template<int MODE, int NSPLIT>
__global__ __launch_bounds__(256) void gemm_k(
    const unsigned short* __restrict__ A,
    const unsigned short* __restrict__ Bt,
    const float* __restrict__ bias,
    unsigned short* __restrict__ Cb,
    float* __restrict__ Cf,
    int K, int ldc, size_t splitStride)
{
  __shared__ __attribute__((aligned(16))) unsigned short lA[3][128*32];
  __shared__ __attribute__((aligned(16))) unsigned short lB[3][128*32];
  const int tid = threadIdx.x;
  const int w = tid>>6, lane = tid&63, g = lane>>4, l16 = lane&15;
  const int lr = lane>>2;
  const int lcs = (((lane&3) ^ ((lane>>3)&3)))*8;
  const int swz = ((g ^ ((l16>>1)&3)))*8;
  const int nwg = gridDim.x*gridDim.y;
  const int id = blockIdx.y*gridDim.x + blockIdx.x;
  const int q = nwg>>3, r = nwg&7, xc = id&7, si = id>>3;
  const int nid = (xc<r ? xc*(q+1) : r*(q+1)+(xc-r)*q) + si;
  const int tm = nid / gridDim.x;
  const int tn = nid - tm*gridDim.x;
  const int kchunk = K / NSPLIT;
  const int kofs = (NSPLIT>1) ? blockIdx.z * kchunk : 0;
  const unsigned short* Ab = A + (size_t)tm*128*K + kofs;
  const unsigned short* Bb = Bt + (size_t)tn*128*K + kofs;
  const int wm = (w>>1)*64, wn = (w&1)*64;
  f4 acc[4][4] = {};
  const int nkt = kchunk>>5;

  auto STAGE = [&](int buf, int kt){
    const size_t ko = (size_t)(kt*32 + lcs);
    gl_lds16(Ab + (size_t)(w*16 + lr)*K + ko,     ((char*)lA[buf]) + w*1024);
    gl_lds16(Ab + (size_t)((w+4)*16 + lr)*K + ko, ((char*)lA[buf]) + (w+4)*1024);
    gl_lds16(Bb + (size_t)(w*16 + lr)*K + ko,     ((char*)lB[buf]) + w*1024);
    gl_lds16(Bb + (size_t)((w+4)*16 + lr)*K + ko, ((char*)lB[buf]) + (w+4)*1024);
  };

  STAGE(0, 0);
  STAGE(1, 1);
  for (int kt=0; kt<nkt; ++kt) {
    const int cur = kt % 3;
    if (kt+2 < nkt) {
      STAGE((kt+2)%3, kt+2);
      asm volatile("s_waitcnt vmcnt(8)" ::: "memory");
    } else if (kt+1 < nkt) {
      asm volatile("s_waitcnt vmcnt(4)" ::: "memory");
    } else {
      asm volatile("s_waitcnt vmcnt(0)" ::: "memory");
    }
    __builtin_amdgcn_sched_barrier(0);
    __builtin_amdgcn_s_barrier();
    bs8 af[4], bf[4];
#pragma unroll
    for (int mi=0;mi<4;++mi) af[mi] = *(const bs8*)(lA[cur] + (wm+mi*16+l16)*32 + swz);
#pragma unroll
    for (int ni=0;ni<4;++ni) bf[ni] = *(const bs8*)(lB[cur] + (wn+ni*16+l16)*32 + swz);
    asm volatile("s_waitcnt lgkmcnt(0)" ::: "memory");
    __builtin_amdgcn_sched_barrier(0);
    __builtin_amdgcn_s_barrier();
#pragma unroll
    for (int mi=0;mi<4;++mi)
#pragma unroll
      for (int ni=0;ni<4;++ni)
        acc[mi][ni] = __builtin_amdgcn_mfma_f32_16x16x32_bf16(af[mi], bf[ni], acc[mi][ni], 0,0,0);
  }
  const float bscale = (NSPLIT==1 || blockIdx.z==0) ? 1.f : 0.f;
#pragma unroll
  for (int mi=0;mi<4;++mi)
#pragma unroll
    for (int ni=0;ni<4;++ni) {
      int col = tn*128 + wn + ni*16 + l16;
      float bv = bias[col]*bscale;
#pragma unroll
      for (int r0=0;r0<4;++r0) {
        int row = tm*128 + wm + mi*16 + g*4 + r0;
        float val = acc[mi][ni][r0] + bv;
        if (MODE==1) val = gelu_f(val);
        if (MODE<=1) Cb[(size_t)row*ldc + col] = f2bf(val);
        else Cf[(size_t)blockIdx.z*splitStride + (size_t)row*ldc + col] = val;
      }
    }
}

// ---------------- fused dilated attention, all 3 branches, online-flash
// XCD-swizzled block ids; K/V reg-staged one chunk ahead (T14); raw barriers,
// vmcnt never drained at a barrier.
__global__ __launch_bounds__(256) void attn_all_k(
    const unsigned short* __restrict__ qkv,
    unsigned short* __restrict__ O1, float* __restrict__ L1,
    unsigned short* __restrict__ O2, float* __restrict__ L2,
    unsigned short* __restrict__ O3, float* __restrict__ L3)
{
  __shared__ __attribute__((aligned(16))) unsigned short lK[128*72];    // [key][72]
  __shared__ __attribute__((aligned(16))) unsigned short lVt[64*136];   // [d][136]
  __shared__ __attribute__((aligned(16))) unsigned short Pl[4][16][136];
  const int tid = threadIdx.x;
  const int w = tid>>6, lane = tid&63, g = lane>>4, l16 = lane&15;

  // bijective XCD swizzle: 1920 = 8*240; the 8 q-tiles of one (seg,head)
  // and neighboring segments land on one XCD -> K/V L2 locality.
  int id = (blockIdx.x & 7)*240 + (blockIdx.x >> 3);
  int R, WSZ, NSEG; unsigned short* OB; float* LB;
  if (id < 960)       { R=1; WSZ=512;  NSEG=5; OB=O1; LB=L1; }
  else if (id < 1536) { id -= 960;  R=2; WSZ=1024; NSEG=3; OB=O2; LB=L2; }
  else                { id -= 1536; R=4; WSZ=2048; NSEG=2; OB=O3; LB=L3; }
  const int qt = id & 7; int rest = id >> 3;
  const int seg = rest % NSEG; const int bh = rest / NSEG;
  const int b = bh / NHEADS, hd = bh % NHEADS;
  const int hr = hd % R;
  const int j0 = qt*64 + w*16;
  const int kbase = seg*WSZ + hr;
  const unsigned short* qkvb = qkv + (size_t)b*SEQ*QKVW;

  bs8 z = {0,0,0,0,0,0,0,0};
  bs8 qf0 = z, qf1 = z;
  {
    int qpos = kbase + (j0 + l16)*R;
    if (qpos < SEQ) {
      const unsigned short* qrow = qkvb + (size_t)qpos*QKVW + hd*64 + g*8;
      qf0 = *(const bs8*)(qrow);
      qf1 = *(const bs8*)(qrow + 32);
    }
  }

  bs8 kreg[4], vreg[4];
  auto ISSUE = [&](int c){
#pragma unroll
    for (int it=0; it<4; ++it) {
      int idx = tid + it*256;
      int kkK = idx >> 3, dbK = idx & 7;
      int kposK = kbase + (c*128 + kkK)*R;
      bs8 kv = z;
      if (kposK < SEQ) kv = *(const bs8*)(qkvb + (size_t)kposK*QKVW + EMB + hd*64 + dbK*8);
      kreg[it] = kv;
      int kkV = idx & 127, dbV = idx >> 7;
      int kposV = kbase + (c*128 + kkV)*R;
      bs8 vv = z;
      if (kposV < SEQ) vv = *(const bs8*)(qkvb + (size_t)kposV*QKVW + 1536 + hd*64 + dbV*8);
      vreg[it] = vv;
    }
  };

  float rm[4], rs[4];
  f4 oacc[4] = {};
#pragma unroll
  for (int r=0;r<4;++r) { rm[r] = NEGV; rs[r] = 0.f; }

  ISSUE(0);
  for (int c=0; c<4; ++c) {
    __builtin_amdgcn_s_barrier();   // all waves done reading LDS of chunk c-1
    // write staged regs -> LDS (compiler inserts vmcnt waits on the regs)
#pragma unroll
    for (int it=0; it<4; ++it) {
      int idx = tid + it*256;
      int kkK = idx >> 3, dbK = idx & 7;
      *(bs8*)(lK + kkK*72 + dbK*8) = kreg[it];
      int kkV = idx & 127, dbV = idx >> 7;
#pragma unroll
      for (int ii=0; ii<8; ++ii) lVt[(dbV*8+ii)*136 + kkV] = (unsigned short)vreg[it][ii];
    }
    asm volatile("s_waitcnt lgkmcnt(0)" ::: "memory");
    __builtin_amdgcn_sched_barrier(0);
    __builtin_amdgcn_s_barrier();   // LDS chunk c visible to all waves
    if (c+1 < 4) ISSUE(c+1);        // in flight across the whole compute phase

    f4 sc[8];
#pragma unroll
    for (int kt=0; kt<8; ++kt) {
      int key = kt*16 + l16;
      bs8 kf0 = *(const bs8*)(lK + key*72 + g*8);
      bs8 kf1 = *(const bs8*)(lK + key*72 + 32 + g*8);
      f4 acc = {0.f,0.f,0.f,0.f};
      acc = __builtin_amdgcn_mfma_f32_16x16x32_bf16(qf0, kf0, acc, 0,0,0);
      acc = __builtin_amdgcn_mfma_f32_16x16x32_bf16(qf1, kf1, acc, 0,0,0);
      int kpos = kbase + (c*128 + key)*R;
      bool kvld = (kpos < SEQ);
#pragma unroll
      for (int r=0;r<4;++r) sc[kt][r] = kvld ? acc[r]*0.125f : NEGV;
    }
    float scl[4];
#pragma unroll
    for (int r=0;r<4;++r) {
      float mx = sc[0][r];
#pragma unroll
      for (int kt=1;kt<8;++kt) mx = fmaxf(mx, sc[kt][r]);
      mx = fmaxf(mx, __shfl_xor(mx, 1));
      mx = fmaxf(mx, __shfl_xor(mx, 2));
      mx = fmaxf(mx, __shfl_xor(mx, 4));
      mx = fmaxf(mx, __shfl_xor(mx, 8));
      float mn = fmaxf(rm[r], mx);
      scl[r] = __expf(rm[r] - mn);
      rm[r] = mn;
    }
#pragma unroll
    for (int r=0;r<4;++r) {
      float sm = 0.f;
#pragma unroll
      for (int kt=0;kt<8;++kt) { float p = __expf(sc[kt][r] - rm[r]); sc[kt][r] = p; sm += p; }
      sm += __shfl_xor(sm, 1); sm += __shfl_xor(sm, 2);
      sm += __shfl_xor(sm, 4); sm += __shfl_xor(sm, 8);
      rs[r] = rs[r]*scl[r] + sm;
    }
#pragma unroll
    for (int dt=0; dt<4; ++dt)
#pragma unroll
      for (int r=0;r<4;++r) oacc[dt][r] *= scl[r];
#pragma unroll
    for (int kt=0;kt<8;++kt)
#pragma unroll
      for (int r=0;r<4;++r)
        Pl[w][g*4+r][kt*16+l16] = f2bf_fast(sc[kt][r]);
#pragma unroll
    for (int ks=0; ks<4; ++ks) {
      bs8 pa = *(const bs8*)(&Pl[w][l16][ks*32 + g*8]);
#pragma unroll
      for (int dt=0; dt<4; ++dt) {
        bs8 vb = *(const bs8*)(lVt + (dt*16+l16)*136 + ks*32 + g*8);
        oacc[dt] = __builtin_amdgcn_mfma_f32_16x16x32_bf16(pa, vb, oacc[dt], 0,0,0);
      }
    }
  }

  size_t obase = ((size_t)(b*NSEG + seg)*NHEADS + hd)*512;
#pragma unroll
  for (int dt=0; dt<4; ++dt)
#pragma unroll
    for (int r=0;r<4;++r) {
      int j = j0 + g*4 + r;
      OB[(obase + j)*64 + dt*16 + l16] = f2bf(oacc[dt][r] / rs[r]);
    }
  if (l16 == 0) {
#pragma unroll
    for (int r=0;r<4;++r) LB[obase + j0 + g*4 + r] = rm[r] + __logf(rs[r]);
  }
}

// ---------------- combine 3 branches via lse softmax -> attn bf16 (MPAD,768)
__global__ __launch_bounds__(256) void attn_combine_k(
   const unsigned short* __restrict__ o1, const float* __restrict__ l1,
   const unsigned short* __restrict__ o2, const float* __restrict__ l2,
   const unsigned short* __restrict__ o3, const float* __restrict__ l3,
   unsigned short* __restrict__ attn)
{
  int row = blockIdx.x; int t = threadIdx.x;
  unsigned short* arow = attn + (size_t)row*EMB;
  if (row >= MROWS) { arow[t]=0; arow[t+256]=0; arow[t+512]=0; return; }
  int b = row / SEQ, pos = row - (row/SEQ)*SEQ;
#pragma unroll
  for (int c0=0; c0<3; ++c0) {
    int cc = t + c0*256;
    int hd = cc >> 6, d = cc & 63;
    float L0,L1v,L2v,O0,O1v,O2v;
    {
      int seg = pos >> 9; int j = pos & 511;
      size_t base = ((size_t)(b*5 + seg)*NHEADS + hd)*512 + j;
      L0 = l1[base]; O0 = bf2f(o1[base*64 + d]);
    }
    if ((pos & 1) == (hd & 1)) {
      int seg = pos >> 10; int j = ((pos & 1023) - (hd&1)) >> 1;
      size_t base = ((size_t)(b*3 + seg)*NHEADS + hd)*512 + j;
      L1v = l2[base]; O1v = bf2f(o2[base*64 + d]);
    } else { L1v = NEGV; O1v = 0.f; }
    if ((pos & 3) == (hd & 3)) {
      int seg = pos >> 11; int j = ((pos & 2047) - (hd&3)) >> 2;
      size_t base = ((size_t)(b*2 + seg)*NHEADS + hd)*512 + j;
      L2v = l3[base]; O2v = bf2f(o3[base*64 + d]);
    } else { L2v = NEGV; O2v = 0.f; }
    float m = fmaxf(L0, fmaxf(L1v, L2v));
    float e0 = __expf(L0-m), e1 = __expf(L1v-m), e2 = __expf(L2v-m);
    float inv = 1.f/(e0+e1+e2);
    arow[cc] = f2bf((e0*O0+e1*O1v+e2*O2v)*inv);
  }
}

extern "C" void kernel_launch(void* const* d_in, const int* in_sizes, int n_in,
                              void* d_out, int out_size, void* d_ws, size_t ws_size,
                              hipStream_t stream) {
  const float* x       = (const float*)d_in[0];
  const float* conv_w  = (const float*)d_in[1];
  const float* conv_b  = (const float*)d_in[2];
  const float* cls     = (const float*)d_in[3];
  const float* pos_e   = (const float*)d_in[4];
  const float* ln1_g   = (const float*)d_in[5];
  const float* ln1_b   = (const float*)d_in[6];
  const float* wq      = (const float*)d_in[7];
  const float* bq      = (const float*)d_in[8];
  const float* wk      = (const float*)d_in[9];
  const float* bk      = (const float*)d_in[10];
  const float* wv      = (const float*)d_in[11];
  const float* bv      = (const float*)d_in[12];
  const float* wo      = (const float*)d_in[13];
  const float* bo      = (const float*)d_in[14];
  const float* ln2_g   = (const float*)d_in[15];
  const float* ln2_b   = (const float*)d_in[16];
  const float* w1      = (const float*)d_in[17];
  const float* b1      = (const float*)d_in[18];
  const float* w2      = (const float*)d_in[19];
  const float* b2      = (const float*)d_in[20];
  const float* nf_g    = (const float*)d_in[21];
  const float* nf_b    = (const float*)d_in[22];

  char* ws = (char*)d_ws;
  size_t off = 0;
  auto alloc = [&](size_t bytes)->char* {
    char* p = ws + off; off += (bytes + 255) & ~(size_t)255; return p;
  };
  unsigned short* wqkv_t = (unsigned short*)alloc((size_t)12*2304*768*2);
  unsigned short* wo_t   = (unsigned short*)alloc((size_t)12*768*768*2);
  unsigned short* w1_t   = (unsigned short*)alloc((size_t)12*3072*768*2);
  unsigned short* w2_t   = (unsigned short*)alloc((size_t)12*768*3072*2);
  unsigned short* cw_b   = (unsigned short*)alloc((size_t)768*4096*2);
  float* bqkv            = (float*)alloc((size_t)12*2304*4);
  unsigned short* Xp     = (unsigned short*)alloc((size_t)4096*4096*2);
  float* H               = (float*)alloc((size_t)MPAD*768*4);
  float* P               = (float*)alloc((size_t)4*MPAD*768*4);
  unsigned short* Y      = (unsigned short*)alloc((size_t)MPAD*768*2);
  unsigned short* QKV    = (unsigned short*)alloc((size_t)MPAD*2304*2);
  unsigned short* ATT    = (unsigned short*)alloc((size_t)MPAD*768*2);
  unsigned short* Y2     = (unsigned short*)alloc((size_t)MPAD*3072*2);
  unsigned short* O1 = (unsigned short*)alloc((size_t)2*5*12*512*64*2);
  unsigned short* O2 = (unsigned short*)alloc((size_t)2*3*12*512*64*2);
  unsigned short* O3 = (unsigned short*)alloc((size_t)2*2*12*512*64*2);
  float* L1 = (float*)alloc((size_t)2*5*12*512*4);
  float* L2 = (float*)alloc((size_t)2*3*12*512*4);
  float* L3 = (float*)alloc((size_t)2*2*12*512*4);
  const size_t PSTR = (size_t)MPAD*768;

  dim3 tb(32,8);
  wtr_k<<<dim3(24,24,12), tb, 0, stream>>>(wq, wqkv_t, 768, 768, 2304, 0);
  wtr_k<<<dim3(24,24,12), tb, 0, stream>>>(wk, wqkv_t, 768, 768, 2304, 768);
  wtr_k<<<dim3(24,24,12), tb, 0, stream>>>(wv, wqkv_t, 768, 768, 2304, 1536);
  wtr_k<<<dim3(24,24,12), tb, 0, stream>>>(wo, wo_t, 768, 768, 768, 0);
  wtr_k<<<dim3(24,96,12), tb, 0, stream>>>(w1, w1_t, 768, 3072, 3072, 0);
  wtr_k<<<dim3(96,24,12), tb, 0, stream>>>(w2, w2_t, 3072, 768, 768, 0);
  castconv_k<<<3072,256,0,stream>>>(conv_w, cw_b);
  biascat_k<<<108,256,0,stream>>>(bq,bk,bv,bqkv);
  patchify_k<<<16384,256,0,stream>>>(x, Xp);
  gemm_k<3,4><<<dim3(6,32,4),256,0,stream>>>(Xp, cw_b, conv_b, nullptr, P, 4096, 768, PSTR);
  assemble_k<<<MPAD,256,0,stream>>>(P, PSTR, cls, pos_e, H);

  for (int l=0;l<12;++l) {
    if (l==0) ln_k<<<MPAD,256,0,stream>>>(H, ln1_g, ln1_b, Y);
    else ln_red_k<2><<<MPAD,256,0,stream>>>(H, P, PSTR, ln1_g + l*768, ln1_b + l*768, Y);
    gemm_k<0,1><<<dim3(18,33),256,0,stream>>>(Y, wqkv_t + (size_t)l*2304*768, bqkv + l*2304, QKV, nullptr, 768, 2304, 0);
    attn_all_k<<<1920,256,0,stream>>>(QKV, O1,L1,O2,L2,O3,L3);
    attn_combine_k<<<MPAD,256,0,stream>>>(O1,L1,O2,L2,O3,L3, ATT);
    gemm_k<3,2><<<dim3(6,33,2),256,0,stream>>>(ATT, wo_t + (size_t)l*768*768, bo + l*768, nullptr, P, 768, 768, PSTR);
    ln_red_k<2><<<MPAD,256,0,stream>>>(H, P, PSTR, ln2_g + l*768, ln2_b + l*768, Y);
    gemm_k<1,1><<<dim3(24,33),256,0,stream>>>(Y, w1_t + (size_t)l*3072*768, b1 + l*3072, Y2, nullptr, 768, 3072, 0);
    gemm_k<3,2><<<dim3(6,33,2),256,0,stream>>>(Y2, w2_t + (size_t)l*768*3072, b2 + l*768, nullptr, P, 3072, 768, PSTR);
  }
  final_ln_red_k<2><<<2,256,0,stream>>>(H, P, PSTR, nf_g, nf_b, (float*)d_out);
}

// Round 8
// 2738.322 us; speedup vs baseline: 1.9379x; 1.0428x over previous
//
#include <hip/hip_runtime.h>
#include <math.h>

#define SEQ 2049
#define EMB 768
#define NHEADS 12
#define QKVW 2304
#define MROWS 4098
#define MPAD 4224
#define NEGV -1000000000.0f

typedef short bs8 __attribute__((ext_vector_type(8)));
typedef float f4 __attribute__((ext_vector_type(4)));

__device__ __forceinline__ unsigned short f2bf(float f){
  union { float f; unsigned u; } x; x.f = f;
  unsigned r = x.u + 0x7fffu + ((x.u >> 16) & 1u);
  return (unsigned short)(r >> 16);
}
__device__ __forceinline__ unsigned short f2bf_fast(float f){
  union { float f; unsigned u; } x; x.f = f;
  return (unsigned short)((x.u + 0x8000u) >> 16);
}
__device__ __forceinline__ float bf2f(unsigned short u){
  union { unsigned u; float f; } x; x.u = ((unsigned)u) << 16; return x.f;
}

__device__ __forceinline__ float gelu_f(float x){
  float ax = fabsf(x)*0.70710678f;
  float t = 1.f/(1.f + 0.3275911f*ax);
  float p = t*(0.254829592f + t*(-0.284496736f + t*(1.421413741f
            + t*(-1.453152027f + t*1.061405429f))));
  float erfv = 1.f - p*__expf(-ax*ax);
  float s = (x >= 0.f) ? erfv : -erfv;
  return 0.5f*x*(1.f + s);
}

__device__ __forceinline__ void gl_lds16(const void* g, void* l){
  __builtin_amdgcn_global_load_lds((const __attribute__((address_space(1))) void*)g,
                                   (__attribute__((address_space(3))) void*)l, 16, 0, 0);
}

// ---------------- weight transpose fp32 (L,K,N) -> bf16 dst[(l*LD+NOFF+n)*K+k]
__global__ void wtr_k(const float* __restrict__ src, unsigned short* __restrict__ dst,
                      int K, int N, int LD, int NOFF)
{
  __shared__ float tile[32][33];
  int k0 = blockIdx.x*32, n0 = blockIdx.y*32, z = blockIdx.z;
  int tx = threadIdx.x, ty = threadIdx.y;
  const float* s = src + (size_t)z*K*N;
#pragma unroll
  for (int i=0;i<4;++i)
    tile[ty*4+i][tx] = s[(size_t)(k0+ty*4+i)*N + n0+tx];
  __syncthreads();
  unsigned short* dz = dst + ((size_t)z*LD + NOFF)*K;
#pragma unroll
  for (int i=0;i<4;++i)
    dz[(size_t)(n0+ty*4+i)*K + k0+tx] = f2bf(tile[tx][ty*4+i]);
}

__global__ void castconv_k(const float* __restrict__ src, unsigned short* __restrict__ dst){
  size_t i = ((size_t)blockIdx.x*256 + threadIdx.x)*4;
  float4 f = *(const float4*)(src+i);
  dst[i+0]=f2bf(f.x); dst[i+1]=f2bf(f.y); dst[i+2]=f2bf(f.z); dst[i+3]=f2bf(f.w);
}

__global__ void biascat_k(const float* __restrict__ bq, const float* __restrict__ bk,
                          const float* __restrict__ bv, float* __restrict__ dst){
  int i = blockIdx.x*256+threadIdx.x;
  int l = i/QKVW, c = i%QKVW;
  float v = (c<768) ? bq[l*768+c] : (c<1536 ? bk[l*768+c-768] : bv[l*768+c-1536]);
  dst[i] = v;
}

// ---------------- patch extraction
__global__ void patchify_k(const float* __restrict__ x, unsigned short* __restrict__ Xp)
{
  size_t gid = (size_t)blockIdx.x*256 + threadIdx.x;
  size_t oi = gid*4;
  int row = (int)(oi >> 12);
  int c = (int)(oi & 4095);
  int b = row >> 11; int p = row & 2047;
  int pd = p >> 8, ph = (p>>4)&15, pw = p&15;
  int pz = c >> 8, py = (c>>4)&15, px = c&15;
  size_t src = (((size_t)(b*128 + pd*16+pz)*256) + (size_t)(ph*16+py))*256 + (size_t)(pw*16+px);
  float4 f = *(const float4*)(x+src);
  Xp[oi+0]=f2bf(f.x); Xp[oi+1]=f2bf(f.y); Xp[oi+2]=f2bf(f.z); Xp[oi+3]=f2bf(f.w);
}

// ---------------- assemble h = [cls; sum4(P)] + pos, zero pads
__global__ void assemble_k(const float* __restrict__ P, size_t pstride,
                           const float* __restrict__ cls,
                           const float* __restrict__ pos_e, float* __restrict__ H)
{
  int row = blockIdx.x; int t = threadIdx.x;
  float* hr = H + (size_t)row*EMB;
  if (row >= MROWS) { hr[t]=0.f; hr[t+256]=0.f; hr[t+512]=0.f; return; }
  int b = row / SEQ; int pos = row - b*SEQ;
#pragma unroll
  for (int c0=0;c0<3;++c0) {
    int c = t + c0*256;
    float v;
    if (pos==0) v = cls[c];
    else {
      size_t idx = ((size_t)(b*2048 + pos-1))*EMB + c;
      v = P[idx] + P[pstride+idx] + P[2*pstride+idx] + P[3*pstride+idx];
    }
    hr[c] = v + pos_e[(size_t)pos*EMB + c];
  }
}

// ---------------- layernorm row -> bf16
__global__ __launch_bounds__(256) void ln_k(const float* __restrict__ H,
    const float* __restrict__ gam, const float* __restrict__ bet,
    unsigned short* __restrict__ Y)
{
  int row = blockIdx.x, t = threadIdx.x;
  const float* hr = H + (size_t)row*EMB;
  float v0 = hr[t], v1 = hr[t+256], v2 = hr[t+512];
  float s = v0+v1+v2;
#pragma unroll
  for (int off=32; off>=1; off>>=1) s += __shfl_down(s, off);
  __shared__ float r1[4], r2[4];
  if ((t&63)==0) r1[t>>6] = s;
  __syncthreads();
  float mean = (r1[0]+r1[1]+r1[2]+r1[3]) * (1.f/768.f);
  float d0=v0-mean, d1=v1-mean, d2=v2-mean;
  float q = d0*d0+d1*d1+d2*d2;
#pragma unroll
  for (int off=32; off>=1; off>>=1) q += __shfl_down(q, off);
  if ((t&63)==0) r2[t>>6] = q;
  __syncthreads();
  float rstd = rsqrtf((r2[0]+r2[1]+r2[2]+r2[3])*(1.f/768.f) + 1e-5f);
  unsigned short* yr = Y + (size_t)row*EMB;
  yr[t]     = f2bf(d0*rstd*gam[t]     + bet[t]);
  yr[t+256] = f2bf(d1*rstd*gam[t+256] + bet[t+256]);
  yr[t+512] = f2bf(d2*rstd*gam[t+512] + bet[t+512]);
}

// ---------------- fused: H += sum_{s<S} P[s]; Y = LN(H)
template<int S>
__global__ __launch_bounds__(256) void ln_red_k(float* __restrict__ H,
    const float* __restrict__ P, size_t pstride,
    const float* __restrict__ gam, const float* __restrict__ bet,
    unsigned short* __restrict__ Y)
{
  int row = blockIdx.x, t = threadIdx.x;
  size_t base = (size_t)row*EMB;
  float v[3];
#pragma unroll
  for (int c0=0;c0<3;++c0) {
    size_t idx = base + t + c0*256;
    float h = H[idx];
#pragma unroll
    for (int s=0;s<S;++s) h += P[(size_t)s*pstride + idx];
    H[idx] = h; v[c0] = h;
  }
  float s = v[0]+v[1]+v[2];
#pragma unroll
  for (int off=32; off>=1; off>>=1) s += __shfl_down(s, off);
  __shared__ float r1[4], r2[4];
  if ((t&63)==0) r1[t>>6] = s;
  __syncthreads();
  float mean = (r1[0]+r1[1]+r1[2]+r1[3]) * (1.f/768.f);
  float d0=v[0]-mean, d1=v[1]-mean, d2=v[2]-mean;
  float q = d0*d0+d1*d1+d2*d2;
#pragma unroll
  for (int off=32; off>=1; off>>=1) q += __shfl_down(q, off);
  if ((t&63)==0) r2[t>>6] = q;
  __syncthreads();
  float rstd = rsqrtf((r2[0]+r2[1]+r2[2]+r2[3])*(1.f/768.f) + 1e-5f);
  unsigned short* yr = Y + base;
  yr[t]     = f2bf(d0*rstd*gam[t]     + bet[t]);
  yr[t+256] = f2bf(d1*rstd*gam[t+256] + bet[t+256]);
  yr[t+512] = f2bf(d2*rstd*gam[t+512] + bet[t+512]);
}

// ---------------- final layernorm on cls rows -> fp32 out
template<int S>
__global__ __launch_bounds__(256) void final_ln_red_k(const float* __restrict__ H,
   const float* __restrict__ P, size_t pstride,
   const float* __restrict__ gam, const float* __restrict__ bet, float* __restrict__ out)
{
  int b = blockIdx.x, t = threadIdx.x;
  size_t base = (size_t)(b*SEQ)*EMB;
  float v[3];
#pragma unroll
  for (int c0=0;c0<3;++c0) {
    size_t idx = base + t + c0*256;
    float h = H[idx];
#pragma unroll
    for (int s=0;s<S;++s) h += P[(size_t)s*pstride + idx];
    v[c0] = h;
  }
  float s = v[0]+v[1]+v[2];
#pragma unroll
  for (int off=32; off>=1; off>>=1) s += __shfl_down(s, off);
  __shared__ float r1[4], r2[4];
  if ((t&63)==0) r1[t>>6] = s;
  __syncthreads();
  float mean = (r1[0]+r1[1]+r1[2]+r1[3]) * (1.f/768.f);
  float d0=v[0]-mean, d1=v[1]-mean, d2=v[2]-mean;
  float q = d0*d0+d1*d1+d2*d2;
#pragma unroll
  for (int off=32; off>=1; off>>=1) q += __shfl_down(q, off);
  if ((t&63)==0) r2[t>>6] = q;
  __syncthreads();
  float rstd = rsqrtf((r2[0]+r2[1]+r2[2]+r2[3])*(1.f/768.f) + 1e-5f);
  out[b*EMB + t]     = d0*rstd*gam[t]     + bet[t];
  out[b*EMB + t+256] = d1*rstd*gam[t+256] + bet[t+256];
  out[b*EMB + t+512] = d2*rstd*gam[t+512] + bet[t+512];
}

// ---------------- GEMM (unchanged, passed rounds 4-6)
template<int MODE, int NSPLIT>
__global__ __launch_bounds__(256) void gemm_k(
    const unsigned short* __restrict__ A,
    const unsigned short* __restrict__ Bt,
    const float* __restrict__ bias,
    unsigned short* __restrict__ Cb,
    float* __restrict__ Cf,
    int K, int ldc, size_t splitStride)
{
  __shared__ __attribute__((aligned(16))) unsigned short lA[3][128*32];
  __shared__ __attribute__((aligned(16))) unsigned short lB[3][128*32];
  const int tid = threadIdx.x;
  const int w = tid>>6, lane = tid&63, g = lane>>4, l16 = lane&15;
  const int lr = lane>>2;
  const int lcs = (((lane&3) ^ ((lane>>3)&3)))*8;
  const int swz = ((g ^ ((l16>>1)&3)))*8;
  const int nwg = gridDim.x*gridDim.y;
  const int id = blockIdx.y*gridDim.x + blockIdx.x;
  const int q = nwg>>3, r = nwg&7, xc = id&7, si = id>>3;
  const int nid = (xc<r ? xc*(q+1) : r*(q+1)+(xc-r)*q) + si;
  const int tm = nid / gridDim.x;
  const int tn = nid - tm*gridDim.x;
  const int kchunk = K / NSPLIT;
  const int kofs = (NSPLIT>1) ? blockIdx.z * kchunk : 0;
  const unsigned short* Ab = A + (size_t)tm*128*K + kofs;
  const unsigned short* Bb = Bt + (size_t)tn*128*K + kofs;
  const int wm = (w>>1)*64, wn = (w&1)*64;
  f4 acc[4][4] = {};
  const int nkt = kchunk>>5;

  auto STAGE = [&](int buf, int kt){
    const size_t ko = (size_t)(kt*32 + lcs);
    gl_lds16(Ab + (size_t)(w*16 + lr)*K + ko,     ((char*)lA[buf]) + w*1024);
    gl_lds16(Ab + (size_t)((w+4)*16 + lr)*K + ko, ((char*)lA[buf]) + (w+4)*1024);
    gl_lds16(Bb + (size_t)(w*16 + lr)*K + ko,     ((char*)lB[buf]) + w*1024);
    gl_lds16(Bb + (size_t)((w+4)*16 + lr)*K + ko, ((char*)lB[buf]) + (w+4)*1024);
  };

  STAGE(0, 0);
  STAGE(1, 1);
  for (int kt=0; kt<nkt; ++kt) {
    const int cur = kt % 3;
    if (kt+2 < nkt) {
      STAGE((kt+2)%3, kt+2);
      asm volatile("s_waitcnt vmcnt(8)" ::: "memory");
    } else if (kt+1 < nkt) {
      asm volatile("s_waitcnt vmcnt(4)" ::: "memory");
    } else {
      asm volatile("s_waitcnt vmcnt(0)" ::: "memory");
    }
    __builtin_amdgcn_sched_barrier(0);
    __builtin_amdgcn_s_barrier();
    bs8 af[4], bf[4];
#pragma unroll
    for (int mi=0;mi<4;++mi) af[mi] = *(const bs8*)(lA[cur] + (wm+mi*16+l16)*32 + swz);
#pragma unroll
    for (int ni=0;ni<4;++ni) bf[ni] = *(const bs8*)(lB[cur] + (wn+ni*16+l16)*32 + swz);
    asm volatile("s_waitcnt lgkmcnt(0)" ::: "memory");
    __builtin_amdgcn_sched_barrier(0);
    __builtin_amdgcn_s_barrier();
#pragma unroll
    for (int mi=0;mi<4;++mi)
#pragma unroll
      for (int ni=0;ni<4;++ni)
        acc[mi][ni] = __builtin_amdgcn_mfma_f32_16x16x32_bf16(af[mi], bf[ni], acc[mi][ni], 0,0,0);
  }
  const float bscale = (NSPLIT==1 || blockIdx.z==0) ? 1.f : 0.f;
#pragma unroll
  for (int mi=0;mi<4;++mi)
#pragma unroll
    for (int ni=0;ni<4;++ni) {
      int col = tn*128 + wn + ni*16 + l16;
      float bv = bias[col]*bscale;
#pragma unroll
      for (int r0=0;r0<4;++r0) {
        int row = tm*128 + wm + mi*16 + g*4 + r0;
        float val = acc[mi][ni][r0] + bv;
        if (MODE==1) val = gelu_f(val);
        if (MODE<=1) Cb[(size_t)row*ldc + col] = f2bf(val);
        else Cf[(size_t)blockIdx.z*splitStride + (size_t)row*ldc + col] = val;
      }
    }
}

// ---------------- fused dilated attention: early-exit blocks WRITE defaults
// (ws-state independence); __syncthreads barriers; reg-staged prefetch kept.
__global__ __launch_bounds__(256) void attn_all_k(
    const unsigned short* __restrict__ qkv,
    unsigned short* __restrict__ O1, float* __restrict__ L1,
    unsigned short* __restrict__ O2, float* __restrict__ L2,
    unsigned short* __restrict__ O3, float* __restrict__ L3)
{
  __shared__ __attribute__((aligned(16))) unsigned short lK[128*72];
  __shared__ __attribute__((aligned(16))) unsigned short lVt[64*136];
  __shared__ __attribute__((aligned(16))) unsigned short Pl[4][16][136];
  const int tid = threadIdx.x;
  const int w = tid>>6, lane = tid&63, g = lane>>4, l16 = lane&15;

  int id = (blockIdx.x & 7)*240 + (blockIdx.x >> 3);
  int R, WSZ, NSEG; unsigned short* OB; float* LB;
  if (id < 960)       { R=1; WSZ=512;  NSEG=5; OB=O1; LB=L1; }
  else if (id < 1536) { id -= 960;  R=2; WSZ=1024; NSEG=3; OB=O2; LB=L2; }
  else                { id -= 1536; R=4; WSZ=2048; NSEG=2; OB=O3; LB=L3; }
  const int qt = id & 7; int rest = id >> 3;
  const int seg = rest % NSEG; const int bh = rest / NSEG;
  const int b = bh / NHEADS, hd = bh % NHEADS;
  const int hr = hd % R;
  const int kbase = seg*WSZ + hr;
  bs8 z = {0,0,0,0,0,0,0,0};

  // blocks with no valid q-row: write deterministic defaults and leave
  if (kbase + qt*64*R >= SEQ) {
    size_t ob2 = ((size_t)(b*NSEG + seg)*NHEADS + hd)*512 + qt*64;
    int row = tid>>2, cb = (tid&3)*16;
    *(bs8*)(&OB[(ob2 + row)*64 + cb])     = z;
    *(bs8*)(&OB[(ob2 + row)*64 + cb + 8]) = z;
    if (tid < 64) LB[ob2 + tid] = NEGV;
    return;
  }
  int nvk = (SEQ - 1 - kbase)/R + 1; if (nvk > 512) nvk = 512;
  const int nck = (nvk + 127) >> 7;

  const int j0 = qt*64 + w*16;
  const unsigned short* qkvb = qkv + (size_t)b*SEQ*QKVW;

  bs8 qf0 = z, qf1 = z;
  {
    int qpos = kbase + (j0 + l16)*R;
    if (qpos < SEQ) {
      const unsigned short* qrow = qkvb + (size_t)qpos*QKVW + hd*64 + g*8;
      qf0 = *(const bs8*)(qrow);
      qf1 = *(const bs8*)(qrow + 32);
    }
  }

  const int dbK = tid&7, kkKb = tid>>3;
  const int kkV = tid&127, dbV0 = tid>>7;
  const unsigned short* pK = qkvb + (size_t)(kbase + kkKb*R)*QKVW + EMB + hd*64 + dbK*8;
  const unsigned short* pV = qkvb + (size_t)(kbase + kkV*R)*QKVW + 1536 + hd*64 + dbV0*8;
  const size_t stepIt = (size_t)32*R*QKVW;
  const size_t stepC  = (size_t)128*R*QKVW;
  int ci = 0;
  bs8 kreg[4], vreg[4];
  auto ISSUE = [&](){
    const bool full = (kbase + (ci*128 + 127)*R) < SEQ;
    if (full) {
#pragma unroll
      for (int it=0; it<4; ++it) kreg[it] = *(const bs8*)(pK + (size_t)it*stepIt);
#pragma unroll
      for (int it=0; it<4; ++it) vreg[it] = *(const bs8*)(pV + it*16);
    } else {
      const int cofs = ci*128*R;
#pragma unroll
      for (int it=0; it<4; ++it)
        kreg[it] = (kbase + (kkKb + it*32)*R + cofs < SEQ)
                   ? *(const bs8*)(pK + (size_t)it*stepIt) : z;
      const bool vv = (kbase + kkV*R + cofs) < SEQ;
#pragma unroll
      for (int it=0; it<4; ++it) vreg[it] = vv ? *(const bs8*)(pV + it*16) : z;
    }
    pK += stepC; pV += stepC; ++ci;
  };

  float rm[4], rs[4];
  f4 oacc[4] = {};
#pragma unroll
  for (int r=0;r<4;++r) { rm[r] = NEGV; rs[r] = 0.f; }

  ISSUE();
  for (int c=0; c<nck; ++c) {
    __syncthreads();                // all waves done reading chunk c-1; staged loads drained
#pragma unroll
    for (int it=0; it<4; ++it) {
      *(bs8*)(lK + (kkKb + it*32)*72 + dbK*8) = kreg[it];
#pragma unroll
      for (int ii=0; ii<8; ++ii) lVt[((dbV0+it*2)*8+ii)*136 + kkV] = (unsigned short)vreg[it][ii];
    }
    __syncthreads();                // LDS chunk c visible to all waves
    if (c+1 < nck) ISSUE();         // next chunk's loads overlap this compute phase

    const bool fullc = (kbase + (c*128 + 127)*R) < SEQ;
    f4 sc[8];
    __builtin_amdgcn_s_setprio(1);
#pragma unroll
    for (int kt=0; kt<8; ++kt) {
      int key = kt*16 + l16;
      bs8 kf0 = *(const bs8*)(lK + key*72 + g*8);
      bs8 kf1 = *(const bs8*)(lK + key*72 + 32 + g*8);
      f4 acc = {0.f,0.f,0.f,0.f};
      acc = __builtin_amdgcn_mfma_f32_16x16x32_bf16(qf0, kf0, acc, 0,0,0);
      acc = __builtin_amdgcn_mfma_f32_16x16x32_bf16(qf1, kf1, acc, 0,0,0);
      sc[kt] = acc;
    }
    __builtin_amdgcn_s_setprio(0);
    if (fullc) {
#pragma unroll
      for (int kt=0; kt<8; ++kt)
#pragma unroll
        for (int r=0;r<4;++r) sc[kt][r] *= 0.125f;
    } else {
#pragma unroll
      for (int kt=0; kt<8; ++kt) {
        bool kvld = (kbase + (c*128 + kt*16 + l16)*R) < SEQ;
#pragma unroll
        for (int r=0;r<4;++r) sc[kt][r] = kvld ? sc[kt][r]*0.125f : NEGV;
      }
    }
    float scl[4];
#pragma unroll
    for (int r=0;r<4;++r) {
      float mx = sc[0][r];
#pragma unroll
      for (int kt=1;kt<8;++kt) mx = fmaxf(mx, sc[kt][r]);
      mx = fmaxf(mx, __shfl_xor(mx, 1));
      mx = fmaxf(mx, __shfl_xor(mx, 2));
      mx = fmaxf(mx, __shfl_xor(mx, 4));
      mx = fmaxf(mx, __shfl_xor(mx, 8));
      float mn = fmaxf(rm[r], mx);
      scl[r] = __expf(rm[r] - mn);
      rm[r] = mn;
    }
#pragma unroll
    for (int r=0;r<4;++r) {
      float sm = 0.f;
#pragma unroll
      for (int kt=0;kt<8;++kt) { float p = __expf(sc[kt][r] - rm[r]); sc[kt][r] = p; sm += p; }
      rs[r] = rs[r]*scl[r] + sm;
    }
    if (scl[0]<1.f || scl[1]<1.f || scl[2]<1.f || scl[3]<1.f) {
#pragma unroll
      for (int dt=0; dt<4; ++dt)
#pragma unroll
        for (int r=0;r<4;++r) oacc[dt][r] *= scl[r];
    }
#pragma unroll
    for (int kt=0;kt<8;++kt)
#pragma unroll
      for (int r=0;r<4;++r)
        Pl[w][g*4+r][kt*16+l16] = f2bf_fast(sc[kt][r]);
    __builtin_amdgcn_s_setprio(1);
#pragma unroll
    for (int ks=0; ks<4; ++ks) {
      bs8 pa = *(const bs8*)(&Pl[w][l16][ks*32 + g*8]);
#pragma unroll
      for (int dt=0; dt<4; ++dt) {
        bs8 vb = *(const bs8*)(lVt + (dt*16+l16)*136 + ks*32 + g*8);
        oacc[dt] = __builtin_amdgcn_mfma_f32_16x16x32_bf16(pa, vb, oacc[dt], 0,0,0);
      }
    }
    __builtin_amdgcn_s_setprio(0);
  }

#pragma unroll
  for (int r=0;r<4;++r) {
    float s = rs[r];
    s += __shfl_xor(s, 1); s += __shfl_xor(s, 2);
    s += __shfl_xor(s, 4); s += __shfl_xor(s, 8);
    rs[r] = s;
  }

  size_t obase = ((size_t)(b*NSEG + seg)*NHEADS + hd)*512;
#pragma unroll
  for (int dt=0; dt<4; ++dt)
#pragma unroll
    for (int r=0;r<4;++r) {
      int j = j0 + g*4 + r;
      OB[(obase + j)*64 + dt*16 + l16] = f2bf(oacc[dt][r] / rs[r]);
    }
  if (l16 == 0) {
#pragma unroll
    for (int r=0;r<4;++r) LB[obase + j0 + g*4 + r] = rm[r] + __logf(rs[r]);
  }
}

// ---------------- combine 3 branches via lse softmax -> attn bf16 (MPAD,768)
__global__ __launch_bounds__(256) void attn_combine_k(
   const unsigned short* __restrict__ o1, const float* __restrict__ l1,
   const unsigned short* __restrict__ o2, const float* __restrict__ l2,
   const unsigned short* __restrict__ o3, const float* __restrict__ l3,
   unsigned short* __restrict__ attn)
{
  int row = blockIdx.x; int t = threadIdx.x;
  unsigned short* arow = attn + (size_t)row*EMB;
  if (row >= MROWS) { arow[t]=0; arow[t+256]=0; arow[t+512]=0; return; }
  int b = row / SEQ, pos = row - (row/SEQ)*SEQ;
#pragma unroll
  for (int c0=0; c0<3; ++c0) {
    int cc = t + c0*256;
    int hd = cc >> 6, d = cc & 63;
    float L0,L1v,L2v,O0,O1v,O2v;
    {
      int seg = pos >> 9; int j = pos & 511;
      size_t base = ((size_t)(b*5 + seg)*NHEADS + hd)*512 + j;
      L0 = l1[base]; O0 = bf2f(o1[base*64 + d]);
    }
    if ((pos & 1) == (hd & 1)) {
      int seg = pos >> 10; int j = ((pos & 1023) - (hd&1)) >> 1;
      size_t base = ((size_t)(b*3 + seg)*NHEADS + hd)*512 + j;
      L1v = l2[base]; O1v = bf2f(o2[base*64 + d]);
    } else { L1v = NEGV; O1v = 0.f; }
    if ((pos & 3) == (hd & 3)) {
      int seg = pos >> 11; int j = ((pos & 2047) - (hd&3)) >> 2;
      size_t base = ((size_t)(b*2 + seg)*NHEADS + hd)*512 + j;
      L2v = l3[base]; O2v = bf2f(o3[base*64 + d]);
    } else { L2v = NEGV; O2v = 0.f; }
    float m = fmaxf(L0, fmaxf(L1v, L2v));
    float e0 = __expf(L0-m), e1 = __expf(L1v-m), e2 = __expf(L2v-m);
    float inv = 1.f/(e0+e1+e2);
    arow[cc] = f2bf((e0*O0+e1*O1v+e2*O2v)*inv);
  }
}

extern "C" void kernel_launch(void* const* d_in, const int* in_sizes, int n_in,
                              void* d_out, int out_size, void* d_ws, size_t ws_size,
                              hipStream_t stream) {
  const float* x       = (const float*)d_in[0];
  const float* conv_w  = (const float*)d_in[1];
  const float* conv_b  = (const float*)d_in[2];
  const float* cls     = (const float*)d_in[3];
  const float* pos_e   = (const float*)d_in[4];
  const float* ln1_g   = (const float*)d_in[5];
  const float* ln1_b   = (const float*)d_in[6];
  const float* wq      = (const float*)d_in[7];
  const float* bq      = (const float*)d_in[8];
  const float* wk      = (const float*)d_in[9];
  const float* bk      = (const float*)d_in[10];
  const float* wv      = (const float*)d_in[11];
  const float* bv      = (const float*)d_in[12];
  const float* wo      = (const float*)d_in[13];
  const float* bo      = (const float*)d_in[14];
  const float* ln2_g   = (const float*)d_in[15];
  const float* ln2_b   = (const float*)d_in[16];
  const float* w1      = (const float*)d_in[17];
  const float* b1      = (const float*)d_in[18];
  const float* w2      = (const float*)d_in[19];
  const float* b2      = (const float*)d_in[20];
  const float* nf_g    = (const float*)d_in[21];
  const float* nf_b    = (const float*)d_in[22];

  char* ws = (char*)d_ws;
  size_t off = 0;
  auto alloc = [&](size_t bytes)->char* {
    char* p = ws + off; off += (bytes + 255) & ~(size_t)255; return p;
  };
  unsigned short* wqkv_t = (unsigned short*)alloc((size_t)12*2304*768*2);
  unsigned short* wo_t   = (unsigned short*)alloc((size_t)12*768*768*2);
  unsigned short* w1_t   = (unsigned short*)alloc((size_t)12*3072*768*2);
  unsigned short* w2_t   = (unsigned short*)alloc((size_t)12*768*3072*2);
  unsigned short* cw_b   = (unsigned short*)alloc((size_t)768*4096*2);
  float* bqkv            = (float*)alloc((size_t)12*2304*4);
  unsigned short* Xp     = (unsigned short*)alloc((size_t)4096*4096*2);
  float* H               = (float*)alloc((size_t)MPAD*768*4);
  float* P               = (float*)alloc((size_t)4*MPAD*768*4);
  unsigned short* Y      = (unsigned short*)alloc((size_t)MPAD*768*2);
  unsigned short* QKV    = (unsigned short*)alloc((size_t)MPAD*2304*2);
  unsigned short* ATT    = (unsigned short*)alloc((size_t)MPAD*768*2);
  unsigned short* Y2     = (unsigned short*)alloc((size_t)MPAD*3072*2);
  unsigned short* O1 = (unsigned short*)alloc((size_t)2*5*12*512*64*2);
  unsigned short* O2 = (unsigned short*)alloc((size_t)2*3*12*512*64*2);
  unsigned short* O3 = (unsigned short*)alloc((size_t)2*2*12*512*64*2);
  float* L1 = (float*)alloc((size_t)2*5*12*512*4);
  float* L2 = (float*)alloc((size_t)2*3*12*512*4);
  float* L3 = (float*)alloc((size_t)2*2*12*512*4);
  const size_t PSTR = (size_t)MPAD*768;

  dim3 tb(32,8);
  wtr_k<<<dim3(24,24,12), tb, 0, stream>>>(wq, wqkv_t, 768, 768, 2304, 0);
  wtr_k<<<dim3(24,24,12), tb, 0, stream>>>(wk, wqkv_t, 768, 768, 2304, 768);
  wtr_k<<<dim3(24,24,12), tb, 0, stream>>>(wv, wqkv_t, 768, 768, 2304, 1536);
  wtr_k<<<dim3(24,24,12), tb, 0, stream>>>(wo, wo_t, 768, 768, 768, 0);
  wtr_k<<<dim3(24,96,12), tb, 0, stream>>>(w1, w1_t, 768, 3072, 3072, 0);
  wtr_k<<<dim3(96,24,12), tb, 0, stream>>>(w2, w2_t, 3072, 768, 768, 0);
  castconv_k<<<3072,256,0,stream>>>(conv_w, cw_b);
  biascat_k<<<108,256,0,stream>>>(bq,bk,bv,bqkv);
  patchify_k<<<16384,256,0,stream>>>(x, Xp);
  gemm_k<3,4><<<dim3(6,32,4),256,0,stream>>>(Xp, cw_b, conv_b, nullptr, P, 4096, 768, PSTR);
  assemble_k<<<MPAD,256,0,stream>>>(P, PSTR, cls, pos_e, H);

  for (int l=0;l<12;++l) {
    if (l==0) ln_k<<<MPAD,256,0,stream>>>(H, ln1_g, ln1_b, Y);
    else ln_red_k<2><<<MPAD,256,0,stream>>>(H, P, PSTR, ln1_g + l*768, ln1_b + l*768, Y);
    gemm_k<0,1><<<dim3(18,33),256,0,stream>>>(Y, wqkv_t + (size_t)l*2304*768, bqkv + l*2304, QKV, nullptr, 768, 2304, 0);
    attn_all_k<<<1920,256,0,stream>>>(QKV, O1,L1,O2,L2,O3,L3);
    attn_combine_k<<<MPAD,256,0,stream>>>(O1,L1,O2,L2,O3,L3, ATT);
    gemm_k<3,2><<<dim3(6,33,2),256,0,stream>>>(ATT, wo_t + (size_t)l*768*768, bo + l*768, nullptr, P, 768, 768, PSTR);
    ln_red_k<2><<<MPAD,256,0,stream>>>(H, P, PSTR, ln2_g + l*768, ln2_b + l*768, Y);
    gemm_k<1,1><<<dim3(24,33),256,0,stream>>>(Y, w1_t + (size_t)l*3072*768, b1 + l*3072, Y2, nullptr, 768, 3072, 0);
    gemm_k<3,2><<<dim3(6,33,2),256,0,stream>>>(Y2, w2_t + (size_t)l*768*3072, b2 + l*768, nullptr, P, 3072, 768, PSTR);
  }
  final_ln_red_k<2><<<2,256,0,stream>>>(H, P, PSTR, nf_g, nf_b, (float*)d_out);
}